// Round 10
// baseline (2149.980 us; speedup 1.0000x reference)
//
#include <hip/hip_runtime.h>
#include <math.h>

#define NB 4
#define SS 8320
#define DD 512
#define NH_ 8
#define LL 4
#define FF_ 2048
#define MTOT (NB*SS)   // 33280

typedef __attribute__((ext_vector_type(8))) short short8;
typedef __attribute__((ext_vector_type(4))) float f32x4;

__device__ __forceinline__ unsigned short f2bf(float f){
  union { float f; unsigned int u; } x; x.f = f;
  unsigned int r = x.u + 0x7FFFu + ((x.u >> 16) & 1u);
  return (unsigned short)(r >> 16);
}
__device__ __forceinline__ float bf2f(unsigned short u){
  return __uint_as_float(((unsigned int)u) << 16);
}
__device__ __forceinline__ void gload_lds16(const void* g, void* l){
  __builtin_amdgcn_global_load_lds(
      (__attribute__((address_space(1))) void*)g,
      (__attribute__((address_space(3))) void*)l, 16, 0, 0);
}
__device__ __forceinline__ float wred(float v){
  #pragma unroll
  for (int o = 32; o; o >>= 1) v += __shfl_xor(v, o);
  return v;
}
__device__ __forceinline__ float block_sum256(float v){
  __shared__ float sb[4];
  #pragma unroll
  for (int o = 32; o; o >>= 1) v += __shfl_down(v, o);
  int w = threadIdx.x >> 6;
  __syncthreads();
  if ((threadIdx.x & 63) == 0) sb[w] = v;
  __syncthreads();
  return sb[0] + sb[1] + sb[2] + sb[3];
}

// bijective XCD-chunked block remap
__device__ __forceinline__ void xcd_remap(int& bn, int& bm)
{
  const int gx = gridDim.x;
  const int nblk = gx * gridDim.y;
  const int id = blockIdx.x + gx * blockIdx.y;
  const int qd = nblk >> 3, rd = nblk & 7;
  const int xcd = id & 7, pos = id >> 3;
  const int nid = (xcd < rd) ? (xcd * (qd + 1) + pos)
                             : (rd * (qd + 1) + (xcd - rd) * qd + pos);
  bn = nid % gx; bm = nid / gx;
}

// output-tile LDS chunk swizzle (16B chunks, XOR low 3 bits with row&7)
__device__ __forceinline__ int cswz(int row, int ch){
  return (ch & 8) | ((ch & 7) ^ (row & 7));
}

// ---------------- batched weight transposes (K x N fp32 -> N x K bf16) -------
struct P4 { const float* p0; const float* p1; const float* p2; const float* p3; };

__global__ __launch_bounds__(256) void transpose_qkvo_kernel(P4 srcs, unsigned short* __restrict__ dst)
{
  __shared__ float tile[32][33];
  const int z = blockIdx.z;
  const int layer = z >> 2, m = z & 3;
  const float* base = (m == 0) ? srcs.p0 : (m == 1) ? srcs.p1 : (m == 2) ? srcs.p2 : srcs.p3;
  const float* src = base + (size_t)layer * DD * DD;
  unsigned short* d = dst + (size_t)z * DD * DD;
  const int n0 = blockIdx.x * 32, k0 = blockIdx.y * 32;
  const int tx = threadIdx.x & 31, ty = threadIdx.x >> 5;
  #pragma unroll
  for (int j = 0; j < 32; j += 8) tile[ty + j][tx] = src[(size_t)(k0 + ty + j) * DD + n0 + tx];
  __syncthreads();
  #pragma unroll
  for (int j = 0; j < 32; j += 8) d[(size_t)(n0 + ty + j) * DD + k0 + tx] = f2bf(tile[tx][ty + j]);
}

__global__ __launch_bounds__(256) void transpose_bf16_kernel(
    const float* __restrict__ src0, unsigned short* __restrict__ dst0, int K, int N)
{
  __shared__ float tile[32][33];
  const float* src = src0 + (size_t)blockIdx.z * K * N;
  unsigned short* dst = dst0 + (size_t)blockIdx.z * K * N;
  const int n0 = blockIdx.x * 32, k0 = blockIdx.y * 32;
  const int tx = threadIdx.x & 31, ty = threadIdx.x >> 5;
  #pragma unroll
  for (int j = 0; j < 32; j += 8) tile[ty + j][tx] = src[(size_t)(k0 + ty + j) * N + n0 + tx];
  __syncthreads();
  #pragma unroll
  for (int j = 0; j < 32; j += 8) dst[(size_t)(n0 + ty + j) * K + k0 + tx] = f2bf(tile[tx][ty + j]);
}

// ---------------- embedding + 2D sinusoidal PE ----------------
__global__ __launch_bounds__(256) void embed_kernel(
    const float* __restrict__ fbp, const int* __restrict__ coords,
    const float* __restrict__ emb_w, const float* __restrict__ emb_b,
    unsigned short* __restrict__ hb)
{
  const int row = blockIdx.x;
  const int c = threadIdx.x;
  const int s = row % SS;
  const float f0 = fbp[(size_t)row * 2], f1 = fbp[(size_t)row * 2 + 1];
  const float v0 = f0 * emb_w[c] + f1 * emb_w[256 + c] + emb_b[c];
  const int p = (c < 128) ? coords[s * 2 + 1] : coords[s * 2];
  const int c2 = c & 127;
  const int jj = c2 >> 1;
  const float dv = expf(-(float)(2 * jj) * (9.210340371976184f / 128.f));
  const float a = (float)p * dv;
  const float v1 = (c2 & 1) ? cosf(a) : sinf(a);
  const size_t base = (size_t)row * DD;
  hb[base + c] = f2bf(v0);
  hb[base + 256 + c] = f2bf(v1);
}

// ---------------- fused QKV GEMM, 128^2 tile, XCD-remapped, LDS epilogue -----
__global__ __launch_bounds__(256, 4) void gemm_qkv_kernel(
    const unsigned short* __restrict__ A,     // [M][512]
    const unsigned short* __restrict__ Bt,    // [1536][512]
    const float* __restrict__ bq_, const float* __restrict__ bk_, const float* __restrict__ bv_,
    unsigned short* __restrict__ qo, unsigned short* __restrict__ ko, unsigned short* __restrict__ vo)
{
  __shared__ __attribute__((aligned(16))) unsigned short smem[16384];
  unsigned short* As = smem;
  unsigned short* Bs = smem + 8192;
  const int tid = threadIdx.x;
  const int lane = tid & 63, w = tid >> 6;
  const int lr = lane & 15, lg = lane >> 4;
  const int wm = w >> 1, wn = w & 1;
  int bn, bm; xcd_remap(bn, bm);                 // bn 0..11
  const int which = bn >> 2;
  const unsigned short* Ag = A + (size_t)bm * 128 * DD;
  const unsigned short* Bg = Bt + (size_t)bn * 128 * DD;
  unsigned short* out = (which == 0) ? qo : (which == 1) ? ko : vo;
  const float* bias = (which == 0) ? bq_ : (which == 1) ? bk_ : bv_;
  f32x4 acc[4][4] = {};
  for (int kt = 0; kt < 8; ++kt) {
    if (kt) __syncthreads();
    const int kbase = kt << 6;
    #pragma unroll
    for (int i = 0; i < 4; ++i) {
      int cid = i * 256 + tid;
      int row = cid >> 3, c = cid & 7;
      gload_lds16(Ag + (size_t)row * DD + kbase + ((c ^ (row & 7)) << 3), (void*)(As + cid * 8));
    }
    #pragma unroll
    for (int i = 0; i < 4; ++i) {
      int cid = i * 256 + tid;
      int row = cid >> 3, c = cid & 7;
      gload_lds16(Bg + (size_t)row * DD + kbase + ((c ^ (row & 7)) << 3), (void*)(Bs + cid * 8));
    }
    __syncthreads();
    #pragma unroll
    for (int kk = 0; kk < 2; ++kk) {
      short8 af[4], bfv[4];
      #pragma unroll
      for (int f = 0; f < 4; ++f) {
        int row = wm * 64 + f * 16 + lr;
        af[f] = *(const short8*)(As + row * 64 + (((kk * 4 + lg) ^ (row & 7)) << 3));
      }
      #pragma unroll
      for (int f = 0; f < 4; ++f) {
        int row = wn * 64 + f * 16 + lr;
        bfv[f] = *(const short8*)(Bs + row * 64 + (((kk * 4 + lg) ^ (row & 7)) << 3));
      }
      #pragma unroll
      for (int fm = 0; fm < 4; ++fm)
        #pragma unroll
        for (int fn = 0; fn < 4; ++fn)
          acc[fm][fn] = __builtin_amdgcn_mfma_f32_16x16x32_bf16(af[fm], bfv[fn], acc[fm][fn], 0, 0, 0);
    }
  }
  // epilogue: stage bf16 tile in LDS (swizzled), then vector stores
  const int elu = (which < 2);
  __syncthreads();
  #pragma unroll
  for (int fm = 0; fm < 4; ++fm) {
    const int rr = wm * 64 + fm * 16 + lg * 4;
    #pragma unroll
    for (int fn = 0; fn < 4; ++fn) {
      const int col = wn * 64 + fn * 16 + lr;
      const int ch = col >> 3, cl = col & 7;
      const float bv = bias[(bn & 3) * 128 + col];
      #pragma unroll
      for (int r = 0; r < 4; ++r) {
        float v = acc[fm][fn][r] + bv;
        if (elu) v = (v > 0.f) ? (v + 1.f) : expf(v);
        const int row = rr + r;
        smem[row * 128 + (cswz(row, ch) << 3) + cl] = f2bf(v);
      }
    }
  }
  __syncthreads();
  const int orow = tid >> 1, ocb = (tid & 1) << 6;
  unsigned short* og = out + (size_t)(bm * 128 + orow) * DD + (bn & 3) * 128 + ocb;
  #pragma unroll
  for (int j = 0; j < 8; ++j) {
    const int ch = (ocb >> 3) + j;
    *(short8*)(og + j * 8) = *(const short8*)(smem + orow * 128 + (cswz(orow, ch) << 3));
  }
}

// ---------------- generic GEMM, 128^2 tile, XCD-remapped, LDS epilogue -------
// ACT: 0=none 2=relu.  RES: add existing C (in-place residual)
template<int ACT, int RES>
__global__ __launch_bounds__(256, 4) void gemm_kernel(
    const unsigned short* __restrict__ A,
    const unsigned short* __restrict__ Bt,
    const float* __restrict__ bias,
    unsigned short* __restrict__ C,
    int N, int K, int lda, int ldb)
{
  __shared__ __attribute__((aligned(16))) unsigned short smem[16384];
  unsigned short* As = smem;
  unsigned short* Bs = smem + 8192;
  const int tid = threadIdx.x;
  const int lane = tid & 63, w = tid >> 6;
  const int lr = lane & 15, lg = lane >> 4;
  const int wm = w >> 1, wn = w & 1;
  int bn, bm; xcd_remap(bn, bm);
  const unsigned short* Ag = A + (size_t)bm * 128 * lda;
  const unsigned short* Bg = Bt + (size_t)bn * 128 * ldb;
  f32x4 acc[4][4] = {};
  const int nkt = K >> 6;
  for (int kt = 0; kt < nkt; ++kt) {
    if (kt) __syncthreads();
    const int kbase = kt << 6;
    #pragma unroll
    for (int i = 0; i < 4; ++i) {
      int cid = i * 256 + tid;
      int row = cid >> 3, c = cid & 7;
      gload_lds16(Ag + (size_t)row * lda + kbase + ((c ^ (row & 7)) << 3), (void*)(As + cid * 8));
    }
    #pragma unroll
    for (int i = 0; i < 4; ++i) {
      int cid = i * 256 + tid;
      int row = cid >> 3, c = cid & 7;
      gload_lds16(Bg + (size_t)row * ldb + kbase + ((c ^ (row & 7)) << 3), (void*)(Bs + cid * 8));
    }
    __syncthreads();
    #pragma unroll
    for (int kk = 0; kk < 2; ++kk) {
      short8 af[4], bfv[4];
      #pragma unroll
      for (int f = 0; f < 4; ++f) {
        int row = wm * 64 + f * 16 + lr;
        af[f] = *(const short8*)(As + row * 64 + (((kk * 4 + lg) ^ (row & 7)) << 3));
      }
      #pragma unroll
      for (int f = 0; f < 4; ++f) {
        int row = wn * 64 + f * 16 + lr;
        bfv[f] = *(const short8*)(Bs + row * 64 + (((kk * 4 + lg) ^ (row & 7)) << 3));
      }
      #pragma unroll
      for (int fm = 0; fm < 4; ++fm)
        #pragma unroll
        for (int fn = 0; fn < 4; ++fn)
          acc[fm][fn] = __builtin_amdgcn_mfma_f32_16x16x32_bf16(af[fm], bfv[fn], acc[fm][fn], 0, 0, 0);
    }
  }
  __syncthreads();
  #pragma unroll
  for (int fm = 0; fm < 4; ++fm) {
    const int rr = wm * 64 + fm * 16 + lg * 4;
    #pragma unroll
    for (int fn = 0; fn < 4; ++fn) {
      const int col = wn * 64 + fn * 16 + lr;
      const int ch = col >> 3, cl = col & 7;
      const float bv = bias[bn * 128 + col];
      #pragma unroll
      for (int r = 0; r < 4; ++r) {
        float v = acc[fm][fn][r] + bv;
        if (ACT == 2) v = (v > 0.f) ? v : 0.f;
        const int row = rr + r;
        smem[row * 128 + (cswz(row, ch) << 3) + cl] = f2bf(v);
      }
    }
  }
  __syncthreads();
  const int orow = tid >> 1, ocb = (tid & 1) << 6;
  unsigned short* og = C + (size_t)(bm * 128 + orow) * N + bn * 128 + ocb;
  #pragma unroll
  for (int j = 0; j < 8; ++j) {
    const int ch = (ocb >> 3) + j;
    short8 c8 = *(const short8*)(smem + orow * 128 + (cswz(orow, ch) << 3));
    if (RES) {
      short8 r8 = *(const short8*)(og + j * 8);
      #pragma unroll
      for (int k = 0; k < 8; ++k)
        c8[k] = (short)f2bf(bf2f((unsigned short)c8[k]) + bf2f((unsigned short)r8[k]));
    }
    *(short8*)(og + j * 8) = c8;
  }
}

// ---------------- kv partials: 640-row chunks x (b,h) ----------------
__global__ __launch_bounds__(256) void kv_part_kernel(
    const unsigned short* __restrict__ kb, const unsigned short* __restrict__ vb,
    float* __restrict__ kvp, float* __restrict__ ksp)
{
  __shared__ __attribute__((aligned(16))) float Kc[128][64];
  __shared__ __attribute__((aligned(16))) float Vc[128][64];
  const int ch = blockIdx.x;
  const int bh = blockIdx.y;
  const int NBH = gridDim.y;
  const int b = bh >> 3, h = bh & 7;
  const int tid = threadIdx.x;
  const int d = tid >> 2, m0 = (tid & 3) << 4;
  f32x4 a0 = {}, a1 = {}, a2 = {}, a3 = {};
  float sk = 0.f;
  for (int t = 0; t < 5; ++t) {
    if (t) __syncthreads();
    const size_t roff = ((size_t)b * SS + ch * 640 + t * 128) * DD + h * 64;
    #pragma unroll
    for (int i = 0; i < 8; ++i) {
      int e4 = i * 256 + tid;
      int r = e4 >> 4, c4 = e4 & 15;
      ushort4 kq = *(const ushort4*)(kb + roff + (size_t)r * DD + c4 * 4);
      ushort4 vq = *(const ushort4*)(vb + roff + (size_t)r * DD + c4 * 4);
      f32x4 kf4 = { bf2f(kq.x), bf2f(kq.y), bf2f(kq.z), bf2f(kq.w) };
      f32x4 vf4 = { bf2f(vq.x), bf2f(vq.y), bf2f(vq.z), bf2f(vq.w) };
      *(f32x4*)&Kc[r][c4 * 4] = kf4;
      *(f32x4*)&Vc[r][c4 * 4] = vf4;
    }
    __syncthreads();
    for (int s2 = 0; s2 < 128; ++s2) {
      const float kd = Kc[s2][d];
      const f32x4* vp = (const f32x4*)&Vc[s2][m0];
      a0 += kd * vp[0]; a1 += kd * vp[1]; a2 += kd * vp[2]; a3 += kd * vp[3];
    }
    if (tid < 64) {
      for (int s2 = 0; s2 < 128; ++s2) sk += Kc[s2][tid];
    }
  }
  float* ko = kvp + (((size_t)ch * NBH + bh) * 64 + d) * 64 + m0;
  *(f32x4*)(ko) = a0; *(f32x4*)(ko + 4) = a1; *(f32x4*)(ko + 8) = a2; *(f32x4*)(ko + 12) = a3;
  if (tid < 64) ksp[((size_t)ch * NBH + bh) * 64 + tid] = sk;
}

__global__ __launch_bounds__(256) void kv_reduce_kernel(
    const float* __restrict__ kvp, const float* __restrict__ ksp,
    unsigned short* __restrict__ kvT, float* __restrict__ ksum, int NBH)
{
  const int idx = blockIdx.x * 256 + threadIdx.x;
  const int nkv = NBH * 4096;
  if (idx < nkv) {
    const int bh = idx >> 12, dm = idx & 4095;
    const int d = dm >> 6, m = dm & 63;
    float s = 0.f;
    #pragma unroll
    for (int c = 0; c < 13; ++c) s += kvp[(((size_t)c * NBH + bh) << 12) + dm];
    kvT[(size_t)bh * 4096 + m * 64 + d] = f2bf(s);
  } else if (idx < nkv + NBH * 64) {
    const int i2 = idx - nkv;
    const int bh = i2 >> 6, d = i2 & 63;
    float s = 0.f;
    #pragma unroll
    for (int c = 0; c < 13; ++c) s += ksp[((size_t)c * NBH + bh) * 64 + d];
    ksum[i2] = s;
  }
}

// ---------------- attn: z fused (zloc from Qs) + (qf @ kv) * z, in-place ----
__global__ __launch_bounds__(256) void attn_kernel(
    unsigned short* __restrict__ qb, const unsigned short* __restrict__ kvT,
    const float* __restrict__ ksum)
{
  __shared__ __attribute__((aligned(16))) unsigned short Qs[128 * 64];
  __shared__ __attribute__((aligned(16))) unsigned short Ks[64 * 64];
  __shared__ float zloc[128];
  const int st = blockIdx.x;
  const int bh = blockIdx.y;
  const int b = bh >> 3, h = bh & 7;
  const int tid = threadIdx.x, lane = tid & 63, w = tid >> 6;
  const int lr = lane & 15, lg = lane >> 4;
  const size_t row0 = (size_t)b * SS + st * 128;
  const unsigned short* Qg = qb + row0 * DD + h * 64;
  #pragma unroll
  for (int i = 0; i < 4; ++i) {
    int cid = i * 256 + tid;
    int r = cid >> 3, c = cid & 7;
    gload_lds16(Qg + (size_t)r * DD + ((c ^ (r & 7)) << 3), (void*)(Qs + cid * 8));
  }
  #pragma unroll
  for (int i = 0; i < 2; ++i) {
    int cid = i * 256 + tid;
    int r = cid >> 3, c = cid & 7;
    gload_lds16(kvT + (size_t)bh * 4096 + r * 64 + ((c ^ (r & 7)) << 3), (void*)(Ks + cid * 8));
  }
  __syncthreads();
  if (tid < 128) {
    const float* ks = ksum + (size_t)bh * 64;
    float dot = 0.f;
    #pragma unroll
    for (int c = 0; c < 8; ++c) {
      short8 qv = *(const short8*)(Qs + tid * 64 + ((c ^ (tid & 7)) << 3));
      #pragma unroll
      for (int j = 0; j < 8; ++j) dot += bf2f((unsigned short)qv[j]) * ks[c * 8 + j];
    }
    zloc[tid] = 1.f / (dot + 1e-6f);
  }
  __syncthreads();
  f32x4 acc[2][4] = {};
  #pragma unroll
  for (int kk = 0; kk < 2; ++kk) {
    short8 af[2], bfv[4];
    #pragma unroll
    for (int f = 0; f < 2; ++f) {
      int r = w * 32 + f * 16 + lr;
      af[f] = *(const short8*)(Qs + r * 64 + (((kk * 4 + lg) ^ (r & 7)) << 3));
    }
    #pragma unroll
    for (int f = 0; f < 4; ++f) {
      int r = f * 16 + lr;
      bfv[f] = *(const short8*)(Ks + r * 64 + (((kk * 4 + lg) ^ (r & 7)) << 3));
    }
    #pragma unroll
    for (int fm = 0; fm < 2; ++fm)
      #pragma unroll
      for (int fn = 0; fn < 4; ++fn)
        acc[fm][fn] = __builtin_amdgcn_mfma_f32_16x16x32_bf16(af[fm], bfv[fn], acc[fm][fn], 0, 0, 0);
  }
  #pragma unroll
  for (int fm = 0; fm < 2; ++fm) {
    #pragma unroll
    for (int r = 0; r < 4; ++r) {
      const int lrow = w * 32 + fm * 16 + lg * 4 + r;
      const size_t grow = row0 + lrow;
      const float zv = zloc[lrow];
      unsigned short* out = qb + grow * DD + h * 64;
      #pragma unroll
      for (int fn = 0; fn < 4; ++fn)
        out[fn * 16 + lr] = f2bf(acc[fm][fn][r] * zv);
    }
  }
}

// ---------------- wave-per-row LayerNorm, in-place bf16 ----------------
__global__ __launch_bounds__(256) void ln_wave_kernel(
    unsigned short* __restrict__ hb, const float* __restrict__ g, const float* __restrict__ bt)
{
  const int tid = threadIdx.x, wv = tid >> 6, ln = tid & 63;
  const size_t row = (size_t)blockIdx.x * 4 + wv;
  unsigned short* p = hb + row * DD + ln * 8;
  ushort4 u0 = *(const ushort4*)p;
  ushort4 u1 = *(const ushort4*)(p + 4);
  float x[8] = { bf2f(u0.x), bf2f(u0.y), bf2f(u0.z), bf2f(u0.w),
                 bf2f(u1.x), bf2f(u1.y), bf2f(u1.z), bf2f(u1.w) };
  float s = 0.f;
  #pragma unroll
  for (int i = 0; i < 8; ++i) s += x[i];
  const float mean = wred(s) * (1.f / DD);
  float sq = 0.f;
  #pragma unroll
  for (int i = 0; i < 8; ++i) { const float d = x[i] - mean; sq += d * d; }
  const float rstd = rsqrtf(wred(sq) * (1.f / DD) + 1e-5f);
  const float4 g0 = *(const float4*)(g + ln * 8), g1 = *(const float4*)(g + ln * 8 + 4);
  const float4 b0 = *(const float4*)(bt + ln * 8), b1 = *(const float4*)(bt + ln * 8 + 4);
  const float gg[8] = { g0.x, g0.y, g0.z, g0.w, g1.x, g1.y, g1.z, g1.w };
  const float bb[8] = { b0.x, b0.y, b0.z, b0.w, b1.x, b1.y, b1.z, b1.w };
  ushort4 o0, o1;
  o0.x = f2bf((x[0] - mean) * rstd * gg[0] + bb[0]);
  o0.y = f2bf((x[1] - mean) * rstd * gg[1] + bb[1]);
  o0.z = f2bf((x[2] - mean) * rstd * gg[2] + bb[2]);
  o0.w = f2bf((x[3] - mean) * rstd * gg[3] + bb[3]);
  o1.x = f2bf((x[4] - mean) * rstd * gg[4] + bb[4]);
  o1.y = f2bf((x[5] - mean) * rstd * gg[5] + bb[5]);
  o1.z = f2bf((x[6] - mean) * rstd * gg[6] + bb[6]);
  o1.w = f2bf((x[7] - mean) * rstd * gg[7] + bb[7]);
  *(ushort4*)p = o0;
  *(ushort4*)(p + 4) = o1;
}

// ---------------- wave-per-row final LN + heads + DFT scatter ----------------
__global__ __launch_bounds__(256) void head_wave_kernel(
    const unsigned short* __restrict__ hb,
    const float* __restrict__ lg_, const float* __restrict__ lb_,
    const float* __restrict__ aw, const float* __restrict__ ab,
    const float* __restrict__ pw, const float* __restrict__ pb,
    const float* __restrict__ mag_min, const float* __restrict__ mag_max,
    const float* __restrict__ atten, const int* __restrict__ dst,
    float* __restrict__ yhat, float* __restrict__ dre, float* __restrict__ dimg)
{
  const int tid = threadIdx.x, wv = tid >> 6, ln = tid & 63;
  const size_t row = (size_t)blockIdx.x * 4 + wv;
  const unsigned short* p = hb + row * DD + ln * 8;
  ushort4 u0 = *(const ushort4*)p;
  ushort4 u1 = *(const ushort4*)(p + 4);
  float x[8] = { bf2f(u0.x), bf2f(u0.y), bf2f(u0.z), bf2f(u0.w),
                 bf2f(u1.x), bf2f(u1.y), bf2f(u1.z), bf2f(u1.w) };
  float s = 0.f;
  #pragma unroll
  for (int i = 0; i < 8; ++i) s += x[i];
  const float mean = wred(s) * (1.f / DD);
  float sq = 0.f;
  #pragma unroll
  for (int i = 0; i < 8; ++i) { const float d = x[i] - mean; sq += d * d; }
  const float rstd = rsqrtf(wred(sq) * (1.f / DD) + 1e-5f);
  float ad = 0.f, pd = 0.f;
  #pragma unroll
  for (int i = 0; i < 8; ++i) {
    const float y = (x[i] - mean) * rstd * lg_[ln * 8 + i] + lb_[ln * 8 + i];
    ad += y * aw[ln * 8 + i];
    pd += y * pw[ln * 8 + i];
  }
  ad = wred(ad); pd = wred(pd);
  if (ln == 0) {
    const float ya = ad + ab[0];
    const float yp = tanhf(pd + pb[0]);
    yhat[row * 2] = ya;
    yhat[row * 2 + 1] = yp;
    const int b = (int)(row / SS), s2 = (int)(row % SS);
    const float amp = expf((ya + 1.f) * 0.5f * (mag_max[0] - mag_min[0]) + mag_min[0]);
    const float phi = yp * 3.14159265358979323846f;
    const int j = dst[s2];
    const float at = atten[j];
    dre[(size_t)b * SS + j] = amp * cosf(phi) * at;
    dimg[(size_t)b * SS + j] = amp * sinf(phi) * at;
  }
}

// ---------------- iDFT stage A ----------------
__global__ __launch_bounds__(256) void fftA_kernel(
    const float* __restrict__ dre, const float* __restrict__ dimg,
    float* __restrict__ tre, float* __restrict__ tim)
{
  __shared__ float ct[128], st[128];
  const int tid = threadIdx.x;
  if (tid < 128) {
    float a = (float)tid * (3.14159265358979323846f / 64.f);
    ct[tid] = cosf(a); st[tid] = sinf(a);
  }
  __syncthreads();
  const int idx = blockIdx.x * 256 + tid;
  const int v = idx % 65;
  const int y = (idx / 65) & 127;
  const int b = idx / (65 * 128);
  const float* pr = dre + (size_t)b * SS + v;
  const float* pi = dimg + (size_t)b * SS + v;
  float ar = 0.f, ai = 0.f;
  for (int u = 0; u < 128; ++u) {
    int t2 = (u * y) & 127;
    float cr = ct[t2], si = st[t2];
    float xr = pr[(size_t)u * 65], xi = pi[(size_t)u * 65];
    ar += xr * cr - xi * si;
    ai += xr * si + xi * cr;
  }
  tre[idx] = ar * (1.f / 128.f);
  tim[idx] = ai * (1.f / 128.f);
}

// ---------------- iDFT stage B ----------------
__global__ __launch_bounds__(256) void fftB_kernel(
    const float* __restrict__ tre, const float* __restrict__ tim,
    float* __restrict__ img)
{
  __shared__ float ct[128], st[128];
  const int tid = threadIdx.x;
  if (tid < 128) {
    float a = (float)tid * (3.14159265358979323846f / 64.f);
    ct[tid] = cosf(a); st[tid] = sinf(a);
  }
  __syncthreads();
  const int idx = blockIdx.x * 256 + tid;
  const int x = idx & 127;
  const int y = (idx >> 7) & 127;
  const int b = idx >> 14;
  const float* pr = tre + ((size_t)b * 128 + y) * 65;
  const float* pi = tim + ((size_t)b * 128 + y) * 65;
  float a2 = pr[0] + ((x & 1) ? -pr[64] : pr[64]);
  for (int v = 1; v < 64; ++v) {
    int t2 = (v * x) & 127;
    a2 += 2.f * (pr[v] * ct[t2] - pi[v] * st[t2]);
  }
  a2 *= (1.f / 128.f);
  const int yy = (y + 64) & 127, xx = (x + 64) & 127;
  img[((size_t)b << 14) + (yy << 7) + xx] = a2;
}

// ---------------- conv 3x3 (1->8) + relu ----------------
__global__ __launch_bounds__(256) void conv1_kernel(
    const float* __restrict__ img, const float* __restrict__ w,
    const float* __restrict__ bi, float* __restrict__ c1)
{
  const int idx = blockIdx.x * 256 + threadIdx.x;
  const int x = idx & 127, y = (idx >> 7) & 127, ch = (idx >> 14) & 7, b = idx >> 17;
  const float* ip = img + ((size_t)b << 14);
  const float* wp = w + ch * 9;
  float acc = bi[ch];
  #pragma unroll
  for (int dy = -1; dy <= 1; ++dy) {
    const int yy = y + dy;
    if (yy < 0 || yy > 127) continue;
    #pragma unroll
    for (int dx = -1; dx <= 1; ++dx) {
      const int xx = x + dx;
      if (xx < 0 || xx > 127) continue;
      acc += ip[(yy << 7) + xx] * wp[(dy + 1) * 3 + (dx + 1)];
    }
  }
  c1[idx] = acc > 0.f ? acc : 0.f;
}

// ---------------- BN stats: two-stage ----------------
__global__ __launch_bounds__(256) void bn_part_kernel(
    const float* __restrict__ c1, float* __restrict__ bnp)
{
  const int ch = blockIdx.x >> 5, sl = blockIdx.x & 31;
  const int tid = threadIdx.x;
  const int n = sl * 2048 + tid * 8;
  const int b = n >> 14, i = n & 16383;
  const float* p = c1 + (((size_t)b * 8 + ch) << 14) + i;
  float4 a0 = *(const float4*)p, a1 = *(const float4*)(p + 4);
  float s = a0.x + a0.y + a0.z + a0.w + a1.x + a1.y + a1.z + a1.w;
  float sq = a0.x*a0.x + a0.y*a0.y + a0.z*a0.z + a0.w*a0.w
           + a1.x*a1.x + a1.y*a1.y + a1.z*a1.z + a1.w*a1.w;
  s = block_sum256(s);
  sq = block_sum256(sq);
  if (tid == 0) { bnp[blockIdx.x] = s; bnp[256 + blockIdx.x] = sq; }
}

__global__ __launch_bounds__(256) void bn_final_kernel(
    const float* __restrict__ bnp, float* __restrict__ stats)
{
  const int t = threadIdx.x;
  float s = bnp[t], sq = bnp[256 + t];
  #pragma unroll
  for (int o = 16; o; o >>= 1) { s += __shfl_down(s, o, 32); sq += __shfl_down(sq, o, 32); }
  if ((t & 31) == 0) {
    const int ch = t >> 5;
    const float m = s * (1.f / 65536.f);
    const float var = sq * (1.f / 65536.f) - m * m;
    stats[ch] = m;
    stats[8 + ch] = rsqrtf(var + 1e-5f);
  }
}

__global__ __launch_bounds__(256) void conv2_kernel(
    const float* __restrict__ c1, const float* __restrict__ stats,
    const float* __restrict__ bng, const float* __restrict__ bnb,
    const float* __restrict__ w2, const float* __restrict__ b2,
    const float* __restrict__ img, float* __restrict__ out)
{
  const int idx = blockIdx.x * 256 + threadIdx.x;
  const int b = idx >> 14, sp = idx & 16383;
  float acc = b2[0];
  #pragma unroll
  for (int ch = 0; ch < 8; ++ch) {
    float v = c1[(((size_t)b * 8 + ch) << 14) + sp];
    v = (v - stats[ch]) * stats[8 + ch] * bng[ch] + bnb[ch];
    acc += v * w2[ch];
  }
  out[idx] = acc + img[idx];
}

extern "C" void kernel_launch(void* const* d_in, const int* in_sizes, int n_in,
                              void* d_out, int out_size, void* d_ws, size_t ws_size,
                              hipStream_t stream)
{
  (void)in_sizes; (void)n_in; (void)out_size;
  const float* fbp = (const float*)d_in[1];
  const float* mag_min = (const float*)d_in[2];
  const float* mag_max = (const float*)d_in[3];
  const float* atten = (const float*)d_in[4];
  const int* coords = (const int*)d_in[5];
  const int* dstc = (const int*)d_in[6];
  const float* emb_w = (const float*)d_in[8];
  const float* emb_b = (const float*)d_in[9];
  const float* Wq = (const float*)d_in[10]; const float* bq = (const float*)d_in[11];
  const float* Wk = (const float*)d_in[12]; const float* bk = (const float*)d_in[13];
  const float* Wv = (const float*)d_in[14]; const float* bv = (const float*)d_in[15];
  const float* Wo = (const float*)d_in[16]; const float* bo = (const float*)d_in[17];
  const float* ln1g = (const float*)d_in[18]; const float* ln1b = (const float*)d_in[19];
  const float* W1 = (const float*)d_in[20]; const float* b1 = (const float*)d_in[21];
  const float* W2 = (const float*)d_in[22]; const float* b2 = (const float*)d_in[23];
  const float* ln2g = (const float*)d_in[24]; const float* ln2b = (const float*)d_in[25];
  const float* lnfg = (const float*)d_in[26]; const float* lnfb = (const float*)d_in[27];
  const float* aw = (const float*)d_in[28]; const float* ab = (const float*)d_in[29];
  const float* pw = (const float*)d_in[30]; const float* pb = (const float*)d_in[31];
  const float* c1w = (const float*)d_in[32]; const float* c1b = (const float*)d_in[33];
  const float* bng = (const float*)d_in[34]; const float* bnb = (const float*)d_in[35];
  const float* c2w = (const float*)d_in[36]; const float* c2b = (const float*)d_in[37];

  auto rnd = [](size_t b_) { return (b_ + 255) & ~(size_t)255; };
  const size_t SZ_M    = rnd((size_t)MTOT * DD * 2);            // 34.08 MB
  const size_t SZ_Y1   = rnd((size_t)MTOT * FF_ * 2);           // 136.3 MB
  const size_t SZ_WQKVO= rnd((size_t)LL * 4 * DD * DD * 2);
  const size_t SZ_W12  = rnd((size_t)LL * DD * FF_ * 2);
  const size_t SZ_WALL = SZ_WQKVO + 2 * SZ_W12;
  const size_t NEED_FULL = SZ_WALL + 4 * SZ_M + rnd((size_t)13*32*4096*4) + rnd((size_t)13*32*64*4) +
                           rnd((size_t)32*4096*2) + rnd((size_t)32*64*4) + 4096;
  const size_t NEED_FULLY = NEED_FULL + SZ_Y1;
  const size_t NEED_FB = SZ_WALL + SZ_M + rnd((size_t)SS*DD*2) + rnd((size_t)SS*FF_*2) +
                         rnd((size_t)8*4096*2) + rnd((size_t)8*64*4) + 4096;
  const int mode = (ws_size >= NEED_FULLY) ? 2 : (ws_size >= NEED_FULL) ? 1 : 0;
  if (mode == 0 && ws_size < NEED_FB) return;

  char* wsp = (char*)d_ws;
  size_t off = 0;
  auto alloc = [&](size_t bytes) -> char* { char* p = wsp + off; off += rnd(bytes); return p; };

  unsigned short* wsTall = (unsigned short*)alloc((size_t)LL * 4 * DD * DD * 2);
  unsigned short* w1Tall = (unsigned short*)alloc((size_t)LL * DD * FF_ * 2);
  unsigned short* w2Tall = (unsigned short*)alloc((size_t)LL * DD * FF_ * 2);

  unsigned short *hb, *qb_, *kb_, *vb_, *y1c, *y1ded = nullptr, *kvT;
  float *kvp, *ksp, *ksum;
  if (mode >= 1) {
    hb  = (unsigned short*)alloc((size_t)MTOT * DD * 2);
    qb_ = (unsigned short*)alloc((size_t)MTOT * DD * 2);
    kb_ = (unsigned short*)alloc((size_t)MTOT * DD * 2);
    vb_ = (unsigned short*)alloc((size_t)MTOT * DD * 2);
    if (mode == 2) y1ded = (unsigned short*)alloc((size_t)MTOT * FF_ * 2);
    kvp = (float*)alloc((size_t)13 * 32 * 4096 * 4);
    ksp = (float*)alloc((size_t)13 * 32 * 64 * 4);
    kvT = (unsigned short*)alloc((size_t)32 * 4096 * 2);
    ksum = (float*)alloc((size_t)32 * 64 * 4);
    y1c = nullptr;
  } else {
    hb  = (unsigned short*)alloc((size_t)MTOT * DD * 2);
    qb_ = (unsigned short*)alloc((size_t)SS * DD * 2);
    unsigned short* uni = (unsigned short*)alloc((size_t)SS * FF_ * 2);
    kb_ = uni;
    vb_ = uni + (size_t)SS * DD;
    kvp = (float*)(uni + 2 * (size_t)SS * DD);
    ksp = kvp + (size_t)13 * 8 * 4096;
    kvT = (unsigned short*)alloc((size_t)8 * 4096 * 2);
    ksum = (float*)alloc((size_t)8 * 64 * 4);
    y1c = uni;
  }

  // FFT/conv overlay inside qb_ (dead after the final layer's o-proj)
  float* dre  = (float*)qb_;
  float* dimg = dre + (size_t)NB * SS;
  float* tre  = dimg + (size_t)NB * SS;
  float* tim  = tre + (size_t)NB * 128 * 65;
  float* img  = tim + (size_t)NB * 128 * 65;
  float* c1buf = img + (size_t)NB * 128 * 128;
  float* bnp  = c1buf + (size_t)NB * 8 * 128 * 128;
  float* stats = bnp + 512;

  P4 sq4 = { Wq, Wk, Wv, Wo };
  transpose_qkvo_kernel<<<dim3(16, 16, 16), 256, 0, stream>>>(sq4, wsTall);
  transpose_bf16_kernel<<<dim3(64, 16, 4), 256, 0, stream>>>(W1, w1Tall, DD, FF_);
  transpose_bf16_kernel<<<dim3(16, 64, 4), 256, 0, stream>>>(W2, w2Tall, FF_, DD);

  embed_kernel<<<MTOT, 256, 0, stream>>>(fbp, coords, emb_w, emb_b, hb);

  const int npass = (mode >= 1) ? 1 : 4;
  const int NBH = (mode >= 1) ? 32 : 8;
  const int Mrows = (mode >= 1) ? MTOT : SS;

  for (int i = 0; i < LL; ++i) {
    const unsigned short* wsT = wsTall + (size_t)i * 4 * DD * DD;
    const unsigned short* w1T = w1Tall + (size_t)i * DD * FF_;
    const unsigned short* w2T = w2Tall + (size_t)i * DD * FF_;

    for (int p = 0; p < npass; ++p) {
      unsigned short* hbp = hb + (size_t)p * SS * DD;
      gemm_qkv_kernel<<<dim3(12, Mrows / 128), 256, 0, stream>>>(
          hbp, wsT, bq + (size_t)i * DD, bk + (size_t)i * DD, bv + (size_t)i * DD,
          qb_, kb_, vb_);
      kv_part_kernel<<<dim3(13, NBH), 256, 0, stream>>>(kb_, vb_, kvp, ksp);
      kv_reduce_kernel<<<(NBH * 4096 + NBH * 64 + 255) / 256, 256, 0, stream>>>(kvp, ksp, kvT, ksum, NBH);
      attn_kernel<<<dim3(65, NBH), 256, 0, stream>>>(qb_, kvT, ksum);
      gemm_kernel<0, 1><<<dim3(4, Mrows / 128), 256, 0, stream>>>(
          qb_, wsT + (size_t)3 * DD * DD, bo + (size_t)i * DD, hbp, DD, DD, DD, DD);
      ln_wave_kernel<<<Mrows / 4, 256, 0, stream>>>(hbp, ln1g + (size_t)i * DD, ln1b + (size_t)i * DD);

      if (mode == 2) {
        gemm_kernel<2, 0><<<dim3(16, MTOT / 128), 256, 0, stream>>>(
            hb, w1T, b1 + (size_t)i * FF_, y1ded, FF_, DD, DD, DD);
        gemm_kernel<0, 1><<<dim3(4, MTOT / 128), 256, 0, stream>>>(
            y1ded, w2T, b2 + (size_t)i * DD, hb, DD, FF_, FF_, FF_);
      } else if (mode == 1) {
        unsigned short* y1half = qb_;   // overlays qb_+kb_ (both dead here)
        for (int g2 = 0; g2 < 2; ++g2) {
          unsigned short* hbg = hb + (size_t)g2 * 2 * SS * DD;
          gemm_kernel<2, 0><<<dim3(16, 2 * SS / 128), 256, 0, stream>>>(
              hbg, w1T, b1 + (size_t)i * FF_, y1half, FF_, DD, DD, DD);
          gemm_kernel<0, 1><<<dim3(4, 2 * SS / 128), 256, 0, stream>>>(
              y1half, w2T, b2 + (size_t)i * DD, hbg, DD, FF_, FF_, FF_);
        }
      } else {
        gemm_kernel<2, 0><<<dim3(16, SS / 128), 256, 0, stream>>>(
            hbp, w1T, b1 + (size_t)i * FF_, y1c, FF_, DD, DD, DD);
        gemm_kernel<0, 1><<<dim3(4, SS / 128), 256, 0, stream>>>(
            y1c, w2T, b2 + (size_t)i * DD, hbp, DD, FF_, FF_, FF_);
      }
      ln_wave_kernel<<<Mrows / 4, 256, 0, stream>>>(hbp, ln2g + (size_t)i * DD, ln2b + (size_t)i * DD);
    }
  }

  (void)hipMemsetAsync(dre, 0, (size_t)NB * SS * 4 * 2, stream);
  head_wave_kernel<<<MTOT / 4, 256, 0, stream>>>(hb, lnfg, lnfb, aw, ab, pw, pb,
                                                 mag_min, mag_max, atten, dstc,
                                                 (float*)d_out, dre, dimg);
  fftA_kernel<<<130, 256, 0, stream>>>(dre, dimg, tre, tim);
  fftB_kernel<<<256, 256, 0, stream>>>(tre, tim, img);
  conv1_kernel<<<2048, 256, 0, stream>>>(img, c1w, c1b, c1buf);
  bn_part_kernel<<<256, 256, 0, stream>>>(c1buf, bnp);
  bn_final_kernel<<<1, 256, 0, stream>>>(bnp, stats);
  conv2_kernel<<<256, 256, 0, stream>>>(c1buf, stats, bng, bnb, c2w, c2b, img,
                                        (float*)d_out + (size_t)MTOT * 2);
}

// Round 11
// 1911.618 us; speedup vs baseline: 1.1247x; 1.1247x over previous
//
#include <hip/hip_runtime.h>
#include <math.h>

#define NB 4
#define SS 8320
#define DD 512
#define NH_ 8
#define LL 4
#define FF_ 2048
#define MTOT (NB*SS)   // 33280

typedef __attribute__((ext_vector_type(8))) short short8;
typedef __attribute__((ext_vector_type(4))) float f32x4;

__device__ __forceinline__ unsigned short f2bf(float f){
  union { float f; unsigned int u; } x; x.f = f;
  unsigned int r = x.u + 0x7FFFu + ((x.u >> 16) & 1u);
  return (unsigned short)(r >> 16);
}
__device__ __forceinline__ float bf2f(unsigned short u){
  return __uint_as_float(((unsigned int)u) << 16);
}
__device__ __forceinline__ void gload_lds16(const void* g, void* l){
  __builtin_amdgcn_global_load_lds(
      (__attribute__((address_space(1))) void*)g,
      (__attribute__((address_space(3))) void*)l, 16, 0, 0);
}
__device__ __forceinline__ float wred(float v){
  #pragma unroll
  for (int o = 32; o; o >>= 1) v += __shfl_xor(v, o);
  return v;
}
__device__ __forceinline__ float block_sum256(float v){
  __shared__ float sb[4];
  #pragma unroll
  for (int o = 32; o; o >>= 1) v += __shfl_down(v, o);
  int w = threadIdx.x >> 6;
  __syncthreads();
  if ((threadIdx.x & 63) == 0) sb[w] = v;
  __syncthreads();
  return sb[0] + sb[1] + sb[2] + sb[3];
}

// bijective XCD-chunked block remap
__device__ __forceinline__ void xcd_remap(int& bn, int& bm)
{
  const int gx = gridDim.x;
  const int nblk = gx * gridDim.y;
  const int id = blockIdx.x + gx * blockIdx.y;
  const int qd = nblk >> 3, rd = nblk & 7;
  const int xcd = id & 7, pos = id >> 3;
  const int nid = (xcd < rd) ? (xcd * (qd + 1) + pos)
                             : (rd * (qd + 1) + (xcd - rd) * qd + pos);
  bn = nid % gx; bm = nid / gx;
}

// ---------------- batched weight transposes (K x N fp32 -> N x K bf16) -------
struct P4 { const float* p0; const float* p1; const float* p2; const float* p3; };

__global__ __launch_bounds__(256) void transpose_qkvo_kernel(P4 srcs, unsigned short* __restrict__ dst)
{
  __shared__ float tile[32][33];
  const int z = blockIdx.z;
  const int layer = z >> 2, m = z & 3;
  const float* base = (m == 0) ? srcs.p0 : (m == 1) ? srcs.p1 : (m == 2) ? srcs.p2 : srcs.p3;
  const float* src = base + (size_t)layer * DD * DD;
  unsigned short* d = dst + (size_t)z * DD * DD;
  const int n0 = blockIdx.x * 32, k0 = blockIdx.y * 32;
  const int tx = threadIdx.x & 31, ty = threadIdx.x >> 5;
  #pragma unroll
  for (int j = 0; j < 32; j += 8) tile[ty + j][tx] = src[(size_t)(k0 + ty + j) * DD + n0 + tx];
  __syncthreads();
  #pragma unroll
  for (int j = 0; j < 32; j += 8) d[(size_t)(n0 + ty + j) * DD + k0 + tx] = f2bf(tile[tx][ty + j]);
}

__global__ __launch_bounds__(256) void transpose_bf16_kernel(
    const float* __restrict__ src0, unsigned short* __restrict__ dst0, int K, int N)
{
  __shared__ float tile[32][33];
  const float* src = src0 + (size_t)blockIdx.z * K * N;
  unsigned short* dst = dst0 + (size_t)blockIdx.z * K * N;
  const int n0 = blockIdx.x * 32, k0 = blockIdx.y * 32;
  const int tx = threadIdx.x & 31, ty = threadIdx.x >> 5;
  #pragma unroll
  for (int j = 0; j < 32; j += 8) tile[ty + j][tx] = src[(size_t)(k0 + ty + j) * N + n0 + tx];
  __syncthreads();
  #pragma unroll
  for (int j = 0; j < 32; j += 8) dst[(size_t)(n0 + ty + j) * K + k0 + tx] = f2bf(tile[tx][ty + j]);
}

// ---------------- embedding + 2D sinusoidal PE ----------------
__global__ __launch_bounds__(256) void embed_kernel(
    const float* __restrict__ fbp, const int* __restrict__ coords,
    const float* __restrict__ emb_w, const float* __restrict__ emb_b,
    unsigned short* __restrict__ hb)
{
  const int row = blockIdx.x;
  const int c = threadIdx.x;
  const int s = row % SS;
  const float f0 = fbp[(size_t)row * 2], f1 = fbp[(size_t)row * 2 + 1];
  const float v0 = f0 * emb_w[c] + f1 * emb_w[256 + c] + emb_b[c];
  const int p = (c < 128) ? coords[s * 2 + 1] : coords[s * 2];
  const int c2 = c & 127;
  const int jj = c2 >> 1;
  const float dv = expf(-(float)(2 * jj) * (9.210340371976184f / 128.f));
  const float a = (float)p * dv;
  const float v1 = (c2 & 1) ? cosf(a) : sinf(a);
  const size_t base = (size_t)row * DD;
  hb[base + c] = f2bf(v0);
  hb[base + 256 + c] = f2bf(v1);
}

// ---------------- fused QKV GEMM, 128^2 tile, XCD-remapped ----------------
__global__ __launch_bounds__(256, 4) void gemm_qkv_kernel(
    const unsigned short* __restrict__ A,     // [M][512]
    const unsigned short* __restrict__ Bt,    // [1536][512]
    const float* __restrict__ bq_, const float* __restrict__ bk_, const float* __restrict__ bv_,
    unsigned short* __restrict__ qo, unsigned short* __restrict__ ko, unsigned short* __restrict__ vo)
{
  __shared__ __attribute__((aligned(16))) unsigned short As[128 * 64];
  __shared__ __attribute__((aligned(16))) unsigned short Bs[128 * 64];
  const int tid = threadIdx.x;
  const int lane = tid & 63, w = tid >> 6;
  const int lr = lane & 15, lg = lane >> 4;
  const int wm = w >> 1, wn = w & 1;
  int bn, bm; xcd_remap(bn, bm);                 // bn 0..11
  const int which = bn >> 2;
  const unsigned short* Ag = A + (size_t)bm * 128 * DD;
  const unsigned short* Bg = Bt + (size_t)bn * 128 * DD;
  unsigned short* out = (which == 0) ? qo : (which == 1) ? ko : vo;
  const float* bias = (which == 0) ? bq_ : (which == 1) ? bk_ : bv_;
  f32x4 acc[4][4] = {};
  for (int kt = 0; kt < 8; ++kt) {
    if (kt) __syncthreads();
    const int kbase = kt << 6;
    #pragma unroll
    for (int i = 0; i < 4; ++i) {
      int cid = i * 256 + tid;
      int row = cid >> 3, c = cid & 7;
      gload_lds16(Ag + (size_t)row * DD + kbase + ((c ^ (row & 7)) << 3), (void*)(As + cid * 8));
    }
    #pragma unroll
    for (int i = 0; i < 4; ++i) {
      int cid = i * 256 + tid;
      int row = cid >> 3, c = cid & 7;
      gload_lds16(Bg + (size_t)row * DD + kbase + ((c ^ (row & 7)) << 3), (void*)(Bs + cid * 8));
    }
    __syncthreads();
    #pragma unroll
    for (int kk = 0; kk < 2; ++kk) {
      short8 af[4], bfv[4];
      #pragma unroll
      for (int f = 0; f < 4; ++f) {
        int row = wm * 64 + f * 16 + lr;
        af[f] = *(const short8*)(As + row * 64 + (((kk * 4 + lg) ^ (row & 7)) << 3));
      }
      #pragma unroll
      for (int f = 0; f < 4; ++f) {
        int row = wn * 64 + f * 16 + lr;
        bfv[f] = *(const short8*)(Bs + row * 64 + (((kk * 4 + lg) ^ (row & 7)) << 3));
      }
      #pragma unroll
      for (int fm = 0; fm < 4; ++fm)
        #pragma unroll
        for (int fn = 0; fn < 4; ++fn)
          acc[fm][fn] = __builtin_amdgcn_mfma_f32_16x16x32_bf16(af[fm], bfv[fn], acc[fm][fn], 0, 0, 0);
    }
  }
  const int elu = (which < 2);
  #pragma unroll
  for (int fm = 0; fm < 4; ++fm) {
    const int row0 = bm * 128 + wm * 64 + fm * 16 + lg * 4;
    #pragma unroll
    for (int fn = 0; fn < 4; ++fn) {
      const int col = (bn & 3) * 128 + wn * 64 + fn * 16 + lr;
      const float bv = bias[col];
      #pragma unroll
      for (int r = 0; r < 4; ++r) {
        float v = acc[fm][fn][r] + bv;
        if (elu) v = (v > 0.f) ? (v + 1.f) : expf(v);
        out[(size_t)(row0 + r) * DD + col] = f2bf(v);
      }
    }
  }
}

// ---------------- generic GEMM (no residual), XCD-remapped ----------------
// ACT: 0=none 2=relu
template<int ACT>
__global__ __launch_bounds__(256, 4) void gemm_kernel(
    const unsigned short* __restrict__ A,
    const unsigned short* __restrict__ Bt,
    const float* __restrict__ bias,
    unsigned short* __restrict__ C,
    int N, int K, int lda, int ldb)
{
  __shared__ __attribute__((aligned(16))) unsigned short As[128 * 64];
  __shared__ __attribute__((aligned(16))) unsigned short Bs[128 * 64];
  const int tid = threadIdx.x;
  const int lane = tid & 63, w = tid >> 6;
  const int lr = lane & 15, lg = lane >> 4;
  const int wm = w >> 1, wn = w & 1;
  int bn, bm; xcd_remap(bn, bm);
  const unsigned short* Ag = A + (size_t)bm * 128 * lda;
  const unsigned short* Bg = Bt + (size_t)bn * 128 * ldb;
  f32x4 acc[4][4] = {};
  const int nkt = K >> 6;
  for (int kt = 0; kt < nkt; ++kt) {
    if (kt) __syncthreads();
    const int kbase = kt << 6;
    #pragma unroll
    for (int i = 0; i < 4; ++i) {
      int cid = i * 256 + tid;
      int row = cid >> 3, c = cid & 7;
      gload_lds16(Ag + (size_t)row * lda + kbase + ((c ^ (row & 7)) << 3), (void*)(As + cid * 8));
    }
    #pragma unroll
    for (int i = 0; i < 4; ++i) {
      int cid = i * 256 + tid;
      int row = cid >> 3, c = cid & 7;
      gload_lds16(Bg + (size_t)row * ldb + kbase + ((c ^ (row & 7)) << 3), (void*)(Bs + cid * 8));
    }
    __syncthreads();
    #pragma unroll
    for (int kk = 0; kk < 2; ++kk) {
      short8 af[4], bfv[4];
      #pragma unroll
      for (int f = 0; f < 4; ++f) {
        int row = wm * 64 + f * 16 + lr;
        af[f] = *(const short8*)(As + row * 64 + (((kk * 4 + lg) ^ (row & 7)) << 3));
      }
      #pragma unroll
      for (int f = 0; f < 4; ++f) {
        int row = wn * 64 + f * 16 + lr;
        bfv[f] = *(const short8*)(Bs + row * 64 + (((kk * 4 + lg) ^ (row & 7)) << 3));
      }
      #pragma unroll
      for (int fm = 0; fm < 4; ++fm)
        #pragma unroll
        for (int fn = 0; fn < 4; ++fn)
          acc[fm][fn] = __builtin_amdgcn_mfma_f32_16x16x32_bf16(af[fm], bfv[fn], acc[fm][fn], 0, 0, 0);
    }
  }
  #pragma unroll
  for (int fm = 0; fm < 4; ++fm) {
    const int row0 = bm * 128 + wm * 64 + fm * 16 + lg * 4;
    #pragma unroll
    for (int fn = 0; fn < 4; ++fn) {
      const int col = bn * 128 + wn * 64 + fn * 16 + lr;
      const float bv = bias[col];
      #pragma unroll
      for (int r = 0; r < 4; ++r) {
        float v = acc[fm][fn][r] + bv;
        if (ACT == 2) v = (v > 0.f) ? v : 0.f;
        C[(size_t)(row0 + r) * N + col] = f2bf(v);
      }
    }
  }
}

// ---------------- residual GEMM (C += A@Bt^T + bias), no min-waves bound ----
__global__ __launch_bounds__(256) void gemm_res_kernel(
    const unsigned short* __restrict__ A,
    const unsigned short* __restrict__ Bt,
    const float* __restrict__ bias,
    unsigned short* __restrict__ C,
    int N, int K, int lda, int ldb)
{
  __shared__ __attribute__((aligned(16))) unsigned short As[128 * 64];
  __shared__ __attribute__((aligned(16))) unsigned short Bs[128 * 64];
  const int tid = threadIdx.x;
  const int lane = tid & 63, w = tid >> 6;
  const int lr = lane & 15, lg = lane >> 4;
  const int wm = w >> 1, wn = w & 1;
  int bn, bm; xcd_remap(bn, bm);
  const unsigned short* Ag = A + (size_t)bm * 128 * lda;
  const unsigned short* Bg = Bt + (size_t)bn * 128 * ldb;
  f32x4 acc[4][4] = {};
  const int nkt = K >> 6;
  for (int kt = 0; kt < nkt; ++kt) {
    if (kt) __syncthreads();
    const int kbase = kt << 6;
    #pragma unroll
    for (int i = 0; i < 4; ++i) {
      int cid = i * 256 + tid;
      int row = cid >> 3, c = cid & 7;
      gload_lds16(Ag + (size_t)row * lda + kbase + ((c ^ (row & 7)) << 3), (void*)(As + cid * 8));
    }
    #pragma unroll
    for (int i = 0; i < 4; ++i) {
      int cid = i * 256 + tid;
      int row = cid >> 3, c = cid & 7;
      gload_lds16(Bg + (size_t)row * ldb + kbase + ((c ^ (row & 7)) << 3), (void*)(Bs + cid * 8));
    }
    __syncthreads();
    #pragma unroll
    for (int kk = 0; kk < 2; ++kk) {
      short8 af[4], bfv[4];
      #pragma unroll
      for (int f = 0; f < 4; ++f) {
        int row = wm * 64 + f * 16 + lr;
        af[f] = *(const short8*)(As + row * 64 + (((kk * 4 + lg) ^ (row & 7)) << 3));
      }
      #pragma unroll
      for (int f = 0; f < 4; ++f) {
        int row = wn * 64 + f * 16 + lr;
        bfv[f] = *(const short8*)(Bs + row * 64 + (((kk * 4 + lg) ^ (row & 7)) << 3));
      }
      #pragma unroll
      for (int fm = 0; fm < 4; ++fm)
        #pragma unroll
        for (int fn = 0; fn < 4; ++fn)
          acc[fm][fn] = __builtin_amdgcn_mfma_f32_16x16x32_bf16(af[fm], bfv[fn], acc[fm][fn], 0, 0, 0);
    }
  }
  #pragma unroll
  for (int fm = 0; fm < 4; ++fm) {
    const int row0 = bm * 128 + wm * 64 + fm * 16 + lg * 4;
    #pragma unroll
    for (int fn = 0; fn < 4; ++fn) {
      const int col = bn * 128 + wn * 64 + fn * 16 + lr;
      const float bv = bias[col];
      #pragma unroll
      for (int r = 0; r < 4; ++r) {
        float v = acc[fm][fn][r] + bv;
        const size_t idx = (size_t)(row0 + r) * N + col;
        v += bf2f(C[idx]);
        C[idx] = f2bf(v);
      }
    }
  }
}

// ---------------- kv partials: 640-row chunks x (b,h) ----------------
__global__ __launch_bounds__(256) void kv_part_kernel(
    const unsigned short* __restrict__ kb, const unsigned short* __restrict__ vb,
    float* __restrict__ kvp, float* __restrict__ ksp)
{
  __shared__ __attribute__((aligned(16))) float Kc[128][64];
  __shared__ __attribute__((aligned(16))) float Vc[128][64];
  const int ch = blockIdx.x;
  const int bh = blockIdx.y;
  const int NBH = gridDim.y;
  const int b = bh >> 3, h = bh & 7;
  const int tid = threadIdx.x;
  const int d = tid >> 2, m0 = (tid & 3) << 4;
  f32x4 a0 = {}, a1 = {}, a2 = {}, a3 = {};
  float sk = 0.f;
  for (int t = 0; t < 5; ++t) {
    if (t) __syncthreads();
    const size_t roff = ((size_t)b * SS + ch * 640 + t * 128) * DD + h * 64;
    #pragma unroll
    for (int i = 0; i < 8; ++i) {
      int e4 = i * 256 + tid;
      int r = e4 >> 4, c4 = e4 & 15;
      ushort4 kq = *(const ushort4*)(kb + roff + (size_t)r * DD + c4 * 4);
      ushort4 vq = *(const ushort4*)(vb + roff + (size_t)r * DD + c4 * 4);
      f32x4 kf4 = { bf2f(kq.x), bf2f(kq.y), bf2f(kq.z), bf2f(kq.w) };
      f32x4 vf4 = { bf2f(vq.x), bf2f(vq.y), bf2f(vq.z), bf2f(vq.w) };
      *(f32x4*)&Kc[r][c4 * 4] = kf4;
      *(f32x4*)&Vc[r][c4 * 4] = vf4;
    }
    __syncthreads();
    for (int s2 = 0; s2 < 128; ++s2) {
      const float kd = Kc[s2][d];
      const f32x4* vp = (const f32x4*)&Vc[s2][m0];
      a0 += kd * vp[0]; a1 += kd * vp[1]; a2 += kd * vp[2]; a3 += kd * vp[3];
    }
    if (tid < 64) {
      for (int s2 = 0; s2 < 128; ++s2) sk += Kc[s2][tid];
    }
  }
  float* ko = kvp + (((size_t)ch * NBH + bh) * 64 + d) * 64 + m0;
  *(f32x4*)(ko) = a0; *(f32x4*)(ko + 4) = a1; *(f32x4*)(ko + 8) = a2; *(f32x4*)(ko + 12) = a3;
  if (tid < 64) ksp[((size_t)ch * NBH + bh) * 64 + tid] = sk;
}

__global__ __launch_bounds__(256) void kv_reduce_kernel(
    const float* __restrict__ kvp, const float* __restrict__ ksp,
    unsigned short* __restrict__ kvT, float* __restrict__ ksum, int NBH)
{
  const int idx = blockIdx.x * 256 + threadIdx.x;
  const int nkv = NBH * 4096;
  if (idx < nkv) {
    const int bh = idx >> 12, dm = idx & 4095;
    const int d = dm >> 6, m = dm & 63;
    float s = 0.f;
    #pragma unroll
    for (int c = 0; c < 13; ++c) s += kvp[(((size_t)c * NBH + bh) << 12) + dm];
    kvT[(size_t)bh * 4096 + m * 64 + d] = f2bf(s);
  } else if (idx < nkv + NBH * 64) {
    const int i2 = idx - nkv;
    const int bh = i2 >> 6, d = i2 & 63;
    float s = 0.f;
    #pragma unroll
    for (int c = 0; c < 13; ++c) s += ksp[((size_t)c * NBH + bh) * 64 + d];
    ksum[i2] = s;
  }
}

// ---------------- attn: z fused (all 256 threads) + (qf @ kv) * z, in-place -
__global__ __launch_bounds__(256) void attn_kernel(
    unsigned short* __restrict__ qb, const unsigned short* __restrict__ kvT,
    const float* __restrict__ ksum)
{
  __shared__ __attribute__((aligned(16))) unsigned short Qs[128 * 64];
  __shared__ __attribute__((aligned(16))) unsigned short Ks[64 * 64];
  __shared__ float zloc[128];
  const int st = blockIdx.x;
  const int bh = blockIdx.y;
  const int b = bh >> 3, h = bh & 7;
  const int tid = threadIdx.x, lane = tid & 63, w = tid >> 6;
  const int lr = lane & 15, lg = lane >> 4;
  const size_t row0 = (size_t)b * SS + st * 128;
  const unsigned short* Qg = qb + row0 * DD + h * 64;
  #pragma unroll
  for (int i = 0; i < 4; ++i) {
    int cid = i * 256 + tid;
    int r = cid >> 3, c = cid & 7;
    gload_lds16(Qg + (size_t)r * DD + ((c ^ (r & 7)) << 3), (void*)(Qs + cid * 8));
  }
  #pragma unroll
  for (int i = 0; i < 2; ++i) {
    int cid = i * 256 + tid;
    int r = cid >> 3, c = cid & 7;
    gload_lds16(kvT + (size_t)bh * 4096 + r * 64 + ((c ^ (r & 7)) << 3), (void*)(Ks + cid * 8));
  }
  __syncthreads();
  {
    const int row = tid >> 1, half = tid & 1;
    const float* ks = ksum + (size_t)bh * 64;
    float dot = 0.f;
    #pragma unroll
    for (int c0 = 0; c0 < 4; ++c0) {
      const int c = half * 4 + c0;
      short8 qv = *(const short8*)(Qs + row * 64 + ((c ^ (row & 7)) << 3));
      #pragma unroll
      for (int j = 0; j < 8; ++j) dot += bf2f((unsigned short)qv[j]) * ks[c * 8 + j];
    }
    dot += __shfl_xor(dot, 1);
    if (half == 0) zloc[row] = 1.f / (dot + 1e-6f);
  }
  __syncthreads();
  f32x4 acc[2][4] = {};
  #pragma unroll
  for (int kk = 0; kk < 2; ++kk) {
    short8 af[2], bfv[4];
    #pragma unroll
    for (int f = 0; f < 2; ++f) {
      int r = w * 32 + f * 16 + lr;
      af[f] = *(const short8*)(Qs + r * 64 + (((kk * 4 + lg) ^ (r & 7)) << 3));
    }
    #pragma unroll
    for (int f = 0; f < 4; ++f) {
      int r = f * 16 + lr;
      bfv[f] = *(const short8*)(Ks + r * 64 + (((kk * 4 + lg) ^ (r & 7)) << 3));
    }
    #pragma unroll
    for (int fm = 0; fm < 2; ++fm)
      #pragma unroll
      for (int fn = 0; fn < 4; ++fn)
        acc[fm][fn] = __builtin_amdgcn_mfma_f32_16x16x32_bf16(af[fm], bfv[fn], acc[fm][fn], 0, 0, 0);
  }
  #pragma unroll
  for (int fm = 0; fm < 2; ++fm) {
    #pragma unroll
    for (int r = 0; r < 4; ++r) {
      const int lrow = w * 32 + fm * 16 + lg * 4 + r;
      const size_t grow = row0 + lrow;
      const float zv = zloc[lrow];
      unsigned short* out = qb + grow * DD + h * 64;
      #pragma unroll
      for (int fn = 0; fn < 4; ++fn)
        out[fn * 16 + lr] = f2bf(acc[fm][fn][r] * zv);
    }
  }
}

// ---------------- wave-per-row LayerNorm, in-place bf16 ----------------
__global__ __launch_bounds__(256) void ln_wave_kernel(
    unsigned short* __restrict__ hb, const float* __restrict__ g, const float* __restrict__ bt)
{
  const int tid = threadIdx.x, wv = tid >> 6, ln = tid & 63;
  const size_t row = (size_t)blockIdx.x * 4 + wv;
  unsigned short* p = hb + row * DD + ln * 8;
  ushort4 u0 = *(const ushort4*)p;
  ushort4 u1 = *(const ushort4*)(p + 4);
  float x[8] = { bf2f(u0.x), bf2f(u0.y), bf2f(u0.z), bf2f(u0.w),
                 bf2f(u1.x), bf2f(u1.y), bf2f(u1.z), bf2f(u1.w) };
  float s = 0.f;
  #pragma unroll
  for (int i = 0; i < 8; ++i) s += x[i];
  const float mean = wred(s) * (1.f / DD);
  float sq = 0.f;
  #pragma unroll
  for (int i = 0; i < 8; ++i) { const float d = x[i] - mean; sq += d * d; }
  const float rstd = rsqrtf(wred(sq) * (1.f / DD) + 1e-5f);
  const float4 g0 = *(const float4*)(g + ln * 8), g1 = *(const float4*)(g + ln * 8 + 4);
  const float4 b0 = *(const float4*)(bt + ln * 8), b1 = *(const float4*)(bt + ln * 8 + 4);
  const float gg[8] = { g0.x, g0.y, g0.z, g0.w, g1.x, g1.y, g1.z, g1.w };
  const float bb[8] = { b0.x, b0.y, b0.z, b0.w, b1.x, b1.y, b1.z, b1.w };
  ushort4 o0, o1;
  o0.x = f2bf((x[0] - mean) * rstd * gg[0] + bb[0]);
  o0.y = f2bf((x[1] - mean) * rstd * gg[1] + bb[1]);
  o0.z = f2bf((x[2] - mean) * rstd * gg[2] + bb[2]);
  o0.w = f2bf((x[3] - mean) * rstd * gg[3] + bb[3]);
  o1.x = f2bf((x[4] - mean) * rstd * gg[4] + bb[4]);
  o1.y = f2bf((x[5] - mean) * rstd * gg[5] + bb[5]);
  o1.z = f2bf((x[6] - mean) * rstd * gg[6] + bb[6]);
  o1.w = f2bf((x[7] - mean) * rstd * gg[7] + bb[7]);
  *(ushort4*)p = o0;
  *(ushort4*)(p + 4) = o1;
}

// ---------------- wave-per-row final LN + heads + DFT scatter ----------------
__global__ __launch_bounds__(256) void head_wave_kernel(
    const unsigned short* __restrict__ hb,
    const float* __restrict__ lg_, const float* __restrict__ lb_,
    const float* __restrict__ aw, const float* __restrict__ ab,
    const float* __restrict__ pw, const float* __restrict__ pb,
    const float* __restrict__ mag_min, const float* __restrict__ mag_max,
    const float* __restrict__ atten, const int* __restrict__ dst,
    float* __restrict__ yhat, float* __restrict__ dre, float* __restrict__ dimg)
{
  const int tid = threadIdx.x, wv = tid >> 6, ln = tid & 63;
  const size_t row = (size_t)blockIdx.x * 4 + wv;
  const unsigned short* p = hb + row * DD + ln * 8;
  ushort4 u0 = *(const ushort4*)p;
  ushort4 u1 = *(const ushort4*)(p + 4);
  float x[8] = { bf2f(u0.x), bf2f(u0.y), bf2f(u0.z), bf2f(u0.w),
                 bf2f(u1.x), bf2f(u1.y), bf2f(u1.z), bf2f(u1.w) };
  float s = 0.f;
  #pragma unroll
  for (int i = 0; i < 8; ++i) s += x[i];
  const float mean = wred(s) * (1.f / DD);
  float sq = 0.f;
  #pragma unroll
  for (int i = 0; i < 8; ++i) { const float d = x[i] - mean; sq += d * d; }
  const float rstd = rsqrtf(wred(sq) * (1.f / DD) + 1e-5f);
  float ad = 0.f, pd = 0.f;
  #pragma unroll
  for (int i = 0; i < 8; ++i) {
    const float y = (x[i] - mean) * rstd * lg_[ln * 8 + i] + lb_[ln * 8 + i];
    ad += y * aw[ln * 8 + i];
    pd += y * pw[ln * 8 + i];
  }
  ad = wred(ad); pd = wred(pd);
  if (ln == 0) {
    const float ya = ad + ab[0];
    const float yp = tanhf(pd + pb[0]);
    yhat[row * 2] = ya;
    yhat[row * 2 + 1] = yp;
    const int b = (int)(row / SS), s2 = (int)(row % SS);
    const float amp = expf((ya + 1.f) * 0.5f * (mag_max[0] - mag_min[0]) + mag_min[0]);
    const float phi = yp * 3.14159265358979323846f;
    const int j = dst[s2];
    const float at = atten[j];
    dre[(size_t)b * SS + j] = amp * cosf(phi) * at;
    dimg[(size_t)b * SS + j] = amp * sinf(phi) * at;
  }
}

// ---------------- iDFT stage A ----------------
__global__ __launch_bounds__(256) void fftA_kernel(
    const float* __restrict__ dre, const float* __restrict__ dimg,
    float* __restrict__ tre, float* __restrict__ tim)
{
  __shared__ float ct[128], st[128];
  const int tid = threadIdx.x;
  if (tid < 128) {
    float a = (float)tid * (3.14159265358979323846f / 64.f);
    ct[tid] = cosf(a); st[tid] = sinf(a);
  }
  __syncthreads();
  const int idx = blockIdx.x * 256 + tid;
  const int v = idx % 65;
  const int y = (idx / 65) & 127;
  const int b = idx / (65 * 128);
  const float* pr = dre + (size_t)b * SS + v;
  const float* pi = dimg + (size_t)b * SS + v;
  float ar = 0.f, ai = 0.f;
  for (int u = 0; u < 128; ++u) {
    int t2 = (u * y) & 127;
    float cr = ct[t2], si = st[t2];
    float xr = pr[(size_t)u * 65], xi = pi[(size_t)u * 65];
    ar += xr * cr - xi * si;
    ai += xr * si + xi * cr;
  }
  tre[idx] = ar * (1.f / 128.f);
  tim[idx] = ai * (1.f / 128.f);
}

// ---------------- iDFT stage B ----------------
__global__ __launch_bounds__(256) void fftB_kernel(
    const float* __restrict__ tre, const float* __restrict__ tim,
    float* __restrict__ img)
{
  __shared__ float ct[128], st[128];
  const int tid = threadIdx.x;
  if (tid < 128) {
    float a = (float)tid * (3.14159265358979323846f / 64.f);
    ct[tid] = cosf(a); st[tid] = sinf(a);
  }
  __syncthreads();
  const int idx = blockIdx.x * 256 + tid;
  const int x = idx & 127;
  const int y = (idx >> 7) & 127;
  const int b = idx >> 14;
  const float* pr = tre + ((size_t)b * 128 + y) * 65;
  const float* pi = tim + ((size_t)b * 128 + y) * 65;
  float a2 = pr[0] + ((x & 1) ? -pr[64] : pr[64]);
  for (int v = 1; v < 64; ++v) {
    int t2 = (v * x) & 127;
    a2 += 2.f * (pr[v] * ct[t2] - pi[v] * st[t2]);
  }
  a2 *= (1.f / 128.f);
  const int yy = (y + 64) & 127, xx = (x + 64) & 127;
  img[((size_t)b << 14) + (yy << 7) + xx] = a2;
}

// ---------------- conv 3x3 (1->8) + relu ----------------
__global__ __launch_bounds__(256) void conv1_kernel(
    const float* __restrict__ img, const float* __restrict__ w,
    const float* __restrict__ bi, float* __restrict__ c1)
{
  const int idx = blockIdx.x * 256 + threadIdx.x;
  const int x = idx & 127, y = (idx >> 7) & 127, ch = (idx >> 14) & 7, b = idx >> 17;
  const float* ip = img + ((size_t)b << 14);
  const float* wp = w + ch * 9;
  float acc = bi[ch];
  #pragma unroll
  for (int dy = -1; dy <= 1; ++dy) {
    const int yy = y + dy;
    if (yy < 0 || yy > 127) continue;
    #pragma unroll
    for (int dx = -1; dx <= 1; ++dx) {
      const int xx = x + dx;
      if (xx < 0 || xx > 127) continue;
      acc += ip[(yy << 7) + xx] * wp[(dy + 1) * 3 + (dx + 1)];
    }
  }
  c1[idx] = acc > 0.f ? acc : 0.f;
}

// ---------------- BN stats: two-stage ----------------
__global__ __launch_bounds__(256) void bn_part_kernel(
    const float* __restrict__ c1, float* __restrict__ bnp)
{
  const int ch = blockIdx.x >> 5, sl = blockIdx.x & 31;
  const int tid = threadIdx.x;
  const int n = sl * 2048 + tid * 8;
  const int b = n >> 14, i = n & 16383;
  const float* p = c1 + (((size_t)b * 8 + ch) << 14) + i;
  float4 a0 = *(const float4*)p, a1 = *(const float4*)(p + 4);
  float s = a0.x + a0.y + a0.z + a0.w + a1.x + a1.y + a1.z + a1.w;
  float sq = a0.x*a0.x + a0.y*a0.y + a0.z*a0.z + a0.w*a0.w
           + a1.x*a1.x + a1.y*a1.y + a1.z*a1.z + a1.w*a1.w;
  s = block_sum256(s);
  sq = block_sum256(sq);
  if (tid == 0) { bnp[blockIdx.x] = s; bnp[256 + blockIdx.x] = sq; }
}

__global__ __launch_bounds__(256) void bn_final_kernel(
    const float* __restrict__ bnp, float* __restrict__ stats)
{
  const int t = threadIdx.x;
  float s = bnp[t], sq = bnp[256 + t];
  #pragma unroll
  for (int o = 16; o; o >>= 1) { s += __shfl_down(s, o, 32); sq += __shfl_down(sq, o, 32); }
  if ((t & 31) == 0) {
    const int ch = t >> 5;
    const float m = s * (1.f / 65536.f);
    const float var = sq * (1.f / 65536.f) - m * m;
    stats[ch] = m;
    stats[8 + ch] = rsqrtf(var + 1e-5f);
  }
}

__global__ __launch_bounds__(256) void conv2_kernel(
    const float* __restrict__ c1, const float* __restrict__ stats,
    const float* __restrict__ bng, const float* __restrict__ bnb,
    const float* __restrict__ w2, const float* __restrict__ b2,
    const float* __restrict__ img, float* __restrict__ out)
{
  const int idx = blockIdx.x * 256 + threadIdx.x;
  const int b = idx >> 14, sp = idx & 16383;
  float acc = b2[0];
  #pragma unroll
  for (int ch = 0; ch < 8; ++ch) {
    float v = c1[(((size_t)b * 8 + ch) << 14) + sp];
    v = (v - stats[ch]) * stats[8 + ch] * bng[ch] + bnb[ch];
    acc += v * w2[ch];
  }
  out[idx] = acc + img[idx];
}

extern "C" void kernel_launch(void* const* d_in, const int* in_sizes, int n_in,
                              void* d_out, int out_size, void* d_ws, size_t ws_size,
                              hipStream_t stream)
{
  (void)in_sizes; (void)n_in; (void)out_size;
  const float* fbp = (const float*)d_in[1];
  const float* mag_min = (const float*)d_in[2];
  const float* mag_max = (const float*)d_in[3];
  const float* atten = (const float*)d_in[4];
  const int* coords = (const int*)d_in[5];
  const int* dstc = (const int*)d_in[6];
  const float* emb_w = (const float*)d_in[8];
  const float* emb_b = (const float*)d_in[9];
  const float* Wq = (const float*)d_in[10]; const float* bq = (const float*)d_in[11];
  const float* Wk = (const float*)d_in[12]; const float* bk = (const float*)d_in[13];
  const float* Wv = (const float*)d_in[14]; const float* bv = (const float*)d_in[15];
  const float* Wo = (const float*)d_in[16]; const float* bo = (const float*)d_in[17];
  const float* ln1g = (const float*)d_in[18]; const float* ln1b = (const float*)d_in[19];
  const float* W1 = (const float*)d_in[20]; const float* b1 = (const float*)d_in[21];
  const float* W2 = (const float*)d_in[22]; const float* b2 = (const float*)d_in[23];
  const float* ln2g = (const float*)d_in[24]; const float* ln2b = (const float*)d_in[25];
  const float* lnfg = (const float*)d_in[26]; const float* lnfb = (const float*)d_in[27];
  const float* aw = (const float*)d_in[28]; const float* ab = (const float*)d_in[29];
  const float* pw = (const float*)d_in[30]; const float* pb = (const float*)d_in[31];
  const float* c1w = (const float*)d_in[32]; const float* c1b = (const float*)d_in[33];
  const float* bng = (const float*)d_in[34]; const float* bnb = (const float*)d_in[35];
  const float* c2w = (const float*)d_in[36]; const float* c2b = (const float*)d_in[37];

  auto rnd = [](size_t b_) { return (b_ + 255) & ~(size_t)255; };
  const size_t SZ_M    = rnd((size_t)MTOT * DD * 2);            // 34.08 MB
  const size_t SZ_Y1   = rnd((size_t)MTOT * FF_ * 2);           // 136.3 MB
  const size_t SZ_WQKVO= rnd((size_t)LL * 4 * DD * DD * 2);
  const size_t SZ_W12  = rnd((size_t)LL * DD * FF_ * 2);
  const size_t SZ_WALL = SZ_WQKVO + 2 * SZ_W12;
  const size_t NEED_FULL = SZ_WALL + 4 * SZ_M + rnd((size_t)13*32*4096*4) + rnd((size_t)13*32*64*4) +
                           rnd((size_t)32*4096*2) + rnd((size_t)32*64*4) + 4096;
  const size_t NEED_FULLY = NEED_FULL + SZ_Y1;
  const size_t NEED_FB = SZ_WALL + SZ_M + rnd((size_t)SS*DD*2) + rnd((size_t)SS*FF_*2) +
                         rnd((size_t)8*4096*2) + rnd((size_t)8*64*4) + 4096;
  const int mode = (ws_size >= NEED_FULLY) ? 2 : (ws_size >= NEED_FULL) ? 1 : 0;
  if (mode == 0 && ws_size < NEED_FB) return;

  char* wsp = (char*)d_ws;
  size_t off = 0;
  auto alloc = [&](size_t bytes) -> char* { char* p = wsp + off; off += rnd(bytes); return p; };

  unsigned short* wsTall = (unsigned short*)alloc((size_t)LL * 4 * DD * DD * 2);
  unsigned short* w1Tall = (unsigned short*)alloc((size_t)LL * DD * FF_ * 2);
  unsigned short* w2Tall = (unsigned short*)alloc((size_t)LL * DD * FF_ * 2);

  unsigned short *hb, *qb_, *kb_, *vb_, *y1c, *y1ded = nullptr, *kvT;
  float *kvp, *ksp, *ksum;
  if (mode >= 1) {
    hb  = (unsigned short*)alloc((size_t)MTOT * DD * 2);
    qb_ = (unsigned short*)alloc((size_t)MTOT * DD * 2);
    kb_ = (unsigned short*)alloc((size_t)MTOT * DD * 2);
    vb_ = (unsigned short*)alloc((size_t)MTOT * DD * 2);
    if (mode == 2) y1ded = (unsigned short*)alloc((size_t)MTOT * FF_ * 2);
    kvp = (float*)alloc((size_t)13 * 32 * 4096 * 4);
    ksp = (float*)alloc((size_t)13 * 32 * 64 * 4);
    kvT = (unsigned short*)alloc((size_t)32 * 4096 * 2);
    ksum = (float*)alloc((size_t)32 * 64 * 4);
    y1c = nullptr;
  } else {
    hb  = (unsigned short*)alloc((size_t)MTOT * DD * 2);
    qb_ = (unsigned short*)alloc((size_t)SS * DD * 2);
    unsigned short* uni = (unsigned short*)alloc((size_t)SS * FF_ * 2);
    kb_ = uni;
    vb_ = uni + (size_t)SS * DD;
    kvp = (float*)(uni + 2 * (size_t)SS * DD);
    ksp = kvp + (size_t)13 * 8 * 4096;
    kvT = (unsigned short*)alloc((size_t)8 * 4096 * 2);
    ksum = (float*)alloc((size_t)8 * 64 * 4);
    y1c = uni;
  }

  // FFT/conv overlay inside qb_ (dead after the final layer's o-proj)
  float* dre  = (float*)qb_;
  float* dimg = dre + (size_t)NB * SS;
  float* tre  = dimg + (size_t)NB * SS;
  float* tim  = tre + (size_t)NB * 128 * 65;
  float* img  = tim + (size_t)NB * 128 * 65;
  float* c1buf = img + (size_t)NB * 128 * 128;
  float* bnp  = c1buf + (size_t)NB * 8 * 128 * 128;
  float* stats = bnp + 512;

  P4 sq4 = { Wq, Wk, Wv, Wo };
  transpose_qkvo_kernel<<<dim3(16, 16, 16), 256, 0, stream>>>(sq4, wsTall);
  transpose_bf16_kernel<<<dim3(64, 16, 4), 256, 0, stream>>>(W1, w1Tall, DD, FF_);
  transpose_bf16_kernel<<<dim3(16, 64, 4), 256, 0, stream>>>(W2, w2Tall, FF_, DD);

  embed_kernel<<<MTOT, 256, 0, stream>>>(fbp, coords, emb_w, emb_b, hb);

  const int npass = (mode >= 1) ? 1 : 4;
  const int NBH = (mode >= 1) ? 32 : 8;
  const int Mrows = (mode >= 1) ? MTOT : SS;

  for (int i = 0; i < LL; ++i) {
    const unsigned short* wsT = wsTall + (size_t)i * 4 * DD * DD;
    const unsigned short* w1T = w1Tall + (size_t)i * DD * FF_;
    const unsigned short* w2T = w2Tall + (size_t)i * DD * FF_;

    for (int p = 0; p < npass; ++p) {
      unsigned short* hbp = hb + (size_t)p * SS * DD;
      gemm_qkv_kernel<<<dim3(12, Mrows / 128), 256, 0, stream>>>(
          hbp, wsT, bq + (size_t)i * DD, bk + (size_t)i * DD, bv + (size_t)i * DD,
          qb_, kb_, vb_);
      kv_part_kernel<<<dim3(13, NBH), 256, 0, stream>>>(kb_, vb_, kvp, ksp);
      kv_reduce_kernel<<<(NBH * 4096 + NBH * 64 + 255) / 256, 256, 0, stream>>>(kvp, ksp, kvT, ksum, NBH);
      attn_kernel<<<dim3(65, NBH), 256, 0, stream>>>(qb_, kvT, ksum);
      gemm_res_kernel<<<dim3(4, Mrows / 128), 256, 0, stream>>>(
          qb_, wsT + (size_t)3 * DD * DD, bo + (size_t)i * DD, hbp, DD, DD, DD, DD);
      ln_wave_kernel<<<Mrows / 4, 256, 0, stream>>>(hbp, ln1g + (size_t)i * DD, ln1b + (size_t)i * DD);

      if (mode == 2) {
        gemm_kernel<2><<<dim3(16, MTOT / 128), 256, 0, stream>>>(
            hb, w1T, b1 + (size_t)i * FF_, y1ded, FF_, DD, DD, DD);
        gemm_res_kernel<<<dim3(4, MTOT / 128), 256, 0, stream>>>(
            y1ded, w2T, b2 + (size_t)i * DD, hb, DD, FF_, FF_, FF_);
      } else if (mode == 1) {
        unsigned short* y1half = qb_;   // overlays qb_+kb_ (both dead here)
        for (int g2 = 0; g2 < 2; ++g2) {
          unsigned short* hbg = hb + (size_t)g2 * 2 * SS * DD;
          gemm_kernel<2><<<dim3(16, 2 * SS / 128), 256, 0, stream>>>(
              hbg, w1T, b1 + (size_t)i * FF_, y1half, FF_, DD, DD, DD);
          gemm_res_kernel<<<dim3(4, 2 * SS / 128), 256, 0, stream>>>(
              y1half, w2T, b2 + (size_t)i * DD, hbg, DD, FF_, FF_, FF_);
        }
      } else {
        gemm_kernel<2><<<dim3(16, SS / 128), 256, 0, stream>>>(
            hbp, w1T, b1 + (size_t)i * FF_, y1c, FF_, DD, DD, DD);
        gemm_res_kernel<<<dim3(4, SS / 128), 256, 0, stream>>>(
            y1c, w2T, b2 + (size_t)i * DD, hbp, DD, FF_, FF_, FF_);
      }
      ln_wave_kernel<<<Mrows / 4, 256, 0, stream>>>(hbp, ln2g + (size_t)i * DD, ln2b + (size_t)i * DD);
    }
  }

  (void)hipMemsetAsync(dre, 0, (size_t)NB * SS * 4 * 2, stream);
  head_wave_kernel<<<MTOT / 4, 256, 0, stream>>>(hb, lnfg, lnfb, aw, ab, pw, pb,
                                                 mag_min, mag_max, atten, dstc,
                                                 (float*)d_out, dre, dimg);
  fftA_kernel<<<130, 256, 0, stream>>>(dre, dimg, tre, tim);
  fftB_kernel<<<256, 256, 0, stream>>>(tre, tim, img);
  conv1_kernel<<<2048, 256, 0, stream>>>(img, c1w, c1b, c1buf);
  bn_part_kernel<<<256, 256, 0, stream>>>(c1buf, bnp);
  bn_final_kernel<<<1, 256, 0, stream>>>(bnp, stats);
  conv2_kernel<<<256, 256, 0, stream>>>(c1buf, stats, bng, bnb, c2w, c2b, img,
                                        (float*)d_out + (size_t)MTOT * 2);
}

// Round 12
// 1899.709 us; speedup vs baseline: 1.1317x; 1.0063x over previous
//
#include <hip/hip_runtime.h>
#include <math.h>

#define NB 4
#define SS 8320
#define DD 512
#define NH_ 8
#define LL 4
#define FF_ 2048
#define MTOT (NB*SS)   // 33280

typedef __attribute__((ext_vector_type(8))) short short8;
typedef __attribute__((ext_vector_type(4))) float f32x4;

__device__ __forceinline__ unsigned short f2bf(float f){
  union { float f; unsigned int u; } x; x.f = f;
  unsigned int r = x.u + 0x7FFFu + ((x.u >> 16) & 1u);
  return (unsigned short)(r >> 16);
}
__device__ __forceinline__ float bf2f(unsigned short u){
  return __uint_as_float(((unsigned int)u) << 16);
}
__device__ __forceinline__ void gload_lds16(const void* g, void* l){
  __builtin_amdgcn_global_load_lds(
      (__attribute__((address_space(1))) void*)g,
      (__attribute__((address_space(3))) void*)l, 16, 0, 0);
}
__device__ __forceinline__ float wred(float v){
  #pragma unroll
  for (int o = 32; o; o >>= 1) v += __shfl_xor(v, o);
  return v;
}
__device__ __forceinline__ float block_sum256(float v){
  __shared__ float sb[4];
  #pragma unroll
  for (int o = 32; o; o >>= 1) v += __shfl_down(v, o);
  int w = threadIdx.x >> 6;
  __syncthreads();
  if ((threadIdx.x & 63) == 0) sb[w] = v;
  __syncthreads();
  return sb[0] + sb[1] + sb[2] + sb[3];
}

// bijective XCD-chunked block remap
__device__ __forceinline__ void xcd_remap(int& bn, int& bm)
{
  const int gx = gridDim.x;
  const int nblk = gx * gridDim.y;
  const int id = blockIdx.x + gx * blockIdx.y;
  const int qd = nblk >> 3, rd = nblk & 7;
  const int xcd = id & 7, pos = id >> 3;
  const int nid = (xcd < rd) ? (xcd * (qd + 1) + pos)
                             : (rd * (qd + 1) + (xcd - rd) * qd + pos);
  bn = nid % gx; bm = nid / gx;
}

// ---------------- batched weight transposes (K x N fp32 -> N x K bf16) -------
struct P4 { const float* p0; const float* p1; const float* p2; const float* p3; };

__global__ __launch_bounds__(256) void transpose_qkvo_kernel(P4 srcs, unsigned short* __restrict__ dst)
{
  __shared__ float tile[32][33];
  const int z = blockIdx.z;
  const int layer = z >> 2, m = z & 3;
  const float* base = (m == 0) ? srcs.p0 : (m == 1) ? srcs.p1 : (m == 2) ? srcs.p2 : srcs.p3;
  const float* src = base + (size_t)layer * DD * DD;
  unsigned short* d = dst + (size_t)z * DD * DD;
  const int n0 = blockIdx.x * 32, k0 = blockIdx.y * 32;
  const int tx = threadIdx.x & 31, ty = threadIdx.x >> 5;
  #pragma unroll
  for (int j = 0; j < 32; j += 8) tile[ty + j][tx] = src[(size_t)(k0 + ty + j) * DD + n0 + tx];
  __syncthreads();
  #pragma unroll
  for (int j = 0; j < 32; j += 8) d[(size_t)(n0 + ty + j) * DD + k0 + tx] = f2bf(tile[tx][ty + j]);
}

__global__ __launch_bounds__(256) void transpose_bf16_kernel(
    const float* __restrict__ src0, unsigned short* __restrict__ dst0, int K, int N)
{
  __shared__ float tile[32][33];
  const float* src = src0 + (size_t)blockIdx.z * K * N;
  unsigned short* dst = dst0 + (size_t)blockIdx.z * K * N;
  const int n0 = blockIdx.x * 32, k0 = blockIdx.y * 32;
  const int tx = threadIdx.x & 31, ty = threadIdx.x >> 5;
  #pragma unroll
  for (int j = 0; j < 32; j += 8) tile[ty + j][tx] = src[(size_t)(k0 + ty + j) * N + n0 + tx];
  __syncthreads();
  #pragma unroll
  for (int j = 0; j < 32; j += 8) dst[(size_t)(n0 + ty + j) * K + k0 + tx] = f2bf(tile[tx][ty + j]);
}

// ---------------- embedding + 2D sinusoidal PE ----------------
__global__ __launch_bounds__(256) void embed_kernel(
    const float* __restrict__ fbp, const int* __restrict__ coords,
    const float* __restrict__ emb_w, const float* __restrict__ emb_b,
    unsigned short* __restrict__ hb)
{
  const int row = blockIdx.x;
  const int c = threadIdx.x;
  const int s = row % SS;
  const float f0 = fbp[(size_t)row * 2], f1 = fbp[(size_t)row * 2 + 1];
  const float v0 = f0 * emb_w[c] + f1 * emb_w[256 + c] + emb_b[c];
  const int p = (c < 128) ? coords[s * 2 + 1] : coords[s * 2];
  const int c2 = c & 127;
  const int jj = c2 >> 1;
  const float dv = expf(-(float)(2 * jj) * (9.210340371976184f / 128.f));
  const float a = (float)p * dv;
  const float v1 = (c2 & 1) ? cosf(a) : sinf(a);
  const size_t base = (size_t)row * DD;
  hb[base + c] = f2bf(v0);
  hb[base + 256 + c] = f2bf(v1);
}

// ---------------- fused QKV GEMM, 128^2 tile, swapped-MFMA epilogue ----------
__global__ __launch_bounds__(256, 4) void gemm_qkv_kernel(
    const unsigned short* __restrict__ A,     // [M][512]
    const unsigned short* __restrict__ Bt,    // [1536][512]
    const float* __restrict__ bq_, const float* __restrict__ bk_, const float* __restrict__ bv_,
    unsigned short* __restrict__ qo, unsigned short* __restrict__ ko, unsigned short* __restrict__ vo)
{
  __shared__ __attribute__((aligned(16))) unsigned short As[128 * 64];
  __shared__ __attribute__((aligned(16))) unsigned short Bs[128 * 64];
  const int tid = threadIdx.x;
  const int lane = tid & 63, w = tid >> 6;
  const int lr = lane & 15, lg = lane >> 4;
  const int wm = w >> 1, wn = w & 1;
  int bn, bm; xcd_remap(bn, bm);                 // bn 0..11
  const int which = bn >> 2;
  const unsigned short* Ag = A + (size_t)bm * 128 * DD;
  const unsigned short* Bg = Bt + (size_t)bn * 128 * DD;
  unsigned short* out = (which == 0) ? qo : (which == 1) ? ko : vo;
  const float* bias = (which == 0) ? bq_ : (which == 1) ? bk_ : bv_;
  f32x4 acc[4][4] = {};   // [fm][fn]: row = fm*16+lr, cols = fn*16 + lg*4 + r
  for (int kt = 0; kt < 8; ++kt) {
    if (kt) __syncthreads();
    const int kbase = kt << 6;
    #pragma unroll
    for (int i = 0; i < 4; ++i) {
      int cid = i * 256 + tid;
      int row = cid >> 3, c = cid & 7;
      gload_lds16(Ag + (size_t)row * DD + kbase + ((c ^ (row & 7)) << 3), (void*)(As + cid * 8));
    }
    #pragma unroll
    for (int i = 0; i < 4; ++i) {
      int cid = i * 256 + tid;
      int row = cid >> 3, c = cid & 7;
      gload_lds16(Bg + (size_t)row * DD + kbase + ((c ^ (row & 7)) << 3), (void*)(Bs + cid * 8));
    }
    __syncthreads();
    #pragma unroll
    for (int kk = 0; kk < 2; ++kk) {
      short8 af[4], bfv[4];
      #pragma unroll
      for (int f = 0; f < 4; ++f) {
        int row = wm * 64 + f * 16 + lr;
        af[f] = *(const short8*)(As + row * 64 + (((kk * 4 + lg) ^ (row & 7)) << 3));
      }
      #pragma unroll
      for (int f = 0; f < 4; ++f) {
        int row = wn * 64 + f * 16 + lr;
        bfv[f] = *(const short8*)(Bs + row * 64 + (((kk * 4 + lg) ^ (row & 7)) << 3));
      }
      #pragma unroll
      for (int fm = 0; fm < 4; ++fm)
        #pragma unroll
        for (int fn = 0; fn < 4; ++fn)
          acc[fm][fn] = __builtin_amdgcn_mfma_f32_16x16x32_bf16(bfv[fn], af[fm], acc[fm][fn], 0, 0, 0);
    }
  }
  const int elu = (which < 2);
  #pragma unroll
  for (int fm = 0; fm < 4; ++fm) {
    const int row = bm * 128 + wm * 64 + fm * 16 + lr;
    #pragma unroll
    for (int fn = 0; fn < 4; ++fn) {
      const int colq = (bn & 3) * 128 + wn * 64 + fn * 16 + lg * 4;
      const float4 bv4 = *(const float4*)(bias + colq);
      float v0 = acc[fm][fn][0] + bv4.x;
      float v1 = acc[fm][fn][1] + bv4.y;
      float v2 = acc[fm][fn][2] + bv4.z;
      float v3 = acc[fm][fn][3] + bv4.w;
      if (elu) {
        v0 = (v0 > 0.f) ? (v0 + 1.f) : expf(v0);
        v1 = (v1 > 0.f) ? (v1 + 1.f) : expf(v1);
        v2 = (v2 > 0.f) ? (v2 + 1.f) : expf(v2);
        v3 = (v3 > 0.f) ? (v3 + 1.f) : expf(v3);
      }
      ushort4 o4 = { f2bf(v0), f2bf(v1), f2bf(v2), f2bf(v3) };
      *(ushort4*)(out + (size_t)row * DD + colq) = o4;
    }
  }
}

// ---------------- generic GEMM (no residual), swapped-MFMA epilogue ---------
// ACT: 0=none 2=relu
template<int ACT>
__global__ __launch_bounds__(256, 4) void gemm_kernel(
    const unsigned short* __restrict__ A,
    const unsigned short* __restrict__ Bt,
    const float* __restrict__ bias,
    unsigned short* __restrict__ C,
    int N, int K, int lda, int ldb)
{
  __shared__ __attribute__((aligned(16))) unsigned short As[128 * 64];
  __shared__ __attribute__((aligned(16))) unsigned short Bs[128 * 64];
  const int tid = threadIdx.x;
  const int lane = tid & 63, w = tid >> 6;
  const int lr = lane & 15, lg = lane >> 4;
  const int wm = w >> 1, wn = w & 1;
  int bn, bm; xcd_remap(bn, bm);
  const unsigned short* Ag = A + (size_t)bm * 128 * lda;
  const unsigned short* Bg = Bt + (size_t)bn * 128 * ldb;
  f32x4 acc[4][4] = {};
  const int nkt = K >> 6;
  for (int kt = 0; kt < nkt; ++kt) {
    if (kt) __syncthreads();
    const int kbase = kt << 6;
    #pragma unroll
    for (int i = 0; i < 4; ++i) {
      int cid = i * 256 + tid;
      int row = cid >> 3, c = cid & 7;
      gload_lds16(Ag + (size_t)row * lda + kbase + ((c ^ (row & 7)) << 3), (void*)(As + cid * 8));
    }
    #pragma unroll
    for (int i = 0; i < 4; ++i) {
      int cid = i * 256 + tid;
      int row = cid >> 3, c = cid & 7;
      gload_lds16(Bg + (size_t)row * ldb + kbase + ((c ^ (row & 7)) << 3), (void*)(Bs + cid * 8));
    }
    __syncthreads();
    #pragma unroll
    for (int kk = 0; kk < 2; ++kk) {
      short8 af[4], bfv[4];
      #pragma unroll
      for (int f = 0; f < 4; ++f) {
        int row = wm * 64 + f * 16 + lr;
        af[f] = *(const short8*)(As + row * 64 + (((kk * 4 + lg) ^ (row & 7)) << 3));
      }
      #pragma unroll
      for (int f = 0; f < 4; ++f) {
        int row = wn * 64 + f * 16 + lr;
        bfv[f] = *(const short8*)(Bs + row * 64 + (((kk * 4 + lg) ^ (row & 7)) << 3));
      }
      #pragma unroll
      for (int fm = 0; fm < 4; ++fm)
        #pragma unroll
        for (int fn = 0; fn < 4; ++fn)
          acc[fm][fn] = __builtin_amdgcn_mfma_f32_16x16x32_bf16(bfv[fn], af[fm], acc[fm][fn], 0, 0, 0);
    }
  }
  #pragma unroll
  for (int fm = 0; fm < 4; ++fm) {
    const int row = bm * 128 + wm * 64 + fm * 16 + lr;
    #pragma unroll
    for (int fn = 0; fn < 4; ++fn) {
      const int colq = bn * 128 + wn * 64 + fn * 16 + lg * 4;
      const float4 bv4 = *(const float4*)(bias + colq);
      float v0 = acc[fm][fn][0] + bv4.x;
      float v1 = acc[fm][fn][1] + bv4.y;
      float v2 = acc[fm][fn][2] + bv4.z;
      float v3 = acc[fm][fn][3] + bv4.w;
      if (ACT == 2) {
        v0 = v0 > 0.f ? v0 : 0.f;
        v1 = v1 > 0.f ? v1 : 0.f;
        v2 = v2 > 0.f ? v2 : 0.f;
        v3 = v3 > 0.f ? v3 : 0.f;
      }
      ushort4 o4 = { f2bf(v0), f2bf(v1), f2bf(v2), f2bf(v3) };
      *(ushort4*)(C + (size_t)row * N + colq) = o4;
    }
  }
}

// ---------------- residual GEMM (C += A@Bt^T + bias), vector epilogue -------
__global__ __launch_bounds__(256) void gemm_res_kernel(
    const unsigned short* __restrict__ A,
    const unsigned short* __restrict__ Bt,
    const float* __restrict__ bias,
    unsigned short* __restrict__ C,
    int N, int K, int lda, int ldb)
{
  __shared__ __attribute__((aligned(16))) unsigned short As[128 * 64];
  __shared__ __attribute__((aligned(16))) unsigned short Bs[128 * 64];
  const int tid = threadIdx.x;
  const int lane = tid & 63, w = tid >> 6;
  const int lr = lane & 15, lg = lane >> 4;
  const int wm = w >> 1, wn = w & 1;
  int bn, bm; xcd_remap(bn, bm);
  const unsigned short* Ag = A + (size_t)bm * 128 * lda;
  const unsigned short* Bg = Bt + (size_t)bn * 128 * ldb;
  f32x4 acc[4][4] = {};
  const int nkt = K >> 6;
  for (int kt = 0; kt < nkt; ++kt) {
    if (kt) __syncthreads();
    const int kbase = kt << 6;
    #pragma unroll
    for (int i = 0; i < 4; ++i) {
      int cid = i * 256 + tid;
      int row = cid >> 3, c = cid & 7;
      gload_lds16(Ag + (size_t)row * lda + kbase + ((c ^ (row & 7)) << 3), (void*)(As + cid * 8));
    }
    #pragma unroll
    for (int i = 0; i < 4; ++i) {
      int cid = i * 256 + tid;
      int row = cid >> 3, c = cid & 7;
      gload_lds16(Bg + (size_t)row * ldb + kbase + ((c ^ (row & 7)) << 3), (void*)(Bs + cid * 8));
    }
    __syncthreads();
    #pragma unroll
    for (int kk = 0; kk < 2; ++kk) {
      short8 af[4], bfv[4];
      #pragma unroll
      for (int f = 0; f < 4; ++f) {
        int row = wm * 64 + f * 16 + lr;
        af[f] = *(const short8*)(As + row * 64 + (((kk * 4 + lg) ^ (row & 7)) << 3));
      }
      #pragma unroll
      for (int f = 0; f < 4; ++f) {
        int row = wn * 64 + f * 16 + lr;
        bfv[f] = *(const short8*)(Bs + row * 64 + (((kk * 4 + lg) ^ (row & 7)) << 3));
      }
      #pragma unroll
      for (int fm = 0; fm < 4; ++fm)
        #pragma unroll
        for (int fn = 0; fn < 4; ++fn)
          acc[fm][fn] = __builtin_amdgcn_mfma_f32_16x16x32_bf16(bfv[fn], af[fm], acc[fm][fn], 0, 0, 0);
    }
  }
  #pragma unroll
  for (int fm = 0; fm < 4; ++fm) {
    const int row = bm * 128 + wm * 64 + fm * 16 + lr;
    #pragma unroll
    for (int fn = 0; fn < 4; ++fn) {
      const int colq = bn * 128 + wn * 64 + fn * 16 + lg * 4;
      const float4 bv4 = *(const float4*)(bias + colq);
      unsigned short* cp = C + (size_t)row * N + colq;
      const ushort4 r4 = *(const ushort4*)cp;
      ushort4 o4;
      o4.x = f2bf(acc[fm][fn][0] + bv4.x + bf2f(r4.x));
      o4.y = f2bf(acc[fm][fn][1] + bv4.y + bf2f(r4.y));
      o4.z = f2bf(acc[fm][fn][2] + bv4.z + bf2f(r4.z));
      o4.w = f2bf(acc[fm][fn][3] + bv4.w + bf2f(r4.w));
      *(ushort4*)cp = o4;
    }
  }
}

// ---------------- kv partials: 640-row chunks x (b,h) ----------------
__global__ __launch_bounds__(256) void kv_part_kernel(
    const unsigned short* __restrict__ kb, const unsigned short* __restrict__ vb,
    float* __restrict__ kvp, float* __restrict__ ksp)
{
  __shared__ __attribute__((aligned(16))) float Kc[128][64];
  __shared__ __attribute__((aligned(16))) float Vc[128][64];
  const int ch = blockIdx.x;
  const int bh = blockIdx.y;
  const int NBH = gridDim.y;
  const int b = bh >> 3, h = bh & 7;
  const int tid = threadIdx.x;
  const int d = tid >> 2, m0 = (tid & 3) << 4;
  f32x4 a0 = {}, a1 = {}, a2 = {}, a3 = {};
  float sk = 0.f;
  for (int t = 0; t < 5; ++t) {
    if (t) __syncthreads();
    const size_t roff = ((size_t)b * SS + ch * 640 + t * 128) * DD + h * 64;
    #pragma unroll
    for (int i = 0; i < 8; ++i) {
      int e4 = i * 256 + tid;
      int r = e4 >> 4, c4 = e4 & 15;
      ushort4 kq = *(const ushort4*)(kb + roff + (size_t)r * DD + c4 * 4);
      ushort4 vq = *(const ushort4*)(vb + roff + (size_t)r * DD + c4 * 4);
      f32x4 kf4 = { bf2f(kq.x), bf2f(kq.y), bf2f(kq.z), bf2f(kq.w) };
      f32x4 vf4 = { bf2f(vq.x), bf2f(vq.y), bf2f(vq.z), bf2f(vq.w) };
      *(f32x4*)&Kc[r][c4 * 4] = kf4;
      *(f32x4*)&Vc[r][c4 * 4] = vf4;
    }
    __syncthreads();
    for (int s2 = 0; s2 < 128; ++s2) {
      const float kd = Kc[s2][d];
      const f32x4* vp = (const f32x4*)&Vc[s2][m0];
      a0 += kd * vp[0]; a1 += kd * vp[1]; a2 += kd * vp[2]; a3 += kd * vp[3];
    }
    if (tid < 64) {
      for (int s2 = 0; s2 < 128; ++s2) sk += Kc[s2][tid];
    }
  }
  float* ko = kvp + (((size_t)ch * NBH + bh) * 64 + d) * 64 + m0;
  *(f32x4*)(ko) = a0; *(f32x4*)(ko + 4) = a1; *(f32x4*)(ko + 8) = a2; *(f32x4*)(ko + 12) = a3;
  if (tid < 64) ksp[((size_t)ch * NBH + bh) * 64 + tid] = sk;
}

__global__ __launch_bounds__(256) void kv_reduce_kernel(
    const float* __restrict__ kvp, const float* __restrict__ ksp,
    unsigned short* __restrict__ kvT, float* __restrict__ ksum, int NBH)
{
  const int idx = blockIdx.x * 256 + threadIdx.x;
  const int nkv = NBH * 4096;
  if (idx < nkv) {
    const int bh = idx >> 12, dm = idx & 4095;
    const int d = dm >> 6, m = dm & 63;
    float s = 0.f;
    #pragma unroll
    for (int c = 0; c < 13; ++c) s += kvp[(((size_t)c * NBH + bh) << 12) + dm];
    kvT[(size_t)bh * 4096 + m * 64 + d] = f2bf(s);
  } else if (idx < nkv + NBH * 64) {
    const int i2 = idx - nkv;
    const int bh = i2 >> 6, d = i2 & 63;
    float s = 0.f;
    #pragma unroll
    for (int c = 0; c < 13; ++c) s += ksp[((size_t)c * NBH + bh) * 64 + d];
    ksum[i2] = s;
  }
}

// ---------------- attn: z fused + (qf @ kv) * z, swapped-MFMA, in-place -----
__global__ __launch_bounds__(256) void attn_kernel(
    unsigned short* __restrict__ qb, const unsigned short* __restrict__ kvT,
    const float* __restrict__ ksum)
{
  __shared__ __attribute__((aligned(16))) unsigned short Qs[128 * 64];
  __shared__ __attribute__((aligned(16))) unsigned short Ks[64 * 64];
  __shared__ float zloc[128];
  const int st = blockIdx.x;
  const int bh = blockIdx.y;
  const int b = bh >> 3, h = bh & 7;
  const int tid = threadIdx.x, lane = tid & 63, w = tid >> 6;
  const int lr = lane & 15, lg = lane >> 4;
  const size_t row0 = (size_t)b * SS + st * 128;
  const unsigned short* Qg = qb + row0 * DD + h * 64;
  #pragma unroll
  for (int i = 0; i < 4; ++i) {
    int cid = i * 256 + tid;
    int r = cid >> 3, c = cid & 7;
    gload_lds16(Qg + (size_t)r * DD + ((c ^ (r & 7)) << 3), (void*)(Qs + cid * 8));
  }
  #pragma unroll
  for (int i = 0; i < 2; ++i) {
    int cid = i * 256 + tid;
    int r = cid >> 3, c = cid & 7;
    gload_lds16(kvT + (size_t)bh * 4096 + r * 64 + ((c ^ (r & 7)) << 3), (void*)(Ks + cid * 8));
  }
  __syncthreads();
  {
    const int row = tid >> 1, half = tid & 1;
    const float* ks = ksum + (size_t)bh * 64;
    float dot = 0.f;
    #pragma unroll
    for (int c0 = 0; c0 < 4; ++c0) {
      const int c = half * 4 + c0;
      short8 qv = *(const short8*)(Qs + row * 64 + ((c ^ (row & 7)) << 3));
      #pragma unroll
      for (int j = 0; j < 8; ++j) dot += bf2f((unsigned short)qv[j]) * ks[c * 8 + j];
    }
    dot += __shfl_xor(dot, 1);
    if (half == 0) zloc[row] = 1.f / (dot + 1e-6f);
  }
  __syncthreads();
  f32x4 acc[2][4] = {};   // [fm][fn]: row = w*32+fm*16+lr, cols = fn*16+lg*4+r
  #pragma unroll
  for (int kk = 0; kk < 2; ++kk) {
    short8 af[2], bfv[4];
    #pragma unroll
    for (int f = 0; f < 2; ++f) {
      int r = w * 32 + f * 16 + lr;
      af[f] = *(const short8*)(Qs + r * 64 + (((kk * 4 + lg) ^ (r & 7)) << 3));
    }
    #pragma unroll
    for (int f = 0; f < 4; ++f) {
      int r = f * 16 + lr;
      bfv[f] = *(const short8*)(Ks + r * 64 + (((kk * 4 + lg) ^ (r & 7)) << 3));
    }
    #pragma unroll
    for (int fm = 0; fm < 2; ++fm)
      #pragma unroll
      for (int fn = 0; fn < 4; ++fn)
        acc[fm][fn] = __builtin_amdgcn_mfma_f32_16x16x32_bf16(bfv[fn], af[fm], acc[fm][fn], 0, 0, 0);
  }
  #pragma unroll
  for (int fm = 0; fm < 2; ++fm) {
    const int lrow = w * 32 + fm * 16 + lr;
    const float zv = zloc[lrow];
    unsigned short* outp = qb + (row0 + lrow) * DD + h * 64;
    #pragma unroll
    for (int fn = 0; fn < 4; ++fn) {
      ushort4 o4;
      o4.x = f2bf(acc[fm][fn][0] * zv);
      o4.y = f2bf(acc[fm][fn][1] * zv);
      o4.z = f2bf(acc[fm][fn][2] * zv);
      o4.w = f2bf(acc[fm][fn][3] * zv);
      *(ushort4*)(outp + fn * 16 + lg * 4) = o4;
    }
  }
}

// ---------------- wave-per-row LayerNorm, in-place bf16 ----------------
__global__ __launch_bounds__(256) void ln_wave_kernel(
    unsigned short* __restrict__ hb, const float* __restrict__ g, const float* __restrict__ bt)
{
  const int tid = threadIdx.x, wv = tid >> 6, ln = tid & 63;
  const size_t row = (size_t)blockIdx.x * 4 + wv;
  unsigned short* p = hb + row * DD + ln * 8;
  ushort4 u0 = *(const ushort4*)p;
  ushort4 u1 = *(const ushort4*)(p + 4);
  float x[8] = { bf2f(u0.x), bf2f(u0.y), bf2f(u0.z), bf2f(u0.w),
                 bf2f(u1.x), bf2f(u1.y), bf2f(u1.z), bf2f(u1.w) };
  float s = 0.f;
  #pragma unroll
  for (int i = 0; i < 8; ++i) s += x[i];
  const float mean = wred(s) * (1.f / DD);
  float sq = 0.f;
  #pragma unroll
  for (int i = 0; i < 8; ++i) { const float d = x[i] - mean; sq += d * d; }
  const float rstd = rsqrtf(wred(sq) * (1.f / DD) + 1e-5f);
  const float4 g0 = *(const float4*)(g + ln * 8), g1 = *(const float4*)(g + ln * 8 + 4);
  const float4 b0 = *(const float4*)(bt + ln * 8), b1 = *(const float4*)(bt + ln * 8 + 4);
  const float gg[8] = { g0.x, g0.y, g0.z, g0.w, g1.x, g1.y, g1.z, g1.w };
  const float bb[8] = { b0.x, b0.y, b0.z, b0.w, b1.x, b1.y, b1.z, b1.w };
  ushort4 o0, o1;
  o0.x = f2bf((x[0] - mean) * rstd * gg[0] + bb[0]);
  o0.y = f2bf((x[1] - mean) * rstd * gg[1] + bb[1]);
  o0.z = f2bf((x[2] - mean) * rstd * gg[2] + bb[2]);
  o0.w = f2bf((x[3] - mean) * rstd * gg[3] + bb[3]);
  o1.x = f2bf((x[4] - mean) * rstd * gg[4] + bb[4]);
  o1.y = f2bf((x[5] - mean) * rstd * gg[5] + bb[5]);
  o1.z = f2bf((x[6] - mean) * rstd * gg[6] + bb[6]);
  o1.w = f2bf((x[7] - mean) * rstd * gg[7] + bb[7]);
  *(ushort4*)p = o0;
  *(ushort4*)(p + 4) = o1;
}

// ---------------- wave-per-row final LN + heads + DFT scatter ----------------
__global__ __launch_bounds__(256) void head_wave_kernel(
    const unsigned short* __restrict__ hb,
    const float* __restrict__ lg_, const float* __restrict__ lb_,
    const float* __restrict__ aw, const float* __restrict__ ab,
    const float* __restrict__ pw, const float* __restrict__ pb,
    const float* __restrict__ mag_min, const float* __restrict__ mag_max,
    const float* __restrict__ atten, const int* __restrict__ dst,
    float* __restrict__ yhat, float* __restrict__ dre, float* __restrict__ dimg)
{
  const int tid = threadIdx.x, wv = tid >> 6, ln = tid & 63;
  const size_t row = (size_t)blockIdx.x * 4 + wv;
  const unsigned short* p = hb + row * DD + ln * 8;
  ushort4 u0 = *(const ushort4*)p;
  ushort4 u1 = *(const ushort4*)(p + 4);
  float x[8] = { bf2f(u0.x), bf2f(u0.y), bf2f(u0.z), bf2f(u0.w),
                 bf2f(u1.x), bf2f(u1.y), bf2f(u1.z), bf2f(u1.w) };
  float s = 0.f;
  #pragma unroll
  for (int i = 0; i < 8; ++i) s += x[i];
  const float mean = wred(s) * (1.f / DD);
  float sq = 0.f;
  #pragma unroll
  for (int i = 0; i < 8; ++i) { const float d = x[i] - mean; sq += d * d; }
  const float rstd = rsqrtf(wred(sq) * (1.f / DD) + 1e-5f);
  float ad = 0.f, pd = 0.f;
  #pragma unroll
  for (int i = 0; i < 8; ++i) {
    const float y = (x[i] - mean) * rstd * lg_[ln * 8 + i] + lb_[ln * 8 + i];
    ad += y * aw[ln * 8 + i];
    pd += y * pw[ln * 8 + i];
  }
  ad = wred(ad); pd = wred(pd);
  if (ln == 0) {
    const float ya = ad + ab[0];
    const float yp = tanhf(pd + pb[0]);
    yhat[row * 2] = ya;
    yhat[row * 2 + 1] = yp;
    const int b = (int)(row / SS), s2 = (int)(row % SS);
    const float amp = expf((ya + 1.f) * 0.5f * (mag_max[0] - mag_min[0]) + mag_min[0]);
    const float phi = yp * 3.14159265358979323846f;
    const int j = dst[s2];
    const float at = atten[j];
    dre[(size_t)b * SS + j] = amp * cosf(phi) * at;
    dimg[(size_t)b * SS + j] = amp * sinf(phi) * at;
  }
}

// ---------------- iDFT stage A ----------------
__global__ __launch_bounds__(256) void fftA_kernel(
    const float* __restrict__ dre, const float* __restrict__ dimg,
    float* __restrict__ tre, float* __restrict__ tim)
{
  __shared__ float ct[128], st[128];
  const int tid = threadIdx.x;
  if (tid < 128) {
    float a = (float)tid * (3.14159265358979323846f / 64.f);
    ct[tid] = cosf(a); st[tid] = sinf(a);
  }
  __syncthreads();
  const int idx = blockIdx.x * 256 + tid;
  const int v = idx % 65;
  const int y = (idx / 65) & 127;
  const int b = idx / (65 * 128);
  const float* pr = dre + (size_t)b * SS + v;
  const float* pi = dimg + (size_t)b * SS + v;
  float ar = 0.f, ai = 0.f;
  for (int u = 0; u < 128; ++u) {
    int t2 = (u * y) & 127;
    float cr = ct[t2], si = st[t2];
    float xr = pr[(size_t)u * 65], xi = pi[(size_t)u * 65];
    ar += xr * cr - xi * si;
    ai += xr * si + xi * cr;
  }
  tre[idx] = ar * (1.f / 128.f);
  tim[idx] = ai * (1.f / 128.f);
}

// ---------------- iDFT stage B ----------------
__global__ __launch_bounds__(256) void fftB_kernel(
    const float* __restrict__ tre, const float* __restrict__ tim,
    float* __restrict__ img)
{
  __shared__ float ct[128], st[128];
  const int tid = threadIdx.x;
  if (tid < 128) {
    float a = (float)tid * (3.14159265358979323846f / 64.f);
    ct[tid] = cosf(a); st[tid] = sinf(a);
  }
  __syncthreads();
  const int idx = blockIdx.x * 256 + tid;
  const int x = idx & 127;
  const int y = (idx >> 7) & 127;
  const int b = idx >> 14;
  const float* pr = tre + ((size_t)b * 128 + y) * 65;
  const float* pi = tim + ((size_t)b * 128 + y) * 65;
  float a2 = pr[0] + ((x & 1) ? -pr[64] : pr[64]);
  for (int v = 1; v < 64; ++v) {
    int t2 = (v * x) & 127;
    a2 += 2.f * (pr[v] * ct[t2] - pi[v] * st[t2]);
  }
  a2 *= (1.f / 128.f);
  const int yy = (y + 64) & 127, xx = (x + 64) & 127;
  img[((size_t)b << 14) + (yy << 7) + xx] = a2;
}

// ---------------- conv 3x3 (1->8) + relu ----------------
__global__ __launch_bounds__(256) void conv1_kernel(
    const float* __restrict__ img, const float* __restrict__ w,
    const float* __restrict__ bi, float* __restrict__ c1)
{
  const int idx = blockIdx.x * 256 + threadIdx.x;
  const int x = idx & 127, y = (idx >> 7) & 127, ch = (idx >> 14) & 7, b = idx >> 17;
  const float* ip = img + ((size_t)b << 14);
  const float* wp = w + ch * 9;
  float acc = bi[ch];
  #pragma unroll
  for (int dy = -1; dy <= 1; ++dy) {
    const int yy = y + dy;
    if (yy < 0 || yy > 127) continue;
    #pragma unroll
    for (int dx = -1; dx <= 1; ++dx) {
      const int xx = x + dx;
      if (xx < 0 || xx > 127) continue;
      acc += ip[(yy << 7) + xx] * wp[(dy + 1) * 3 + (dx + 1)];
    }
  }
  c1[idx] = acc > 0.f ? acc : 0.f;
}

// ---------------- BN stats: two-stage ----------------
__global__ __launch_bounds__(256) void bn_part_kernel(
    const float* __restrict__ c1, float* __restrict__ bnp)
{
  const int ch = blockIdx.x >> 5, sl = blockIdx.x & 31;
  const int tid = threadIdx.x;
  const int n = sl * 2048 + tid * 8;
  const int b = n >> 14, i = n & 16383;
  const float* p = c1 + (((size_t)b * 8 + ch) << 14) + i;
  float4 a0 = *(const float4*)p, a1 = *(const float4*)(p + 4);
  float s = a0.x + a0.y + a0.z + a0.w + a1.x + a1.y + a1.z + a1.w;
  float sq = a0.x*a0.x + a0.y*a0.y + a0.z*a0.z + a0.w*a0.w
           + a1.x*a1.x + a1.y*a1.y + a1.z*a1.z + a1.w*a1.w;
  s = block_sum256(s);
  sq = block_sum256(sq);
  if (tid == 0) { bnp[blockIdx.x] = s; bnp[256 + blockIdx.x] = sq; }
}

__global__ __launch_bounds__(256) void bn_final_kernel(
    const float* __restrict__ bnp, float* __restrict__ stats)
{
  const int t = threadIdx.x;
  float s = bnp[t], sq = bnp[256 + t];
  #pragma unroll
  for (int o = 16; o; o >>= 1) { s += __shfl_down(s, o, 32); sq += __shfl_down(sq, o, 32); }
  if ((t & 31) == 0) {
    const int ch = t >> 5;
    const float m = s * (1.f / 65536.f);
    const float var = sq * (1.f / 65536.f) - m * m;
    stats[ch] = m;
    stats[8 + ch] = rsqrtf(var + 1e-5f);
  }
}

__global__ __launch_bounds__(256) void conv2_kernel(
    const float* __restrict__ c1, const float* __restrict__ stats,
    const float* __restrict__ bng, const float* __restrict__ bnb,
    const float* __restrict__ w2, const float* __restrict__ b2,
    const float* __restrict__ img, float* __restrict__ out)
{
  const int idx = blockIdx.x * 256 + threadIdx.x;
  const int b = idx >> 14, sp = idx & 16383;
  float acc = b2[0];
  #pragma unroll
  for (int ch = 0; ch < 8; ++ch) {
    float v = c1[(((size_t)b * 8 + ch) << 14) + sp];
    v = (v - stats[ch]) * stats[8 + ch] * bng[ch] + bnb[ch];
    acc += v * w2[ch];
  }
  out[idx] = acc + img[idx];
}

extern "C" void kernel_launch(void* const* d_in, const int* in_sizes, int n_in,
                              void* d_out, int out_size, void* d_ws, size_t ws_size,
                              hipStream_t stream)
{
  (void)in_sizes; (void)n_in; (void)out_size;
  const float* fbp = (const float*)d_in[1];
  const float* mag_min = (const float*)d_in[2];
  const float* mag_max = (const float*)d_in[3];
  const float* atten = (const float*)d_in[4];
  const int* coords = (const int*)d_in[5];
  const int* dstc = (const int*)d_in[6];
  const float* emb_w = (const float*)d_in[8];
  const float* emb_b = (const float*)d_in[9];
  const float* Wq = (const float*)d_in[10]; const float* bq = (const float*)d_in[11];
  const float* Wk = (const float*)d_in[12]; const float* bk = (const float*)d_in[13];
  const float* Wv = (const float*)d_in[14]; const float* bv = (const float*)d_in[15];
  const float* Wo = (const float*)d_in[16]; const float* bo = (const float*)d_in[17];
  const float* ln1g = (const float*)d_in[18]; const float* ln1b = (const float*)d_in[19];
  const float* W1 = (const float*)d_in[20]; const float* b1 = (const float*)d_in[21];
  const float* W2 = (const float*)d_in[22]; const float* b2 = (const float*)d_in[23];
  const float* ln2g = (const float*)d_in[24]; const float* ln2b = (const float*)d_in[25];
  const float* lnfg = (const float*)d_in[26]; const float* lnfb = (const float*)d_in[27];
  const float* aw = (const float*)d_in[28]; const float* ab = (const float*)d_in[29];
  const float* pw = (const float*)d_in[30]; const float* pb = (const float*)d_in[31];
  const float* c1w = (const float*)d_in[32]; const float* c1b = (const float*)d_in[33];
  const float* bng = (const float*)d_in[34]; const float* bnb = (const float*)d_in[35];
  const float* c2w = (const float*)d_in[36]; const float* c2b = (const float*)d_in[37];

  auto rnd = [](size_t b_) { return (b_ + 255) & ~(size_t)255; };
  const size_t SZ_M    = rnd((size_t)MTOT * DD * 2);            // 34.08 MB
  const size_t SZ_Y1   = rnd((size_t)MTOT * FF_ * 2);           // 136.3 MB
  const size_t SZ_WQKVO= rnd((size_t)LL * 4 * DD * DD * 2);
  const size_t SZ_W12  = rnd((size_t)LL * DD * FF_ * 2);
  const size_t SZ_WALL = SZ_WQKVO + 2 * SZ_W12;
  const size_t NEED_FULL = SZ_WALL + 4 * SZ_M + rnd((size_t)13*32*4096*4) + rnd((size_t)13*32*64*4) +
                           rnd((size_t)32*4096*2) + rnd((size_t)32*64*4) + 4096;
  const size_t NEED_FULLY = NEED_FULL + SZ_Y1;
  const size_t NEED_FB = SZ_WALL + SZ_M + rnd((size_t)SS*DD*2) + rnd((size_t)SS*FF_*2) +
                         rnd((size_t)8*4096*2) + rnd((size_t)8*64*4) + 4096;
  const int mode = (ws_size >= NEED_FULLY) ? 2 : (ws_size >= NEED_FULL) ? 1 : 0;
  if (mode == 0 && ws_size < NEED_FB) return;

  char* wsp = (char*)d_ws;
  size_t off = 0;
  auto alloc = [&](size_t bytes) -> char* { char* p = wsp + off; off += rnd(bytes); return p; };

  unsigned short* wsTall = (unsigned short*)alloc((size_t)LL * 4 * DD * DD * 2);
  unsigned short* w1Tall = (unsigned short*)alloc((size_t)LL * DD * FF_ * 2);
  unsigned short* w2Tall = (unsigned short*)alloc((size_t)LL * DD * FF_ * 2);

  unsigned short *hb, *qb_, *kb_, *vb_, *y1c, *y1ded = nullptr, *kvT;
  float *kvp, *ksp, *ksum;
  if (mode >= 1) {
    hb  = (unsigned short*)alloc((size_t)MTOT * DD * 2);
    qb_ = (unsigned short*)alloc((size_t)MTOT * DD * 2);
    kb_ = (unsigned short*)alloc((size_t)MTOT * DD * 2);
    vb_ = (unsigned short*)alloc((size_t)MTOT * DD * 2);
    if (mode == 2) y1ded = (unsigned short*)alloc((size_t)MTOT * FF_ * 2);
    kvp = (float*)alloc((size_t)13 * 32 * 4096 * 4);
    ksp = (float*)alloc((size_t)13 * 32 * 64 * 4);
    kvT = (unsigned short*)alloc((size_t)32 * 4096 * 2);
    ksum = (float*)alloc((size_t)32 * 64 * 4);
    y1c = nullptr;
  } else {
    hb  = (unsigned short*)alloc((size_t)MTOT * DD * 2);
    qb_ = (unsigned short*)alloc((size_t)SS * DD * 2);
    unsigned short* uni = (unsigned short*)alloc((size_t)SS * FF_ * 2);
    kb_ = uni;
    vb_ = uni + (size_t)SS * DD;
    kvp = (float*)(uni + 2 * (size_t)SS * DD);
    ksp = kvp + (size_t)13 * 8 * 4096;
    kvT = (unsigned short*)alloc((size_t)8 * 4096 * 2);
    ksum = (float*)alloc((size_t)8 * 64 * 4);
    y1c = uni;
  }

  // FFT/conv overlay inside qb_ (dead after the final layer's o-proj)
  float* dre  = (float*)qb_;
  float* dimg = dre + (size_t)NB * SS;
  float* tre  = dimg + (size_t)NB * SS;
  float* tim  = tre + (size_t)NB * 128 * 65;
  float* img  = tim + (size_t)NB * 128 * 65;
  float* c1buf = img + (size_t)NB * 128 * 128;
  float* bnp  = c1buf + (size_t)NB * 8 * 128 * 128;
  float* stats = bnp + 512;

  P4 sq4 = { Wq, Wk, Wv, Wo };
  transpose_qkvo_kernel<<<dim3(16, 16, 16), 256, 0, stream>>>(sq4, wsTall);
  transpose_bf16_kernel<<<dim3(64, 16, 4), 256, 0, stream>>>(W1, w1Tall, DD, FF_);
  transpose_bf16_kernel<<<dim3(16, 64, 4), 256, 0, stream>>>(W2, w2Tall, FF_, DD);

  embed_kernel<<<MTOT, 256, 0, stream>>>(fbp, coords, emb_w, emb_b, hb);

  const int npass = (mode >= 1) ? 1 : 4;
  const int NBH = (mode >= 1) ? 32 : 8;
  const int Mrows = (mode >= 1) ? MTOT : SS;

  for (int i = 0; i < LL; ++i) {
    const unsigned short* wsT = wsTall + (size_t)i * 4 * DD * DD;
    const unsigned short* w1T = w1Tall + (size_t)i * DD * FF_;
    const unsigned short* w2T = w2Tall + (size_t)i * DD * FF_;

    for (int p = 0; p < npass; ++p) {
      unsigned short* hbp = hb + (size_t)p * SS * DD;
      gemm_qkv_kernel<<<dim3(12, Mrows / 128), 256, 0, stream>>>(
          hbp, wsT, bq + (size_t)i * DD, bk + (size_t)i * DD, bv + (size_t)i * DD,
          qb_, kb_, vb_);
      kv_part_kernel<<<dim3(13, NBH), 256, 0, stream>>>(kb_, vb_, kvp, ksp);
      kv_reduce_kernel<<<(NBH * 4096 + NBH * 64 + 255) / 256, 256, 0, stream>>>(kvp, ksp, kvT, ksum, NBH);
      attn_kernel<<<dim3(65, NBH), 256, 0, stream>>>(qb_, kvT, ksum);
      gemm_res_kernel<<<dim3(4, Mrows / 128), 256, 0, stream>>>(
          qb_, wsT + (size_t)3 * DD * DD, bo + (size_t)i * DD, hbp, DD, DD, DD, DD);
      ln_wave_kernel<<<Mrows / 4, 256, 0, stream>>>(hbp, ln1g + (size_t)i * DD, ln1b + (size_t)i * DD);

      if (mode == 2) {
        gemm_kernel<2><<<dim3(16, MTOT / 128), 256, 0, stream>>>(
            hb, w1T, b1 + (size_t)i * FF_, y1ded, FF_, DD, DD, DD);
        gemm_res_kernel<<<dim3(4, MTOT / 128), 256, 0, stream>>>(
            y1ded, w2T, b2 + (size_t)i * DD, hb, DD, FF_, FF_, FF_);
      } else if (mode == 1) {
        unsigned short* y1half = qb_;   // overlays qb_+kb_ (both dead here)
        for (int g2 = 0; g2 < 2; ++g2) {
          unsigned short* hbg = hb + (size_t)g2 * 2 * SS * DD;
          gemm_kernel<2><<<dim3(16, 2 * SS / 128), 256, 0, stream>>>(
              hbg, w1T, b1 + (size_t)i * FF_, y1half, FF_, DD, DD, DD);
          gemm_res_kernel<<<dim3(4, 2 * SS / 128), 256, 0, stream>>>(
              y1half, w2T, b2 + (size_t)i * DD, hbg, DD, FF_, FF_, FF_);
        }
      } else {
        gemm_kernel<2><<<dim3(16, SS / 128), 256, 0, stream>>>(
            hbp, w1T, b1 + (size_t)i * FF_, y1c, FF_, DD, DD, DD);
        gemm_res_kernel<<<dim3(4, SS / 128), 256, 0, stream>>>(
            y1c, w2T, b2 + (size_t)i * DD, hbp, DD, FF_, FF_, FF_);
      }
      ln_wave_kernel<<<Mrows / 4, 256, 0, stream>>>(hbp, ln2g + (size_t)i * DD, ln2b + (size_t)i * DD);
    }
  }

  (void)hipMemsetAsync(dre, 0, (size_t)NB * SS * 4 * 2, stream);
  head_wave_kernel<<<MTOT / 4, 256, 0, stream>>>(hb, lnfg, lnfb, aw, ab, pw, pb,
                                                 mag_min, mag_max, atten, dstc,
                                                 (float*)d_out, dre, dimg);
  fftA_kernel<<<130, 256, 0, stream>>>(dre, dimg, tre, tim);
  fftB_kernel<<<256, 256, 0, stream>>>(tre, tim, img);
  conv1_kernel<<<2048, 256, 0, stream>>>(img, c1w, c1b, c1buf);
  bn_part_kernel<<<256, 256, 0, stream>>>(c1buf, bnp);
  bn_final_kernel<<<1, 256, 0, stream>>>(bnp, stats);
  conv2_kernel<<<256, 256, 0, stream>>>(c1buf, stats, bng, bnb, c2w, c2b, img,
                                        (float*)d_out + (size_t)MTOT * 2);
}

// Round 13
// 1868.355 us; speedup vs baseline: 1.1507x; 1.0168x over previous
//
#include <hip/hip_runtime.h>
#include <math.h>

#define NB 4
#define SS 8320
#define DD 512
#define NH_ 8
#define LL 4
#define FF_ 2048
#define MTOT (NB*SS)   // 33280

typedef __attribute__((ext_vector_type(8))) short short8;
typedef __attribute__((ext_vector_type(4))) float f32x4;

__device__ __forceinline__ unsigned short f2bf(float f){
  union { float f; unsigned int u; } x; x.f = f;
  unsigned int r = x.u + 0x7FFFu + ((x.u >> 16) & 1u);
  return (unsigned short)(r >> 16);
}
__device__ __forceinline__ float bf2f(unsigned short u){
  return __uint_as_float(((unsigned int)u) << 16);
}
__device__ __forceinline__ void gload_lds16(const void* g, void* l){
  __builtin_amdgcn_global_load_lds(
      (__attribute__((address_space(1))) void*)g,
      (__attribute__((address_space(3))) void*)l, 16, 0, 0);
}
__device__ __forceinline__ float wred(float v){
  #pragma unroll
  for (int o = 32; o; o >>= 1) v += __shfl_xor(v, o);
  return v;
}
__device__ __forceinline__ float block_sum256(float v){
  __shared__ float sb[4];
  #pragma unroll
  for (int o = 32; o; o >>= 1) v += __shfl_down(v, o);
  int w = threadIdx.x >> 6;
  __syncthreads();
  if ((threadIdx.x & 63) == 0) sb[w] = v;
  __syncthreads();
  return sb[0] + sb[1] + sb[2] + sb[3];
}

// bijective XCD-chunked block remap
__device__ __forceinline__ void xcd_remap(int& bn, int& bm)
{
  const int gx = gridDim.x;
  const int nblk = gx * gridDim.y;
  const int id = blockIdx.x + gx * blockIdx.y;
  const int qd = nblk >> 3, rd = nblk & 7;
  const int xcd = id & 7, pos = id >> 3;
  const int nid = (xcd < rd) ? (xcd * (qd + 1) + pos)
                             : (rd * (qd + 1) + (xcd - rd) * qd + pos);
  bn = nid % gx; bm = nid / gx;
}

// ---------------- batched weight transposes (K x N fp32 -> N x K bf16) -------
struct P4 { const float* p0; const float* p1; const float* p2; const float* p3; };

__global__ __launch_bounds__(256) void transpose_qkvo_kernel(P4 srcs, unsigned short* __restrict__ dst)
{
  __shared__ float tile[32][33];
  const int z = blockIdx.z;
  const int layer = z >> 2, m = z & 3;
  const float* base = (m == 0) ? srcs.p0 : (m == 1) ? srcs.p1 : (m == 2) ? srcs.p2 : srcs.p3;
  const float* src = base + (size_t)layer * DD * DD;
  unsigned short* d = dst + (size_t)z * DD * DD;
  const int n0 = blockIdx.x * 32, k0 = blockIdx.y * 32;
  const int tx = threadIdx.x & 31, ty = threadIdx.x >> 5;
  #pragma unroll
  for (int j = 0; j < 32; j += 8) tile[ty + j][tx] = src[(size_t)(k0 + ty + j) * DD + n0 + tx];
  __syncthreads();
  #pragma unroll
  for (int j = 0; j < 32; j += 8) d[(size_t)(n0 + ty + j) * DD + k0 + tx] = f2bf(tile[tx][ty + j]);
}

__global__ __launch_bounds__(256) void transpose_bf16_kernel(
    const float* __restrict__ src0, unsigned short* __restrict__ dst0, int K, int N)
{
  __shared__ float tile[32][33];
  const float* src = src0 + (size_t)blockIdx.z * K * N;
  unsigned short* dst = dst0 + (size_t)blockIdx.z * K * N;
  const int n0 = blockIdx.x * 32, k0 = blockIdx.y * 32;
  const int tx = threadIdx.x & 31, ty = threadIdx.x >> 5;
  #pragma unroll
  for (int j = 0; j < 32; j += 8) tile[ty + j][tx] = src[(size_t)(k0 + ty + j) * N + n0 + tx];
  __syncthreads();
  #pragma unroll
  for (int j = 0; j < 32; j += 8) dst[(size_t)(n0 + ty + j) * K + k0 + tx] = f2bf(tile[tx][ty + j]);
}

// ---------------- embedding + 2D sinusoidal PE ----------------
__global__ __launch_bounds__(256) void embed_kernel(
    const float* __restrict__ fbp, const int* __restrict__ coords,
    const float* __restrict__ emb_w, const float* __restrict__ emb_b,
    unsigned short* __restrict__ hb)
{
  const int row = blockIdx.x;
  const int c = threadIdx.x;
  const int s = row % SS;
  const float f0 = fbp[(size_t)row * 2], f1 = fbp[(size_t)row * 2 + 1];
  const float v0 = f0 * emb_w[c] + f1 * emb_w[256 + c] + emb_b[c];
  const int p = (c < 128) ? coords[s * 2 + 1] : coords[s * 2];
  const int c2 = c & 127;
  const int jj = c2 >> 1;
  const float dv = expf(-(float)(2 * jj) * (9.210340371976184f / 128.f));
  const float a = (float)p * dv;
  const float v1 = (c2 & 1) ? cosf(a) : sinf(a);
  const size_t base = (size_t)row * DD;
  hb[base + c] = f2bf(v0);
  hb[base + 256 + c] = f2bf(v1);
}

// ---------------- fused QKV GEMM, 128^2 tile, XCD-remapped (unswapped) -------
__global__ __launch_bounds__(256, 4) void gemm_qkv_kernel(
    const unsigned short* __restrict__ A,     // [M][512]
    const unsigned short* __restrict__ Bt,    // [1536][512]
    const float* __restrict__ bq_, const float* __restrict__ bk_, const float* __restrict__ bv_,
    unsigned short* __restrict__ qo, unsigned short* __restrict__ ko, unsigned short* __restrict__ vo)
{
  __shared__ __attribute__((aligned(16))) unsigned short As[128 * 64];
  __shared__ __attribute__((aligned(16))) unsigned short Bs[128 * 64];
  const int tid = threadIdx.x;
  const int lane = tid & 63, w = tid >> 6;
  const int lr = lane & 15, lg = lane >> 4;
  const int wm = w >> 1, wn = w & 1;
  int bn, bm; xcd_remap(bn, bm);                 // bn 0..11
  const int which = bn >> 2;
  const unsigned short* Ag = A + (size_t)bm * 128 * DD;
  const unsigned short* Bg = Bt + (size_t)bn * 128 * DD;
  unsigned short* out = (which == 0) ? qo : (which == 1) ? ko : vo;
  const float* bias = (which == 0) ? bq_ : (which == 1) ? bk_ : bv_;
  f32x4 acc[4][4] = {};
  for (int kt = 0; kt < 8; ++kt) {
    if (kt) __syncthreads();
    const int kbase = kt << 6;
    #pragma unroll
    for (int i = 0; i < 4; ++i) {
      int cid = i * 256 + tid;
      int row = cid >> 3, c = cid & 7;
      gload_lds16(Ag + (size_t)row * DD + kbase + ((c ^ (row & 7)) << 3), (void*)(As + cid * 8));
    }
    #pragma unroll
    for (int i = 0; i < 4; ++i) {
      int cid = i * 256 + tid;
      int row = cid >> 3, c = cid & 7;
      gload_lds16(Bg + (size_t)row * DD + kbase + ((c ^ (row & 7)) << 3), (void*)(Bs + cid * 8));
    }
    __syncthreads();
    #pragma unroll
    for (int kk = 0; kk < 2; ++kk) {
      short8 af[4], bfv[4];
      #pragma unroll
      for (int f = 0; f < 4; ++f) {
        int row = wm * 64 + f * 16 + lr;
        af[f] = *(const short8*)(As + row * 64 + (((kk * 4 + lg) ^ (row & 7)) << 3));
      }
      #pragma unroll
      for (int f = 0; f < 4; ++f) {
        int row = wn * 64 + f * 16 + lr;
        bfv[f] = *(const short8*)(Bs + row * 64 + (((kk * 4 + lg) ^ (row & 7)) << 3));
      }
      #pragma unroll
      for (int fm = 0; fm < 4; ++fm)
        #pragma unroll
        for (int fn = 0; fn < 4; ++fn)
          acc[fm][fn] = __builtin_amdgcn_mfma_f32_16x16x32_bf16(af[fm], bfv[fn], acc[fm][fn], 0, 0, 0);
    }
  }
  const int elu = (which < 2);
  #pragma unroll
  for (int fm = 0; fm < 4; ++fm) {
    const int row0 = bm * 128 + wm * 64 + fm * 16 + lg * 4;
    #pragma unroll
    for (int fn = 0; fn < 4; ++fn) {
      const int col = (bn & 3) * 128 + wn * 64 + fn * 16 + lr;
      const float bv = bias[col];
      #pragma unroll
      for (int r = 0; r < 4; ++r) {
        float v = acc[fm][fn][r] + bv;
        if (elu) v = (v > 0.f) ? (v + 1.f) : expf(v);
        out[(size_t)(row0 + r) * DD + col] = f2bf(v);
      }
    }
  }
}

// ---------------- generic GEMM (no residual), swapped-MFMA epilogue ---------
// ACT: 0=none 2=relu
template<int ACT>
__global__ __launch_bounds__(256, 4) void gemm_kernel(
    const unsigned short* __restrict__ A,
    const unsigned short* __restrict__ Bt,
    const float* __restrict__ bias,
    unsigned short* __restrict__ C,
    int N, int K, int lda, int ldb)
{
  __shared__ __attribute__((aligned(16))) unsigned short As[128 * 64];
  __shared__ __attribute__((aligned(16))) unsigned short Bs[128 * 64];
  const int tid = threadIdx.x;
  const int lane = tid & 63, w = tid >> 6;
  const int lr = lane & 15, lg = lane >> 4;
  const int wm = w >> 1, wn = w & 1;
  int bn, bm; xcd_remap(bn, bm);
  const unsigned short* Ag = A + (size_t)bm * 128 * lda;
  const unsigned short* Bg = Bt + (size_t)bn * 128 * ldb;
  f32x4 acc[4][4] = {};
  const int nkt = K >> 6;
  for (int kt = 0; kt < nkt; ++kt) {
    if (kt) __syncthreads();
    const int kbase = kt << 6;
    #pragma unroll
    for (int i = 0; i < 4; ++i) {
      int cid = i * 256 + tid;
      int row = cid >> 3, c = cid & 7;
      gload_lds16(Ag + (size_t)row * lda + kbase + ((c ^ (row & 7)) << 3), (void*)(As + cid * 8));
    }
    #pragma unroll
    for (int i = 0; i < 4; ++i) {
      int cid = i * 256 + tid;
      int row = cid >> 3, c = cid & 7;
      gload_lds16(Bg + (size_t)row * ldb + kbase + ((c ^ (row & 7)) << 3), (void*)(Bs + cid * 8));
    }
    __syncthreads();
    #pragma unroll
    for (int kk = 0; kk < 2; ++kk) {
      short8 af[4], bfv[4];
      #pragma unroll
      for (int f = 0; f < 4; ++f) {
        int row = wm * 64 + f * 16 + lr;
        af[f] = *(const short8*)(As + row * 64 + (((kk * 4 + lg) ^ (row & 7)) << 3));
      }
      #pragma unroll
      for (int f = 0; f < 4; ++f) {
        int row = wn * 64 + f * 16 + lr;
        bfv[f] = *(const short8*)(Bs + row * 64 + (((kk * 4 + lg) ^ (row & 7)) << 3));
      }
      #pragma unroll
      for (int fm = 0; fm < 4; ++fm)
        #pragma unroll
        for (int fn = 0; fn < 4; ++fn)
          acc[fm][fn] = __builtin_amdgcn_mfma_f32_16x16x32_bf16(bfv[fn], af[fm], acc[fm][fn], 0, 0, 0);
    }
  }
  #pragma unroll
  for (int fm = 0; fm < 4; ++fm) {
    const int row = bm * 128 + wm * 64 + fm * 16 + lr;
    #pragma unroll
    for (int fn = 0; fn < 4; ++fn) {
      const int colq = bn * 128 + wn * 64 + fn * 16 + lg * 4;
      const float4 bv4 = *(const float4*)(bias + colq);
      float v0 = acc[fm][fn][0] + bv4.x;
      float v1 = acc[fm][fn][1] + bv4.y;
      float v2 = acc[fm][fn][2] + bv4.z;
      float v3 = acc[fm][fn][3] + bv4.w;
      if (ACT == 2) {
        v0 = v0 > 0.f ? v0 : 0.f;
        v1 = v1 > 0.f ? v1 : 0.f;
        v2 = v2 > 0.f ? v2 : 0.f;
        v3 = v3 > 0.f ? v3 : 0.f;
      }
      ushort4 o4 = { f2bf(v0), f2bf(v1), f2bf(v2), f2bf(v3) };
      *(ushort4*)(C + (size_t)row * N + colq) = o4;
    }
  }
}

// ---------------- residual GEMM (C += A@Bt^T + bias), vector epilogue -------
__global__ __launch_bounds__(256) void gemm_res_kernel(
    const unsigned short* __restrict__ A,
    const unsigned short* __restrict__ Bt,
    const float* __restrict__ bias,
    unsigned short* __restrict__ C,
    int N, int K, int lda, int ldb)
{
  __shared__ __attribute__((aligned(16))) unsigned short As[128 * 64];
  __shared__ __attribute__((aligned(16))) unsigned short Bs[128 * 64];
  const int tid = threadIdx.x;
  const int lane = tid & 63, w = tid >> 6;
  const int lr = lane & 15, lg = lane >> 4;
  const int wm = w >> 1, wn = w & 1;
  int bn, bm; xcd_remap(bn, bm);
  const unsigned short* Ag = A + (size_t)bm * 128 * lda;
  const unsigned short* Bg = Bt + (size_t)bn * 128 * ldb;
  f32x4 acc[4][4] = {};
  const int nkt = K >> 6;
  for (int kt = 0; kt < nkt; ++kt) {
    if (kt) __syncthreads();
    const int kbase = kt << 6;
    #pragma unroll
    for (int i = 0; i < 4; ++i) {
      int cid = i * 256 + tid;
      int row = cid >> 3, c = cid & 7;
      gload_lds16(Ag + (size_t)row * lda + kbase + ((c ^ (row & 7)) << 3), (void*)(As + cid * 8));
    }
    #pragma unroll
    for (int i = 0; i < 4; ++i) {
      int cid = i * 256 + tid;
      int row = cid >> 3, c = cid & 7;
      gload_lds16(Bg + (size_t)row * ldb + kbase + ((c ^ (row & 7)) << 3), (void*)(Bs + cid * 8));
    }
    __syncthreads();
    #pragma unroll
    for (int kk = 0; kk < 2; ++kk) {
      short8 af[4], bfv[4];
      #pragma unroll
      for (int f = 0; f < 4; ++f) {
        int row = wm * 64 + f * 16 + lr;
        af[f] = *(const short8*)(As + row * 64 + (((kk * 4 + lg) ^ (row & 7)) << 3));
      }
      #pragma unroll
      for (int f = 0; f < 4; ++f) {
        int row = wn * 64 + f * 16 + lr;
        bfv[f] = *(const short8*)(Bs + row * 64 + (((kk * 4 + lg) ^ (row & 7)) << 3));
      }
      #pragma unroll
      for (int fm = 0; fm < 4; ++fm)
        #pragma unroll
        for (int fn = 0; fn < 4; ++fn)
          acc[fm][fn] = __builtin_amdgcn_mfma_f32_16x16x32_bf16(bfv[fn], af[fm], acc[fm][fn], 0, 0, 0);
    }
  }
  #pragma unroll
  for (int fm = 0; fm < 4; ++fm) {
    const int row = bm * 128 + wm * 64 + fm * 16 + lr;
    #pragma unroll
    for (int fn = 0; fn < 4; ++fn) {
      const int colq = bn * 128 + wn * 64 + fn * 16 + lg * 4;
      const float4 bv4 = *(const float4*)(bias + colq);
      unsigned short* cp = C + (size_t)row * N + colq;
      const ushort4 r4 = *(const ushort4*)cp;
      ushort4 o4;
      o4.x = f2bf(acc[fm][fn][0] + bv4.x + bf2f(r4.x));
      o4.y = f2bf(acc[fm][fn][1] + bv4.y + bf2f(r4.y));
      o4.z = f2bf(acc[fm][fn][2] + bv4.z + bf2f(r4.z));
      o4.w = f2bf(acc[fm][fn][3] + bv4.w + bf2f(r4.w));
      *(ushort4*)cp = o4;
    }
  }
}

// ---------------- kv partials: 640-row chunks x (b,h) ----------------
__global__ __launch_bounds__(256) void kv_part_kernel(
    const unsigned short* __restrict__ kb, const unsigned short* __restrict__ vb,
    float* __restrict__ kvp, float* __restrict__ ksp)
{
  __shared__ __attribute__((aligned(16))) float Kc[128][64];
  __shared__ __attribute__((aligned(16))) float Vc[128][64];
  const int ch = blockIdx.x;
  const int bh = blockIdx.y;
  const int NBH = gridDim.y;
  const int b = bh >> 3, h = bh & 7;
  const int tid = threadIdx.x;
  const int d = tid >> 2, m0 = (tid & 3) << 4;
  f32x4 a0 = {}, a1 = {}, a2 = {}, a3 = {};
  float sk = 0.f;
  for (int t = 0; t < 5; ++t) {
    if (t) __syncthreads();
    const size_t roff = ((size_t)b * SS + ch * 640 + t * 128) * DD + h * 64;
    #pragma unroll
    for (int i = 0; i < 8; ++i) {
      int e4 = i * 256 + tid;
      int r = e4 >> 4, c4 = e4 & 15;
      ushort4 kq = *(const ushort4*)(kb + roff + (size_t)r * DD + c4 * 4);
      ushort4 vq = *(const ushort4*)(vb + roff + (size_t)r * DD + c4 * 4);
      f32x4 kf4 = { bf2f(kq.x), bf2f(kq.y), bf2f(kq.z), bf2f(kq.w) };
      f32x4 vf4 = { bf2f(vq.x), bf2f(vq.y), bf2f(vq.z), bf2f(vq.w) };
      *(f32x4*)&Kc[r][c4 * 4] = kf4;
      *(f32x4*)&Vc[r][c4 * 4] = vf4;
    }
    __syncthreads();
    for (int s2 = 0; s2 < 128; ++s2) {
      const float kd = Kc[s2][d];
      const f32x4* vp = (const f32x4*)&Vc[s2][m0];
      a0 += kd * vp[0]; a1 += kd * vp[1]; a2 += kd * vp[2]; a3 += kd * vp[3];
    }
    if (tid < 64) {
      for (int s2 = 0; s2 < 128; ++s2) sk += Kc[s2][tid];
    }
  }
  float* ko = kvp + (((size_t)ch * NBH + bh) * 64 + d) * 64 + m0;
  *(f32x4*)(ko) = a0; *(f32x4*)(ko + 4) = a1; *(f32x4*)(ko + 8) = a2; *(f32x4*)(ko + 12) = a3;
  if (tid < 64) ksp[((size_t)ch * NBH + bh) * 64 + tid] = sk;
}

__global__ __launch_bounds__(256) void kv_reduce_kernel(
    const float* __restrict__ kvp, const float* __restrict__ ksp,
    unsigned short* __restrict__ kvT, float* __restrict__ ksum, int NBH)
{
  const int idx = blockIdx.x * 256 + threadIdx.x;
  const int nkv = NBH * 4096;
  if (idx < nkv) {
    const int bh = idx >> 12, dm = idx & 4095;
    const int d = dm >> 6, m = dm & 63;
    float s = 0.f;
    #pragma unroll
    for (int c = 0; c < 13; ++c) s += kvp[(((size_t)c * NBH + bh) << 12) + dm];
    kvT[(size_t)bh * 4096 + m * 64 + d] = f2bf(s);
  } else if (idx < nkv + NBH * 64) {
    const int i2 = idx - nkv;
    const int bh = i2 >> 6, d = i2 & 63;
    float s = 0.f;
    #pragma unroll
    for (int c = 0; c < 13; ++c) s += ksp[((size_t)c * NBH + bh) * 64 + d];
    ksum[i2] = s;
  }
}

// ---------------- attn: z fused + (qf @ kv) * z, swapped-MFMA, in-place -----
__global__ __launch_bounds__(256) void attn_kernel(
    unsigned short* __restrict__ qb, const unsigned short* __restrict__ kvT,
    const float* __restrict__ ksum)
{
  __shared__ __attribute__((aligned(16))) unsigned short Qs[128 * 64];
  __shared__ __attribute__((aligned(16))) unsigned short Ks[64 * 64];
  __shared__ float zloc[128];
  const int st = blockIdx.x;
  const int bh = blockIdx.y;
  const int b = bh >> 3, h = bh & 7;
  const int tid = threadIdx.x, lane = tid & 63, w = tid >> 6;
  const int lr = lane & 15, lg = lane >> 4;
  const size_t row0 = (size_t)b * SS + st * 128;
  const unsigned short* Qg = qb + row0 * DD + h * 64;
  #pragma unroll
  for (int i = 0; i < 4; ++i) {
    int cid = i * 256 + tid;
    int r = cid >> 3, c = cid & 7;
    gload_lds16(Qg + (size_t)r * DD + ((c ^ (r & 7)) << 3), (void*)(Qs + cid * 8));
  }
  #pragma unroll
  for (int i = 0; i < 2; ++i) {
    int cid = i * 256 + tid;
    int r = cid >> 3, c = cid & 7;
    gload_lds16(kvT + (size_t)bh * 4096 + r * 64 + ((c ^ (r & 7)) << 3), (void*)(Ks + cid * 8));
  }
  __syncthreads();
  {
    const int row = tid >> 1, half = tid & 1;
    const float* ks = ksum + (size_t)bh * 64;
    float dot = 0.f;
    #pragma unroll
    for (int c0 = 0; c0 < 4; ++c0) {
      const int c = half * 4 + c0;
      short8 qv = *(const short8*)(Qs + row * 64 + ((c ^ (row & 7)) << 3));
      #pragma unroll
      for (int j = 0; j < 8; ++j) dot += bf2f((unsigned short)qv[j]) * ks[c * 8 + j];
    }
    dot += __shfl_xor(dot, 1);
    if (half == 0) zloc[row] = 1.f / (dot + 1e-6f);
  }
  __syncthreads();
  f32x4 acc[2][4] = {};   // [fm][fn]: row = w*32+fm*16+lr, cols = fn*16+lg*4+r
  #pragma unroll
  for (int kk = 0; kk < 2; ++kk) {
    short8 af[2], bfv[4];
    #pragma unroll
    for (int f = 0; f < 2; ++f) {
      int r = w * 32 + f * 16 + lr;
      af[f] = *(const short8*)(Qs + r * 64 + (((kk * 4 + lg) ^ (r & 7)) << 3));
    }
    #pragma unroll
    for (int f = 0; f < 4; ++f) {
      int r = f * 16 + lr;
      bfv[f] = *(const short8*)(Ks + r * 64 + (((kk * 4 + lg) ^ (r & 7)) << 3));
    }
    #pragma unroll
    for (int fm = 0; fm < 2; ++fm)
      #pragma unroll
      for (int fn = 0; fn < 4; ++fn)
        acc[fm][fn] = __builtin_amdgcn_mfma_f32_16x16x32_bf16(bfv[fn], af[fm], acc[fm][fn], 0, 0, 0);
  }
  #pragma unroll
  for (int fm = 0; fm < 2; ++fm) {
    const int lrow = w * 32 + fm * 16 + lr;
    const float zv = zloc[lrow];
    unsigned short* outp = qb + (row0 + lrow) * DD + h * 64;
    #pragma unroll
    for (int fn = 0; fn < 4; ++fn) {
      ushort4 o4;
      o4.x = f2bf(acc[fm][fn][0] * zv);
      o4.y = f2bf(acc[fm][fn][1] * zv);
      o4.z = f2bf(acc[fm][fn][2] * zv);
      o4.w = f2bf(acc[fm][fn][3] * zv);
      *(ushort4*)(outp + fn * 16 + lg * 4) = o4;
    }
  }
}

// ---------------- wave-per-row LayerNorm, in-place bf16 ----------------
__global__ __launch_bounds__(256) void ln_wave_kernel(
    unsigned short* __restrict__ hb, const float* __restrict__ g, const float* __restrict__ bt)
{
  const int tid = threadIdx.x, wv = tid >> 6, ln = tid & 63;
  const size_t row = (size_t)blockIdx.x * 4 + wv;
  unsigned short* p = hb + row * DD + ln * 8;
  ushort4 u0 = *(const ushort4*)p;
  ushort4 u1 = *(const ushort4*)(p + 4);
  float x[8] = { bf2f(u0.x), bf2f(u0.y), bf2f(u0.z), bf2f(u0.w),
                 bf2f(u1.x), bf2f(u1.y), bf2f(u1.z), bf2f(u1.w) };
  float s = 0.f;
  #pragma unroll
  for (int i = 0; i < 8; ++i) s += x[i];
  const float mean = wred(s) * (1.f / DD);
  float sq = 0.f;
  #pragma unroll
  for (int i = 0; i < 8; ++i) { const float d = x[i] - mean; sq += d * d; }
  const float rstd = rsqrtf(wred(sq) * (1.f / DD) + 1e-5f);
  const float4 g0 = *(const float4*)(g + ln * 8), g1 = *(const float4*)(g + ln * 8 + 4);
  const float4 b0 = *(const float4*)(bt + ln * 8), b1 = *(const float4*)(bt + ln * 8 + 4);
  const float gg[8] = { g0.x, g0.y, g0.z, g0.w, g1.x, g1.y, g1.z, g1.w };
  const float bb[8] = { b0.x, b0.y, b0.z, b0.w, b1.x, b1.y, b1.z, b1.w };
  ushort4 o0, o1;
  o0.x = f2bf((x[0] - mean) * rstd * gg[0] + bb[0]);
  o0.y = f2bf((x[1] - mean) * rstd * gg[1] + bb[1]);
  o0.z = f2bf((x[2] - mean) * rstd * gg[2] + bb[2]);
  o0.w = f2bf((x[3] - mean) * rstd * gg[3] + bb[3]);
  o1.x = f2bf((x[4] - mean) * rstd * gg[4] + bb[4]);
  o1.y = f2bf((x[5] - mean) * rstd * gg[5] + bb[5]);
  o1.z = f2bf((x[6] - mean) * rstd * gg[6] + bb[6]);
  o1.w = f2bf((x[7] - mean) * rstd * gg[7] + bb[7]);
  *(ushort4*)p = o0;
  *(ushort4*)(p + 4) = o1;
}

// ---------------- wave-per-row final LN + heads + DFT scatter ----------------
__global__ __launch_bounds__(256) void head_wave_kernel(
    const unsigned short* __restrict__ hb,
    const float* __restrict__ lg_, const float* __restrict__ lb_,
    const float* __restrict__ aw, const float* __restrict__ ab,
    const float* __restrict__ pw, const float* __restrict__ pb,
    const float* __restrict__ mag_min, const float* __restrict__ mag_max,
    const float* __restrict__ atten, const int* __restrict__ dst,
    float* __restrict__ yhat, float* __restrict__ dre, float* __restrict__ dimg)
{
  const int tid = threadIdx.x, wv = tid >> 6, ln = tid & 63;
  const size_t row = (size_t)blockIdx.x * 4 + wv;
  const unsigned short* p = hb + row * DD + ln * 8;
  ushort4 u0 = *(const ushort4*)p;
  ushort4 u1 = *(const ushort4*)(p + 4);
  float x[8] = { bf2f(u0.x), bf2f(u0.y), bf2f(u0.z), bf2f(u0.w),
                 bf2f(u1.x), bf2f(u1.y), bf2f(u1.z), bf2f(u1.w) };
  float s = 0.f;
  #pragma unroll
  for (int i = 0; i < 8; ++i) s += x[i];
  const float mean = wred(s) * (1.f / DD);
  float sq = 0.f;
  #pragma unroll
  for (int i = 0; i < 8; ++i) { const float d = x[i] - mean; sq += d * d; }
  const float rstd = rsqrtf(wred(sq) * (1.f / DD) + 1e-5f);
  float ad = 0.f, pd = 0.f;
  #pragma unroll
  for (int i = 0; i < 8; ++i) {
    const float y = (x[i] - mean) * rstd * lg_[ln * 8 + i] + lb_[ln * 8 + i];
    ad += y * aw[ln * 8 + i];
    pd += y * pw[ln * 8 + i];
  }
  ad = wred(ad); pd = wred(pd);
  if (ln == 0) {
    const float ya = ad + ab[0];
    const float yp = tanhf(pd + pb[0]);
    yhat[row * 2] = ya;
    yhat[row * 2 + 1] = yp;
    const int b = (int)(row / SS), s2 = (int)(row % SS);
    const float amp = expf((ya + 1.f) * 0.5f * (mag_max[0] - mag_min[0]) + mag_min[0]);
    const float phi = yp * 3.14159265358979323846f;
    const int j = dst[s2];
    const float at = atten[j];
    dre[(size_t)b * SS + j] = amp * cosf(phi) * at;
    dimg[(size_t)b * SS + j] = amp * sinf(phi) * at;
  }
}

// ---------------- iDFT stage A ----------------
__global__ __launch_bounds__(256) void fftA_kernel(
    const float* __restrict__ dre, const float* __restrict__ dimg,
    float* __restrict__ tre, float* __restrict__ tim)
{
  __shared__ float ct[128], st[128];
  const int tid = threadIdx.x;
  if (tid < 128) {
    float a = (float)tid * (3.14159265358979323846f / 64.f);
    ct[tid] = cosf(a); st[tid] = sinf(a);
  }
  __syncthreads();
  const int idx = blockIdx.x * 256 + tid;
  const int v = idx % 65;
  const int y = (idx / 65) & 127;
  const int b = idx / (65 * 128);
  const float* pr = dre + (size_t)b * SS + v;
  const float* pi = dimg + (size_t)b * SS + v;
  float ar = 0.f, ai = 0.f;
  for (int u = 0; u < 128; ++u) {
    int t2 = (u * y) & 127;
    float cr = ct[t2], si = st[t2];
    float xr = pr[(size_t)u * 65], xi = pi[(size_t)u * 65];
    ar += xr * cr - xi * si;
    ai += xr * si + xi * cr;
  }
  tre[idx] = ar * (1.f / 128.f);
  tim[idx] = ai * (1.f / 128.f);
}

// ---------------- iDFT stage B ----------------
__global__ __launch_bounds__(256) void fftB_kernel(
    const float* __restrict__ tre, const float* __restrict__ tim,
    float* __restrict__ img)
{
  __shared__ float ct[128], st[128];
  const int tid = threadIdx.x;
  if (tid < 128) {
    float a = (float)tid * (3.14159265358979323846f / 64.f);
    ct[tid] = cosf(a); st[tid] = sinf(a);
  }
  __syncthreads();
  const int idx = blockIdx.x * 256 + tid;
  const int x = idx & 127;
  const int y = (idx >> 7) & 127;
  const int b = idx >> 14;
  const float* pr = tre + ((size_t)b * 128 + y) * 65;
  const float* pi = tim + ((size_t)b * 128 + y) * 65;
  float a2 = pr[0] + ((x & 1) ? -pr[64] : pr[64]);
  for (int v = 1; v < 64; ++v) {
    int t2 = (v * x) & 127;
    a2 += 2.f * (pr[v] * ct[t2] - pi[v] * st[t2]);
  }
  a2 *= (1.f / 128.f);
  const int yy = (y + 64) & 127, xx = (x + 64) & 127;
  img[((size_t)b << 14) + (yy << 7) + xx] = a2;
}

// ---------------- conv 3x3 (1->8) + relu ----------------
__global__ __launch_bounds__(256) void conv1_kernel(
    const float* __restrict__ img, const float* __restrict__ w,
    const float* __restrict__ bi, float* __restrict__ c1)
{
  const int idx = blockIdx.x * 256 + threadIdx.x;
  const int x = idx & 127, y = (idx >> 7) & 127, ch = (idx >> 14) & 7, b = idx >> 17;
  const float* ip = img + ((size_t)b << 14);
  const float* wp = w + ch * 9;
  float acc = bi[ch];
  #pragma unroll
  for (int dy = -1; dy <= 1; ++dy) {
    const int yy = y + dy;
    if (yy < 0 || yy > 127) continue;
    #pragma unroll
    for (int dx = -1; dx <= 1; ++dx) {
      const int xx = x + dx;
      if (xx < 0 || xx > 127) continue;
      acc += ip[(yy << 7) + xx] * wp[(dy + 1) * 3 + (dx + 1)];
    }
  }
  c1[idx] = acc > 0.f ? acc : 0.f;
}

// ---------------- BN stats: two-stage ----------------
__global__ __launch_bounds__(256) void bn_part_kernel(
    const float* __restrict__ c1, float* __restrict__ bnp)
{
  const int ch = blockIdx.x >> 5, sl = blockIdx.x & 31;
  const int tid = threadIdx.x;
  const int n = sl * 2048 + tid * 8;
  const int b = n >> 14, i = n & 16383;
  const float* p = c1 + (((size_t)b * 8 + ch) << 14) + i;
  float4 a0 = *(const float4*)p, a1 = *(const float4*)(p + 4);
  float s = a0.x + a0.y + a0.z + a0.w + a1.x + a1.y + a1.z + a1.w;
  float sq = a0.x*a0.x + a0.y*a0.y + a0.z*a0.z + a0.w*a0.w
           + a1.x*a1.x + a1.y*a1.y + a1.z*a1.z + a1.w*a1.w;
  s = block_sum256(s);
  sq = block_sum256(sq);
  if (tid == 0) { bnp[blockIdx.x] = s; bnp[256 + blockIdx.x] = sq; }
}

__global__ __launch_bounds__(256) void bn_final_kernel(
    const float* __restrict__ bnp, float* __restrict__ stats)
{
  const int t = threadIdx.x;
  float s = bnp[t], sq = bnp[256 + t];
  #pragma unroll
  for (int o = 16; o; o >>= 1) { s += __shfl_down(s, o, 32); sq += __shfl_down(sq, o, 32); }
  if ((t & 31) == 0) {
    const int ch = t >> 5;
    const float m = s * (1.f / 65536.f);
    const float var = sq * (1.f / 65536.f) - m * m;
    stats[ch] = m;
    stats[8 + ch] = rsqrtf(var + 1e-5f);
  }
}

__global__ __launch_bounds__(256) void conv2_kernel(
    const float* __restrict__ c1, const float* __restrict__ stats,
    const float* __restrict__ bng, const float* __restrict__ bnb,
    const float* __restrict__ w2, const float* __restrict__ b2,
    const float* __restrict__ img, float* __restrict__ out)
{
  const int idx = blockIdx.x * 256 + threadIdx.x;
  const int b = idx >> 14, sp = idx & 16383;
  float acc = b2[0];
  #pragma unroll
  for (int ch = 0; ch < 8; ++ch) {
    float v = c1[(((size_t)b * 8 + ch) << 14) + sp];
    v = (v - stats[ch]) * stats[8 + ch] * bng[ch] + bnb[ch];
    acc += v * w2[ch];
  }
  out[idx] = acc + img[idx];
}

extern "C" void kernel_launch(void* const* d_in, const int* in_sizes, int n_in,
                              void* d_out, int out_size, void* d_ws, size_t ws_size,
                              hipStream_t stream)
{
  (void)in_sizes; (void)n_in; (void)out_size;
  const float* fbp = (const float*)d_in[1];
  const float* mag_min = (const float*)d_in[2];
  const float* mag_max = (const float*)d_in[3];
  const float* atten = (const float*)d_in[4];
  const int* coords = (const int*)d_in[5];
  const int* dstc = (const int*)d_in[6];
  const float* emb_w = (const float*)d_in[8];
  const float* emb_b = (const float*)d_in[9];
  const float* Wq = (const float*)d_in[10]; const float* bq = (const float*)d_in[11];
  const float* Wk = (const float*)d_in[12]; const float* bk = (const float*)d_in[13];
  const float* Wv = (const float*)d_in[14]; const float* bv = (const float*)d_in[15];
  const float* Wo = (const float*)d_in[16]; const float* bo = (const float*)d_in[17];
  const float* ln1g = (const float*)d_in[18]; const float* ln1b = (const float*)d_in[19];
  const float* W1 = (const float*)d_in[20]; const float* b1 = (const float*)d_in[21];
  const float* W2 = (const float*)d_in[22]; const float* b2 = (const float*)d_in[23];
  const float* ln2g = (const float*)d_in[24]; const float* ln2b = (const float*)d_in[25];
  const float* lnfg = (const float*)d_in[26]; const float* lnfb = (const float*)d_in[27];
  const float* aw = (const float*)d_in[28]; const float* ab = (const float*)d_in[29];
  const float* pw = (const float*)d_in[30]; const float* pb = (const float*)d_in[31];
  const float* c1w = (const float*)d_in[32]; const float* c1b = (const float*)d_in[33];
  const float* bng = (const float*)d_in[34]; const float* bnb = (const float*)d_in[35];
  const float* c2w = (const float*)d_in[36]; const float* c2b = (const float*)d_in[37];

  auto rnd = [](size_t b_) { return (b_ + 255) & ~(size_t)255; };
  const size_t SZ_M    = rnd((size_t)MTOT * DD * 2);            // 34.08 MB
  const size_t SZ_Y1   = rnd((size_t)MTOT * FF_ * 2);           // 136.3 MB
  const size_t SZ_WQKVO= rnd((size_t)LL * 4 * DD * DD * 2);
  const size_t SZ_W12  = rnd((size_t)LL * DD * FF_ * 2);
  const size_t SZ_WALL = SZ_WQKVO + 2 * SZ_W12;
  const size_t NEED_FULL = SZ_WALL + 4 * SZ_M + rnd((size_t)13*32*4096*4) + rnd((size_t)13*32*64*4) +
                           rnd((size_t)32*4096*2) + rnd((size_t)32*64*4) + 4096;
  const size_t NEED_FULLY = NEED_FULL + SZ_Y1;
  const size_t NEED_FB = SZ_WALL + SZ_M + rnd((size_t)SS*DD*2) + rnd((size_t)SS*FF_*2) +
                         rnd((size_t)8*4096*2) + rnd((size_t)8*64*4) + 4096;
  const int mode = (ws_size >= NEED_FULLY) ? 2 : (ws_size >= NEED_FULL) ? 1 : 0;
  if (mode == 0 && ws_size < NEED_FB) return;

  char* wsp = (char*)d_ws;
  size_t off = 0;
  auto alloc = [&](size_t bytes) -> char* { char* p = wsp + off; off += rnd(bytes); return p; };

  unsigned short* wsTall = (unsigned short*)alloc((size_t)LL * 4 * DD * DD * 2);
  unsigned short* w1Tall = (unsigned short*)alloc((size_t)LL * DD * FF_ * 2);
  unsigned short* w2Tall = (unsigned short*)alloc((size_t)LL * DD * FF_ * 2);

  unsigned short *hb, *qb_, *kb_, *vb_, *y1c, *y1ded = nullptr, *kvT;
  float *kvp, *ksp, *ksum;
  if (mode >= 1) {
    hb  = (unsigned short*)alloc((size_t)MTOT * DD * 2);
    qb_ = (unsigned short*)alloc((size_t)MTOT * DD * 2);
    kb_ = (unsigned short*)alloc((size_t)MTOT * DD * 2);
    vb_ = (unsigned short*)alloc((size_t)MTOT * DD * 2);
    if (mode == 2) y1ded = (unsigned short*)alloc((size_t)MTOT * FF_ * 2);
    kvp = (float*)alloc((size_t)13 * 32 * 4096 * 4);
    ksp = (float*)alloc((size_t)13 * 32 * 64 * 4);
    kvT = (unsigned short*)alloc((size_t)32 * 4096 * 2);
    ksum = (float*)alloc((size_t)32 * 64 * 4);
    y1c = nullptr;
  } else {
    hb  = (unsigned short*)alloc((size_t)MTOT * DD * 2);
    qb_ = (unsigned short*)alloc((size_t)SS * DD * 2);
    unsigned short* uni = (unsigned short*)alloc((size_t)SS * FF_ * 2);
    kb_ = uni;
    vb_ = uni + (size_t)SS * DD;
    kvp = (float*)(uni + 2 * (size_t)SS * DD);
    ksp = kvp + (size_t)13 * 8 * 4096;
    kvT = (unsigned short*)alloc((size_t)8 * 4096 * 2);
    ksum = (float*)alloc((size_t)8 * 64 * 4);
    y1c = uni;
  }

  // FFT/conv overlay inside qb_ (dead after the final layer's o-proj)
  float* dre  = (float*)qb_;
  float* dimg = dre + (size_t)NB * SS;
  float* tre  = dimg + (size_t)NB * SS;
  float* tim  = tre + (size_t)NB * 128 * 65;
  float* img  = tim + (size_t)NB * 128 * 65;
  float* c1buf = img + (size_t)NB * 128 * 128;
  float* bnp  = c1buf + (size_t)NB * 8 * 128 * 128;
  float* stats = bnp + 512;

  P4 sq4 = { Wq, Wk, Wv, Wo };
  transpose_qkvo_kernel<<<dim3(16, 16, 16), 256, 0, stream>>>(sq4, wsTall);
  transpose_bf16_kernel<<<dim3(64, 16, 4), 256, 0, stream>>>(W1, w1Tall, DD, FF_);
  transpose_bf16_kernel<<<dim3(16, 64, 4), 256, 0, stream>>>(W2, w2Tall, FF_, DD);

  embed_kernel<<<MTOT, 256, 0, stream>>>(fbp, coords, emb_w, emb_b, hb);

  const int npass = (mode >= 1) ? 1 : 4;
  const int NBH = (mode >= 1) ? 32 : 8;
  const int Mrows = (mode >= 1) ? MTOT : SS;

  for (int i = 0; i < LL; ++i) {
    const unsigned short* wsT = wsTall + (size_t)i * 4 * DD * DD;
    const unsigned short* w1T = w1Tall + (size_t)i * DD * FF_;
    const unsigned short* w2T = w2Tall + (size_t)i * DD * FF_;

    for (int p = 0; p < npass; ++p) {
      unsigned short* hbp = hb + (size_t)p * SS * DD;
      gemm_qkv_kernel<<<dim3(12, Mrows / 128), 256, 0, stream>>>(
          hbp, wsT, bq + (size_t)i * DD, bk + (size_t)i * DD, bv + (size_t)i * DD,
          qb_, kb_, vb_);
      kv_part_kernel<<<dim3(13, NBH), 256, 0, stream>>>(kb_, vb_, kvp, ksp);
      kv_reduce_kernel<<<(NBH * 4096 + NBH * 64 + 255) / 256, 256, 0, stream>>>(kvp, ksp, kvT, ksum, NBH);
      attn_kernel<<<dim3(65, NBH), 256, 0, stream>>>(qb_, kvT, ksum);
      gemm_res_kernel<<<dim3(4, Mrows / 128), 256, 0, stream>>>(
          qb_, wsT + (size_t)3 * DD * DD, bo + (size_t)i * DD, hbp, DD, DD, DD, DD);
      ln_wave_kernel<<<Mrows / 4, 256, 0, stream>>>(hbp, ln1g + (size_t)i * DD, ln1b + (size_t)i * DD);

      if (mode == 2) {
        gemm_kernel<2><<<dim3(16, MTOT / 128), 256, 0, stream>>>(
            hb, w1T, b1 + (size_t)i * FF_, y1ded, FF_, DD, DD, DD);
        gemm_res_kernel<<<dim3(4, MTOT / 128), 256, 0, stream>>>(
            y1ded, w2T, b2 + (size_t)i * DD, hb, DD, FF_, FF_, FF_);
      } else if (mode == 1) {
        unsigned short* y1half = qb_;   // overlays qb_+kb_ (both dead here)
        for (int g2 = 0; g2 < 2; ++g2) {
          unsigned short* hbg = hb + (size_t)g2 * 2 * SS * DD;
          gemm_kernel<2><<<dim3(16, 2 * SS / 128), 256, 0, stream>>>(
              hbg, w1T, b1 + (size_t)i * FF_, y1half, FF_, DD, DD, DD);
          gemm_res_kernel<<<dim3(4, 2 * SS / 128), 256, 0, stream>>>(
              y1half, w2T, b2 + (size_t)i * DD, hbg, DD, FF_, FF_, FF_);
        }
      } else {
        gemm_kernel<2><<<dim3(16, SS / 128), 256, 0, stream>>>(
            hbp, w1T, b1 + (size_t)i * FF_, y1c, FF_, DD, DD, DD);
        gemm_res_kernel<<<dim3(4, SS / 128), 256, 0, stream>>>(
            y1c, w2T, b2 + (size_t)i * DD, hbp, DD, FF_, FF_, FF_);
      }
      ln_wave_kernel<<<Mrows / 4, 256, 0, stream>>>(hbp, ln2g + (size_t)i * DD, ln2b + (size_t)i * DD);
    }
  }

  (void)hipMemsetAsync(dre, 0, (size_t)NB * SS * 4 * 2, stream);
  head_wave_kernel<<<MTOT / 4, 256, 0, stream>>>(hb, lnfg, lnfb, aw, ab, pw, pb,
                                                 mag_min, mag_max, atten, dstc,
                                                 (float*)d_out, dre, dimg);
  fftA_kernel<<<130, 256, 0, stream>>>(dre, dimg, tre, tim);
  fftB_kernel<<<256, 256, 0, stream>>>(tre, tim, img);
  conv1_kernel<<<2048, 256, 0, stream>>>(img, c1w, c1b, c1buf);
  bn_part_kernel<<<256, 256, 0, stream>>>(c1buf, bnp);
  bn_final_kernel<<<1, 256, 0, stream>>>(bnp, stats);
  conv2_kernel<<<256, 256, 0, stream>>>(c1buf, stats, bng, bnb, c2w, c2b, img,
                                        (float*)d_out + (size_t)MTOT * 2);
}

// Round 14
// 1837.550 us; speedup vs baseline: 1.1700x; 1.0168x over previous
//
#include <hip/hip_runtime.h>
#include <math.h>

#define NB 4
#define SS 8320
#define DD 512
#define NH_ 8
#define LL 4
#define FF_ 2048
#define MTOT (NB*SS)   // 33280

typedef __attribute__((ext_vector_type(8))) short short8;
typedef __attribute__((ext_vector_type(4))) float f32x4;

__device__ __forceinline__ unsigned short f2bf(float f){
  union { float f; unsigned int u; } x; x.f = f;
  unsigned int r = x.u + 0x7FFFu + ((x.u >> 16) & 1u);
  return (unsigned short)(r >> 16);
}
__device__ __forceinline__ float bf2f(unsigned short u){
  return __uint_as_float(((unsigned int)u) << 16);
}
__device__ __forceinline__ void gload_lds16(const void* g, void* l){
  __builtin_amdgcn_global_load_lds(
      (__attribute__((address_space(1))) void*)g,
      (__attribute__((address_space(3))) void*)l, 16, 0, 0);
}
__device__ __forceinline__ float wred(float v){
  #pragma unroll
  for (int o = 32; o; o >>= 1) v += __shfl_xor(v, o);
  return v;
}
__device__ __forceinline__ float block_sum256(float v){
  __shared__ float sb[4];
  #pragma unroll
  for (int o = 32; o; o >>= 1) v += __shfl_down(v, o);
  int w = threadIdx.x >> 6;
  __syncthreads();
  if ((threadIdx.x & 63) == 0) sb[w] = v;
  __syncthreads();
  return sb[0] + sb[1] + sb[2] + sb[3];
}

// bijective XCD-chunked block remap
__device__ __forceinline__ void xcd_remap(int& bn, int& bm)
{
  const int gx = gridDim.x;
  const int nblk = gx * gridDim.y;
  const int id = blockIdx.x + gx * blockIdx.y;
  const int qd = nblk >> 3, rd = nblk & 7;
  const int xcd = id & 7, pos = id >> 3;
  const int nid = (xcd < rd) ? (xcd * (qd + 1) + pos)
                             : (rd * (qd + 1) + (xcd - rd) * qd + pos);
  bn = nid % gx; bm = nid / gx;
}

// ---------------- batched weight transposes (K x N fp32 -> N x K bf16) -------
struct P4 { const float* p0; const float* p1; const float* p2; const float* p3; };

__global__ __launch_bounds__(256) void transpose_qkvo_kernel(P4 srcs, unsigned short* __restrict__ dst)
{
  __shared__ float tile[32][33];
  const int z = blockIdx.z;
  const int layer = z >> 2, m = z & 3;
  const float* base = (m == 0) ? srcs.p0 : (m == 1) ? srcs.p1 : (m == 2) ? srcs.p2 : srcs.p3;
  const float* src = base + (size_t)layer * DD * DD;
  unsigned short* d = dst + (size_t)z * DD * DD;
  const int n0 = blockIdx.x * 32, k0 = blockIdx.y * 32;
  const int tx = threadIdx.x & 31, ty = threadIdx.x >> 5;
  #pragma unroll
  for (int j = 0; j < 32; j += 8) tile[ty + j][tx] = src[(size_t)(k0 + ty + j) * DD + n0 + tx];
  __syncthreads();
  #pragma unroll
  for (int j = 0; j < 32; j += 8) d[(size_t)(n0 + ty + j) * DD + k0 + tx] = f2bf(tile[tx][ty + j]);
}

__global__ __launch_bounds__(256) void transpose_bf16_kernel(
    const float* __restrict__ src0, unsigned short* __restrict__ dst0, int K, int N)
{
  __shared__ float tile[32][33];
  const float* src = src0 + (size_t)blockIdx.z * K * N;
  unsigned short* dst = dst0 + (size_t)blockIdx.z * K * N;
  const int n0 = blockIdx.x * 32, k0 = blockIdx.y * 32;
  const int tx = threadIdx.x & 31, ty = threadIdx.x >> 5;
  #pragma unroll
  for (int j = 0; j < 32; j += 8) tile[ty + j][tx] = src[(size_t)(k0 + ty + j) * N + n0 + tx];
  __syncthreads();
  #pragma unroll
  for (int j = 0; j < 32; j += 8) dst[(size_t)(n0 + ty + j) * K + k0 + tx] = f2bf(tile[tx][ty + j]);
}

// ---------------- embedding + 2D sinusoidal PE ----------------
__global__ __launch_bounds__(256) void embed_kernel(
    const float* __restrict__ fbp, const int* __restrict__ coords,
    const float* __restrict__ emb_w, const float* __restrict__ emb_b,
    unsigned short* __restrict__ hb)
{
  const int row = blockIdx.x;
  const int c = threadIdx.x;
  const int s = row % SS;
  const float f0 = fbp[(size_t)row * 2], f1 = fbp[(size_t)row * 2 + 1];
  const float v0 = f0 * emb_w[c] + f1 * emb_w[256 + c] + emb_b[c];
  const int p = (c < 128) ? coords[s * 2 + 1] : coords[s * 2];
  const int c2 = c & 127;
  const int jj = c2 >> 1;
  const float dv = expf(-(float)(2 * jj) * (9.210340371976184f / 128.f));
  const float a = (float)p * dv;
  const float v1 = (c2 & 1) ? cosf(a) : sinf(a);
  const size_t base = (size_t)row * DD;
  hb[base + c] = f2bf(v0);
  hb[base + 256 + c] = f2bf(v1);
}

// ---------------- fused QKV GEMM, 128^2 tile, XCD-remapped (unswapped) -------
__global__ __launch_bounds__(256, 4) void gemm_qkv_kernel(
    const unsigned short* __restrict__ A,     // [M][512]
    const unsigned short* __restrict__ Bt,    // [1536][512]
    const float* __restrict__ bq_, const float* __restrict__ bk_, const float* __restrict__ bv_,
    unsigned short* __restrict__ qo, unsigned short* __restrict__ ko, unsigned short* __restrict__ vo)
{
  __shared__ __attribute__((aligned(16))) unsigned short As[128 * 64];
  __shared__ __attribute__((aligned(16))) unsigned short Bs[128 * 64];
  const int tid = threadIdx.x;
  const int lane = tid & 63, w = tid >> 6;
  const int lr = lane & 15, lg = lane >> 4;
  const int wm = w >> 1, wn = w & 1;
  int bn, bm; xcd_remap(bn, bm);                 // bn 0..11
  const int which = bn >> 2;
  const unsigned short* Ag = A + (size_t)bm * 128 * DD;
  const unsigned short* Bg = Bt + (size_t)bn * 128 * DD;
  unsigned short* out = (which == 0) ? qo : (which == 1) ? ko : vo;
  const float* bias = (which == 0) ? bq_ : (which == 1) ? bk_ : bv_;
  f32x4 acc[4][4] = {};
  for (int kt = 0; kt < 8; ++kt) {
    if (kt) __syncthreads();
    const int kbase = kt << 6;
    #pragma unroll
    for (int i = 0; i < 4; ++i) {
      int cid = i * 256 + tid;
      int row = cid >> 3, c = cid & 7;
      gload_lds16(Ag + (size_t)row * DD + kbase + ((c ^ (row & 7)) << 3), (void*)(As + cid * 8));
    }
    #pragma unroll
    for (int i = 0; i < 4; ++i) {
      int cid = i * 256 + tid;
      int row = cid >> 3, c = cid & 7;
      gload_lds16(Bg + (size_t)row * DD + kbase + ((c ^ (row & 7)) << 3), (void*)(Bs + cid * 8));
    }
    __syncthreads();
    #pragma unroll
    for (int kk = 0; kk < 2; ++kk) {
      short8 af[4], bfv[4];
      #pragma unroll
      for (int f = 0; f < 4; ++f) {
        int row = wm * 64 + f * 16 + lr;
        af[f] = *(const short8*)(As + row * 64 + (((kk * 4 + lg) ^ (row & 7)) << 3));
      }
      #pragma unroll
      for (int f = 0; f < 4; ++f) {
        int row = wn * 64 + f * 16 + lr;
        bfv[f] = *(const short8*)(Bs + row * 64 + (((kk * 4 + lg) ^ (row & 7)) << 3));
      }
      #pragma unroll
      for (int fm = 0; fm < 4; ++fm)
        #pragma unroll
        for (int fn = 0; fn < 4; ++fn)
          acc[fm][fn] = __builtin_amdgcn_mfma_f32_16x16x32_bf16(af[fm], bfv[fn], acc[fm][fn], 0, 0, 0);
    }
  }
  const int elu = (which < 2);
  #pragma unroll
  for (int fm = 0; fm < 4; ++fm) {
    const int row0 = bm * 128 + wm * 64 + fm * 16 + lg * 4;
    #pragma unroll
    for (int fn = 0; fn < 4; ++fn) {
      const int col = (bn & 3) * 128 + wn * 64 + fn * 16 + lr;
      const float bv = bias[col];
      #pragma unroll
      for (int r = 0; r < 4; ++r) {
        float v = acc[fm][fn][r] + bv;
        if (elu) v = (v > 0.f) ? (v + 1.f) : __expf(v);
        out[(size_t)(row0 + r) * DD + col] = f2bf(v);
      }
    }
  }
}

// ---------------- generic GEMM (no residual), swapped-MFMA epilogue ---------
// ACT: 0=none 2=relu
template<int ACT>
__global__ __launch_bounds__(256, 4) void gemm_kernel(
    const unsigned short* __restrict__ A,
    const unsigned short* __restrict__ Bt,
    const float* __restrict__ bias,
    unsigned short* __restrict__ C,
    int N, int K, int lda, int ldb)
{
  __shared__ __attribute__((aligned(16))) unsigned short As[128 * 64];
  __shared__ __attribute__((aligned(16))) unsigned short Bs[128 * 64];
  const int tid = threadIdx.x;
  const int lane = tid & 63, w = tid >> 6;
  const int lr = lane & 15, lg = lane >> 4;
  const int wm = w >> 1, wn = w & 1;
  int bn, bm; xcd_remap(bn, bm);
  const unsigned short* Ag = A + (size_t)bm * 128 * lda;
  const unsigned short* Bg = Bt + (size_t)bn * 128 * ldb;
  f32x4 acc[4][4] = {};
  const int nkt = K >> 6;
  for (int kt = 0; kt < nkt; ++kt) {
    if (kt) __syncthreads();
    const int kbase = kt << 6;
    #pragma unroll
    for (int i = 0; i < 4; ++i) {
      int cid = i * 256 + tid;
      int row = cid >> 3, c = cid & 7;
      gload_lds16(Ag + (size_t)row * lda + kbase + ((c ^ (row & 7)) << 3), (void*)(As + cid * 8));
    }
    #pragma unroll
    for (int i = 0; i < 4; ++i) {
      int cid = i * 256 + tid;
      int row = cid >> 3, c = cid & 7;
      gload_lds16(Bg + (size_t)row * ldb + kbase + ((c ^ (row & 7)) << 3), (void*)(Bs + cid * 8));
    }
    __syncthreads();
    #pragma unroll
    for (int kk = 0; kk < 2; ++kk) {
      short8 af[4], bfv[4];
      #pragma unroll
      for (int f = 0; f < 4; ++f) {
        int row = wm * 64 + f * 16 + lr;
        af[f] = *(const short8*)(As + row * 64 + (((kk * 4 + lg) ^ (row & 7)) << 3));
      }
      #pragma unroll
      for (int f = 0; f < 4; ++f) {
        int row = wn * 64 + f * 16 + lr;
        bfv[f] = *(const short8*)(Bs + row * 64 + (((kk * 4 + lg) ^ (row & 7)) << 3));
      }
      #pragma unroll
      for (int fm = 0; fm < 4; ++fm)
        #pragma unroll
        for (int fn = 0; fn < 4; ++fn)
          acc[fm][fn] = __builtin_amdgcn_mfma_f32_16x16x32_bf16(bfv[fn], af[fm], acc[fm][fn], 0, 0, 0);
    }
  }
  #pragma unroll
  for (int fm = 0; fm < 4; ++fm) {
    const int row = bm * 128 + wm * 64 + fm * 16 + lr;
    #pragma unroll
    for (int fn = 0; fn < 4; ++fn) {
      const int colq = bn * 128 + wn * 64 + fn * 16 + lg * 4;
      const float4 bv4 = *(const float4*)(bias + colq);
      float v0 = acc[fm][fn][0] + bv4.x;
      float v1 = acc[fm][fn][1] + bv4.y;
      float v2 = acc[fm][fn][2] + bv4.z;
      float v3 = acc[fm][fn][3] + bv4.w;
      if (ACT == 2) {
        v0 = v0 > 0.f ? v0 : 0.f;
        v1 = v1 > 0.f ? v1 : 0.f;
        v2 = v2 > 0.f ? v2 : 0.f;
        v3 = v3 > 0.f ? v3 : 0.f;
      }
      ushort4 o4 = { f2bf(v0), f2bf(v1), f2bf(v2), f2bf(v3) };
      *(ushort4*)(C + (size_t)row * N + colq) = o4;
    }
  }
}

// ---------------- residual GEMM (C += A@Bt^T + bias), vector epilogue -------
__global__ __launch_bounds__(256) void gemm_res_kernel(
    const unsigned short* __restrict__ A,
    const unsigned short* __restrict__ Bt,
    const float* __restrict__ bias,
    unsigned short* __restrict__ C,
    int N, int K, int lda, int ldb)
{
  __shared__ __attribute__((aligned(16))) unsigned short As[128 * 64];
  __shared__ __attribute__((aligned(16))) unsigned short Bs[128 * 64];
  const int tid = threadIdx.x;
  const int lane = tid & 63, w = tid >> 6;
  const int lr = lane & 15, lg = lane >> 4;
  const int wm = w >> 1, wn = w & 1;
  int bn, bm; xcd_remap(bn, bm);
  const unsigned short* Ag = A + (size_t)bm * 128 * lda;
  const unsigned short* Bg = Bt + (size_t)bn * 128 * ldb;
  f32x4 acc[4][4] = {};
  const int nkt = K >> 6;
  for (int kt = 0; kt < nkt; ++kt) {
    if (kt) __syncthreads();
    const int kbase = kt << 6;
    #pragma unroll
    for (int i = 0; i < 4; ++i) {
      int cid = i * 256 + tid;
      int row = cid >> 3, c = cid & 7;
      gload_lds16(Ag + (size_t)row * lda + kbase + ((c ^ (row & 7)) << 3), (void*)(As + cid * 8));
    }
    #pragma unroll
    for (int i = 0; i < 4; ++i) {
      int cid = i * 256 + tid;
      int row = cid >> 3, c = cid & 7;
      gload_lds16(Bg + (size_t)row * ldb + kbase + ((c ^ (row & 7)) << 3), (void*)(Bs + cid * 8));
    }
    __syncthreads();
    #pragma unroll
    for (int kk = 0; kk < 2; ++kk) {
      short8 af[4], bfv[4];
      #pragma unroll
      for (int f = 0; f < 4; ++f) {
        int row = wm * 64 + f * 16 + lr;
        af[f] = *(const short8*)(As + row * 64 + (((kk * 4 + lg) ^ (row & 7)) << 3));
      }
      #pragma unroll
      for (int f = 0; f < 4; ++f) {
        int row = wn * 64 + f * 16 + lr;
        bfv[f] = *(const short8*)(Bs + row * 64 + (((kk * 4 + lg) ^ (row & 7)) << 3));
      }
      #pragma unroll
      for (int fm = 0; fm < 4; ++fm)
        #pragma unroll
        for (int fn = 0; fn < 4; ++fn)
          acc[fm][fn] = __builtin_amdgcn_mfma_f32_16x16x32_bf16(bfv[fn], af[fm], acc[fm][fn], 0, 0, 0);
    }
  }
  #pragma unroll
  for (int fm = 0; fm < 4; ++fm) {
    const int row = bm * 128 + wm * 64 + fm * 16 + lr;
    #pragma unroll
    for (int fn = 0; fn < 4; ++fn) {
      const int colq = bn * 128 + wn * 64 + fn * 16 + lg * 4;
      const float4 bv4 = *(const float4*)(bias + colq);
      unsigned short* cp = C + (size_t)row * N + colq;
      const ushort4 r4 = *(const ushort4*)cp;
      ushort4 o4;
      o4.x = f2bf(acc[fm][fn][0] + bv4.x + bf2f(r4.x));
      o4.y = f2bf(acc[fm][fn][1] + bv4.y + bf2f(r4.y));
      o4.z = f2bf(acc[fm][fn][2] + bv4.z + bf2f(r4.z));
      o4.w = f2bf(acc[fm][fn][3] + bv4.w + bf2f(r4.w));
      *(ushort4*)cp = o4;
    }
  }
}

// ---------------- kv partials: 640-row chunks x (b,h) ----------------
__global__ __launch_bounds__(256) void kv_part_kernel(
    const unsigned short* __restrict__ kb, const unsigned short* __restrict__ vb,
    float* __restrict__ kvp, float* __restrict__ ksp)
{
  __shared__ __attribute__((aligned(16))) float Kc[128][64];
  __shared__ __attribute__((aligned(16))) float Vc[128][64];
  const int ch = blockIdx.x;
  const int bh = blockIdx.y;
  const int NBH = gridDim.y;
  const int b = bh >> 3, h = bh & 7;
  const int tid = threadIdx.x;
  const int d = tid >> 2, m0 = (tid & 3) << 4;
  f32x4 a0 = {}, a1 = {}, a2 = {}, a3 = {};
  float sk = 0.f;
  for (int t = 0; t < 5; ++t) {
    if (t) __syncthreads();
    const size_t roff = ((size_t)b * SS + ch * 640 + t * 128) * DD + h * 64;
    #pragma unroll
    for (int i = 0; i < 8; ++i) {
      int e4 = i * 256 + tid;
      int r = e4 >> 4, c4 = e4 & 15;
      ushort4 kq = *(const ushort4*)(kb + roff + (size_t)r * DD + c4 * 4);
      ushort4 vq = *(const ushort4*)(vb + roff + (size_t)r * DD + c4 * 4);
      f32x4 kf4 = { bf2f(kq.x), bf2f(kq.y), bf2f(kq.z), bf2f(kq.w) };
      f32x4 vf4 = { bf2f(vq.x), bf2f(vq.y), bf2f(vq.z), bf2f(vq.w) };
      *(f32x4*)&Kc[r][c4 * 4] = kf4;
      *(f32x4*)&Vc[r][c4 * 4] = vf4;
    }
    __syncthreads();
    for (int s2 = 0; s2 < 128; ++s2) {
      const float kd = Kc[s2][d];
      const f32x4* vp = (const f32x4*)&Vc[s2][m0];
      a0 += kd * vp[0]; a1 += kd * vp[1]; a2 += kd * vp[2]; a3 += kd * vp[3];
    }
    if (tid < 64) {
      for (int s2 = 0; s2 < 128; ++s2) sk += Kc[s2][tid];
    }
  }
  float* ko = kvp + (((size_t)ch * NBH + bh) * 64 + d) * 64 + m0;
  *(f32x4*)(ko) = a0; *(f32x4*)(ko + 4) = a1; *(f32x4*)(ko + 8) = a2; *(f32x4*)(ko + 12) = a3;
  if (tid < 64) ksp[((size_t)ch * NBH + bh) * 64 + tid] = sk;
}

__global__ __launch_bounds__(256) void kv_reduce_kernel(
    const float* __restrict__ kvp, const float* __restrict__ ksp,
    unsigned short* __restrict__ kvT, float* __restrict__ ksum, int NBH)
{
  const int idx = blockIdx.x * 256 + threadIdx.x;
  const int nkv = NBH * 4096;
  if (idx < nkv) {
    const int bh = idx >> 12, dm = idx & 4095;
    const int d = dm >> 6, m = dm & 63;
    float s = 0.f;
    #pragma unroll
    for (int c = 0; c < 13; ++c) s += kvp[(((size_t)c * NBH + bh) << 12) + dm];
    kvT[(size_t)bh * 4096 + m * 64 + d] = f2bf(s);
  } else if (idx < nkv + NBH * 64) {
    const int i2 = idx - nkv;
    const int bh = i2 >> 6, d = i2 & 63;
    float s = 0.f;
    #pragma unroll
    for (int c = 0; c < 13; ++c) s += ksp[((size_t)c * NBH + bh) * 64 + d];
    ksum[i2] = s;
  }
}

// ---------------- attn: z fused + (qf @ kv) * z, swapped-MFMA, in-place -----
__global__ __launch_bounds__(256, 4) void attn_kernel(
    unsigned short* __restrict__ qb, const unsigned short* __restrict__ kvT,
    const float* __restrict__ ksum)
{
  __shared__ __attribute__((aligned(16))) unsigned short Qs[128 * 64];
  __shared__ __attribute__((aligned(16))) unsigned short Ks[64 * 64];
  __shared__ float zloc[128];
  const int st = blockIdx.x;
  const int bh = blockIdx.y;
  const int b = bh >> 3, h = bh & 7;
  const int tid = threadIdx.x, lane = tid & 63, w = tid >> 6;
  const int lr = lane & 15, lg = lane >> 4;
  const size_t row0 = (size_t)b * SS + st * 128;
  const unsigned short* Qg = qb + row0 * DD + h * 64;
  #pragma unroll
  for (int i = 0; i < 4; ++i) {
    int cid = i * 256 + tid;
    int r = cid >> 3, c = cid & 7;
    gload_lds16(Qg + (size_t)r * DD + ((c ^ (r & 7)) << 3), (void*)(Qs + cid * 8));
  }
  #pragma unroll
  for (int i = 0; i < 2; ++i) {
    int cid = i * 256 + tid;
    int r = cid >> 3, c = cid & 7;
    gload_lds16(kvT + (size_t)bh * 4096 + r * 64 + ((c ^ (r & 7)) << 3), (void*)(Ks + cid * 8));
  }
  __syncthreads();
  {
    const int row = tid >> 1, half = tid & 1;
    const float* ks = ksum + (size_t)bh * 64;
    float dot = 0.f;
    #pragma unroll
    for (int c0 = 0; c0 < 4; ++c0) {
      const int c = half * 4 + c0;
      short8 qv = *(const short8*)(Qs + row * 64 + ((c ^ (row & 7)) << 3));
      #pragma unroll
      for (int j = 0; j < 8; ++j) dot += bf2f((unsigned short)qv[j]) * ks[c * 8 + j];
    }
    dot += __shfl_xor(dot, 1);
    if (half == 0) zloc[row] = 1.f / (dot + 1e-6f);
  }
  __syncthreads();
  f32x4 acc[2][4] = {};   // [fm][fn]: row = w*32+fm*16+lr, cols = fn*16+lg*4+r
  #pragma unroll
  for (int kk = 0; kk < 2; ++kk) {
    short8 af[2], bfv[4];
    #pragma unroll
    for (int f = 0; f < 2; ++f) {
      int r = w * 32 + f * 16 + lr;
      af[f] = *(const short8*)(Qs + r * 64 + (((kk * 4 + lg) ^ (r & 7)) << 3));
    }
    #pragma unroll
    for (int f = 0; f < 4; ++f) {
      int r = f * 16 + lr;
      bfv[f] = *(const short8*)(Ks + r * 64 + (((kk * 4 + lg) ^ (r & 7)) << 3));
    }
    #pragma unroll
    for (int fm = 0; fm < 2; ++fm)
      #pragma unroll
      for (int fn = 0; fn < 4; ++fn)
        acc[fm][fn] = __builtin_amdgcn_mfma_f32_16x16x32_bf16(bfv[fn], af[fm], acc[fm][fn], 0, 0, 0);
  }
  #pragma unroll
  for (int fm = 0; fm < 2; ++fm) {
    const int lrow = w * 32 + fm * 16 + lr;
    const float zv = zloc[lrow];
    unsigned short* outp = qb + (row0 + lrow) * DD + h * 64;
    #pragma unroll
    for (int fn = 0; fn < 4; ++fn) {
      ushort4 o4;
      o4.x = f2bf(acc[fm][fn][0] * zv);
      o4.y = f2bf(acc[fm][fn][1] * zv);
      o4.z = f2bf(acc[fm][fn][2] * zv);
      o4.w = f2bf(acc[fm][fn][3] * zv);
      *(ushort4*)(outp + fn * 16 + lg * 4) = o4;
    }
  }
}

// ---------------- wave-per-row LayerNorm, in-place bf16 ----------------
__global__ __launch_bounds__(256) void ln_wave_kernel(
    unsigned short* __restrict__ hb, const float* __restrict__ g, const float* __restrict__ bt)
{
  const int tid = threadIdx.x, wv = tid >> 6, ln = tid & 63;
  const size_t row = (size_t)blockIdx.x * 4 + wv;
  unsigned short* p = hb + row * DD + ln * 8;
  ushort4 u0 = *(const ushort4*)p;
  ushort4 u1 = *(const ushort4*)(p + 4);
  float x[8] = { bf2f(u0.x), bf2f(u0.y), bf2f(u0.z), bf2f(u0.w),
                 bf2f(u1.x), bf2f(u1.y), bf2f(u1.z), bf2f(u1.w) };
  float s = 0.f;
  #pragma unroll
  for (int i = 0; i < 8; ++i) s += x[i];
  const float mean = wred(s) * (1.f / DD);
  float sq = 0.f;
  #pragma unroll
  for (int i = 0; i < 8; ++i) { const float d = x[i] - mean; sq += d * d; }
  const float rstd = rsqrtf(wred(sq) * (1.f / DD) + 1e-5f);
  const float4 g0 = *(const float4*)(g + ln * 8), g1 = *(const float4*)(g + ln * 8 + 4);
  const float4 b0 = *(const float4*)(bt + ln * 8), b1 = *(const float4*)(bt + ln * 8 + 4);
  const float gg[8] = { g0.x, g0.y, g0.z, g0.w, g1.x, g1.y, g1.z, g1.w };
  const float bb[8] = { b0.x, b0.y, b0.z, b0.w, b1.x, b1.y, b1.z, b1.w };
  ushort4 o0, o1;
  o0.x = f2bf((x[0] - mean) * rstd * gg[0] + bb[0]);
  o0.y = f2bf((x[1] - mean) * rstd * gg[1] + bb[1]);
  o0.z = f2bf((x[2] - mean) * rstd * gg[2] + bb[2]);
  o0.w = f2bf((x[3] - mean) * rstd * gg[3] + bb[3]);
  o1.x = f2bf((x[4] - mean) * rstd * gg[4] + bb[4]);
  o1.y = f2bf((x[5] - mean) * rstd * gg[5] + bb[5]);
  o1.z = f2bf((x[6] - mean) * rstd * gg[6] + bb[6]);
  o1.w = f2bf((x[7] - mean) * rstd * gg[7] + bb[7]);
  *(ushort4*)p = o0;
  *(ushort4*)(p + 4) = o1;
}

// ---------------- wave-per-row final LN + heads + DFT scatter ----------------
__global__ __launch_bounds__(256) void head_wave_kernel(
    const unsigned short* __restrict__ hb,
    const float* __restrict__ lg_, const float* __restrict__ lb_,
    const float* __restrict__ aw, const float* __restrict__ ab,
    const float* __restrict__ pw, const float* __restrict__ pb,
    const float* __restrict__ mag_min, const float* __restrict__ mag_max,
    const float* __restrict__ atten, const int* __restrict__ dst,
    float* __restrict__ yhat, float* __restrict__ dre, float* __restrict__ dimg)
{
  const int tid = threadIdx.x, wv = tid >> 6, ln = tid & 63;
  const size_t row = (size_t)blockIdx.x * 4 + wv;
  const unsigned short* p = hb + row * DD + ln * 8;
  ushort4 u0 = *(const ushort4*)p;
  ushort4 u1 = *(const ushort4*)(p + 4);
  float x[8] = { bf2f(u0.x), bf2f(u0.y), bf2f(u0.z), bf2f(u0.w),
                 bf2f(u1.x), bf2f(u1.y), bf2f(u1.z), bf2f(u1.w) };
  float s = 0.f;
  #pragma unroll
  for (int i = 0; i < 8; ++i) s += x[i];
  const float mean = wred(s) * (1.f / DD);
  float sq = 0.f;
  #pragma unroll
  for (int i = 0; i < 8; ++i) { const float d = x[i] - mean; sq += d * d; }
  const float rstd = rsqrtf(wred(sq) * (1.f / DD) + 1e-5f);
  float ad = 0.f, pd = 0.f;
  #pragma unroll
  for (int i = 0; i < 8; ++i) {
    const float y = (x[i] - mean) * rstd * lg_[ln * 8 + i] + lb_[ln * 8 + i];
    ad += y * aw[ln * 8 + i];
    pd += y * pw[ln * 8 + i];
  }
  ad = wred(ad); pd = wred(pd);
  if (ln == 0) {
    const float ya = ad + ab[0];
    const float yp = tanhf(pd + pb[0]);
    yhat[row * 2] = ya;
    yhat[row * 2 + 1] = yp;
    const int b = (int)(row / SS), s2 = (int)(row % SS);
    const float amp = expf((ya + 1.f) * 0.5f * (mag_max[0] - mag_min[0]) + mag_min[0]);
    const float phi = yp * 3.14159265358979323846f;
    const int j = dst[s2];
    const float at = atten[j];
    dre[(size_t)b * SS + j] = amp * cosf(phi) * at;
    dimg[(size_t)b * SS + j] = amp * sinf(phi) * at;
  }
}

// ---------------- iDFT stage A ----------------
__global__ __launch_bounds__(256) void fftA_kernel(
    const float* __restrict__ dre, const float* __restrict__ dimg,
    float* __restrict__ tre, float* __restrict__ tim)
{
  __shared__ float ct[128], st[128];
  const int tid = threadIdx.x;
  if (tid < 128) {
    float a = (float)tid * (3.14159265358979323846f / 64.f);
    ct[tid] = cosf(a); st[tid] = sinf(a);
  }
  __syncthreads();
  const int idx = blockIdx.x * 256 + tid;
  const int v = idx % 65;
  const int y = (idx / 65) & 127;
  const int b = idx / (65 * 128);
  const float* pr = dre + (size_t)b * SS + v;
  const float* pi = dimg + (size_t)b * SS + v;
  float ar = 0.f, ai = 0.f;
  for (int u = 0; u < 128; ++u) {
    int t2 = (u * y) & 127;
    float cr = ct[t2], si = st[t2];
    float xr = pr[(size_t)u * 65], xi = pi[(size_t)u * 65];
    ar += xr * cr - xi * si;
    ai += xr * si + xi * cr;
  }
  tre[idx] = ar * (1.f / 128.f);
  tim[idx] = ai * (1.f / 128.f);
}

// ---------------- iDFT stage B ----------------
__global__ __launch_bounds__(256) void fftB_kernel(
    const float* __restrict__ tre, const float* __restrict__ tim,
    float* __restrict__ img)
{
  __shared__ float ct[128], st[128];
  const int tid = threadIdx.x;
  if (tid < 128) {
    float a = (float)tid * (3.14159265358979323846f / 64.f);
    ct[tid] = cosf(a); st[tid] = sinf(a);
  }
  __syncthreads();
  const int idx = blockIdx.x * 256 + tid;
  const int x = idx & 127;
  const int y = (idx >> 7) & 127;
  const int b = idx >> 14;
  const float* pr = tre + ((size_t)b * 128 + y) * 65;
  const float* pi = tim + ((size_t)b * 128 + y) * 65;
  float a2 = pr[0] + ((x & 1) ? -pr[64] : pr[64]);
  for (int v = 1; v < 64; ++v) {
    int t2 = (v * x) & 127;
    a2 += 2.f * (pr[v] * ct[t2] - pi[v] * st[t2]);
  }
  a2 *= (1.f / 128.f);
  const int yy = (y + 64) & 127, xx = (x + 64) & 127;
  img[((size_t)b << 14) + (yy << 7) + xx] = a2;
}

// ---------------- conv 3x3 (1->8) + relu ----------------
__global__ __launch_bounds__(256) void conv1_kernel(
    const float* __restrict__ img, const float* __restrict__ w,
    const float* __restrict__ bi, float* __restrict__ c1)
{
  const int idx = blockIdx.x * 256 + threadIdx.x;
  const int x = idx & 127, y = (idx >> 7) & 127, ch = (idx >> 14) & 7, b = idx >> 17;
  const float* ip = img + ((size_t)b << 14);
  const float* wp = w + ch * 9;
  float acc = bi[ch];
  #pragma unroll
  for (int dy = -1; dy <= 1; ++dy) {
    const int yy = y + dy;
    if (yy < 0 || yy > 127) continue;
    #pragma unroll
    for (int dx = -1; dx <= 1; ++dx) {
      const int xx = x + dx;
      if (xx < 0 || xx > 127) continue;
      acc += ip[(yy << 7) + xx] * wp[(dy + 1) * 3 + (dx + 1)];
    }
  }
  c1[idx] = acc > 0.f ? acc : 0.f;
}

// ---------------- BN stats: two-stage ----------------
__global__ __launch_bounds__(256) void bn_part_kernel(
    const float* __restrict__ c1, float* __restrict__ bnp)
{
  const int ch = blockIdx.x >> 5, sl = blockIdx.x & 31;
  const int tid = threadIdx.x;
  const int n = sl * 2048 + tid * 8;
  const int b = n >> 14, i = n & 16383;
  const float* p = c1 + (((size_t)b * 8 + ch) << 14) + i;
  float4 a0 = *(const float4*)p, a1 = *(const float4*)(p + 4);
  float s = a0.x + a0.y + a0.z + a0.w + a1.x + a1.y + a1.z + a1.w;
  float sq = a0.x*a0.x + a0.y*a0.y + a0.z*a0.z + a0.w*a0.w
           + a1.x*a1.x + a1.y*a1.y + a1.z*a1.z + a1.w*a1.w;
  s = block_sum256(s);
  sq = block_sum256(sq);
  if (tid == 0) { bnp[blockIdx.x] = s; bnp[256 + blockIdx.x] = sq; }
}

__global__ __launch_bounds__(256) void bn_final_kernel(
    const float* __restrict__ bnp, float* __restrict__ stats)
{
  const int t = threadIdx.x;
  float s = bnp[t], sq = bnp[256 + t];
  #pragma unroll
  for (int o = 16; o; o >>= 1) { s += __shfl_down(s, o, 32); sq += __shfl_down(sq, o, 32); }
  if ((t & 31) == 0) {
    const int ch = t >> 5;
    const float m = s * (1.f / 65536.f);
    const float var = sq * (1.f / 65536.f) - m * m;
    stats[ch] = m;
    stats[8 + ch] = rsqrtf(var + 1e-5f);
  }
}

__global__ __launch_bounds__(256) void conv2_kernel(
    const float* __restrict__ c1, const float* __restrict__ stats,
    const float* __restrict__ bng, const float* __restrict__ bnb,
    const float* __restrict__ w2, const float* __restrict__ b2,
    const float* __restrict__ img, float* __restrict__ out)
{
  const int idx = blockIdx.x * 256 + threadIdx.x;
  const int b = idx >> 14, sp = idx & 16383;
  float acc = b2[0];
  #pragma unroll
  for (int ch = 0; ch < 8; ++ch) {
    float v = c1[(((size_t)b * 8 + ch) << 14) + sp];
    v = (v - stats[ch]) * stats[8 + ch] * bng[ch] + bnb[ch];
    acc += v * w2[ch];
  }
  out[idx] = acc + img[idx];
}

extern "C" void kernel_launch(void* const* d_in, const int* in_sizes, int n_in,
                              void* d_out, int out_size, void* d_ws, size_t ws_size,
                              hipStream_t stream)
{
  (void)in_sizes; (void)n_in; (void)out_size;
  const float* fbp = (const float*)d_in[1];
  const float* mag_min = (const float*)d_in[2];
  const float* mag_max = (const float*)d_in[3];
  const float* atten = (const float*)d_in[4];
  const int* coords = (const int*)d_in[5];
  const int* dstc = (const int*)d_in[6];
  const float* emb_w = (const float*)d_in[8];
  const float* emb_b = (const float*)d_in[9];
  const float* Wq = (const float*)d_in[10]; const float* bq = (const float*)d_in[11];
  const float* Wk = (const float*)d_in[12]; const float* bk = (const float*)d_in[13];
  const float* Wv = (const float*)d_in[14]; const float* bv = (const float*)d_in[15];
  const float* Wo = (const float*)d_in[16]; const float* bo = (const float*)d_in[17];
  const float* ln1g = (const float*)d_in[18]; const float* ln1b = (const float*)d_in[19];
  const float* W1 = (const float*)d_in[20]; const float* b1 = (const float*)d_in[21];
  const float* W2 = (const float*)d_in[22]; const float* b2 = (const float*)d_in[23];
  const float* ln2g = (const float*)d_in[24]; const float* ln2b = (const float*)d_in[25];
  const float* lnfg = (const float*)d_in[26]; const float* lnfb = (const float*)d_in[27];
  const float* aw = (const float*)d_in[28]; const float* ab = (const float*)d_in[29];
  const float* pw = (const float*)d_in[30]; const float* pb = (const float*)d_in[31];
  const float* c1w = (const float*)d_in[32]; const float* c1b = (const float*)d_in[33];
  const float* bng = (const float*)d_in[34]; const float* bnb = (const float*)d_in[35];
  const float* c2w = (const float*)d_in[36]; const float* c2b = (const float*)d_in[37];

  auto rnd = [](size_t b_) { return (b_ + 255) & ~(size_t)255; };
  const size_t SZ_M    = rnd((size_t)MTOT * DD * 2);            // 34.08 MB
  const size_t SZ_Y1   = rnd((size_t)MTOT * FF_ * 2);           // 136.3 MB
  const size_t SZ_WQKVO= rnd((size_t)LL * 4 * DD * DD * 2);
  const size_t SZ_W12  = rnd((size_t)LL * DD * FF_ * 2);
  const size_t SZ_WALL = SZ_WQKVO + 2 * SZ_W12;
  const size_t NEED_FULL = SZ_WALL + 4 * SZ_M + rnd((size_t)13*32*4096*4) + rnd((size_t)13*32*64*4) +
                           rnd((size_t)32*4096*2) + rnd((size_t)32*64*4) + 4096;
  const size_t NEED_FULLY = NEED_FULL + SZ_Y1;
  const size_t NEED_FB = SZ_WALL + SZ_M + rnd((size_t)SS*DD*2) + rnd((size_t)SS*FF_*2) +
                         rnd((size_t)8*4096*2) + rnd((size_t)8*64*4) + 4096;
  const int mode = (ws_size >= NEED_FULLY) ? 2 : (ws_size >= NEED_FULL) ? 1 : 0;
  if (mode == 0 && ws_size < NEED_FB) return;

  char* wsp = (char*)d_ws;
  size_t off = 0;
  auto alloc = [&](size_t bytes) -> char* { char* p = wsp + off; off += rnd(bytes); return p; };

  unsigned short* wsTall = (unsigned short*)alloc((size_t)LL * 4 * DD * DD * 2);
  unsigned short* w1Tall = (unsigned short*)alloc((size_t)LL * DD * FF_ * 2);
  unsigned short* w2Tall = (unsigned short*)alloc((size_t)LL * DD * FF_ * 2);

  unsigned short *hb, *qb_, *kb_, *vb_, *y1c, *y1ded = nullptr, *kvT;
  float *kvp, *ksp, *ksum;
  if (mode >= 1) {
    hb  = (unsigned short*)alloc((size_t)MTOT * DD * 2);
    qb_ = (unsigned short*)alloc((size_t)MTOT * DD * 2);
    kb_ = (unsigned short*)alloc((size_t)MTOT * DD * 2);
    vb_ = (unsigned short*)alloc((size_t)MTOT * DD * 2);
    if (mode == 2) y1ded = (unsigned short*)alloc((size_t)MTOT * FF_ * 2);
    kvp = (float*)alloc((size_t)13 * 32 * 4096 * 4);
    ksp = (float*)alloc((size_t)13 * 32 * 64 * 4);
    kvT = (unsigned short*)alloc((size_t)32 * 4096 * 2);
    ksum = (float*)alloc((size_t)32 * 64 * 4);
    y1c = nullptr;
  } else {
    hb  = (unsigned short*)alloc((size_t)MTOT * DD * 2);
    qb_ = (unsigned short*)alloc((size_t)SS * DD * 2);
    unsigned short* uni = (unsigned short*)alloc((size_t)SS * FF_ * 2);
    kb_ = uni;
    vb_ = uni + (size_t)SS * DD;
    kvp = (float*)(uni + 2 * (size_t)SS * DD);
    ksp = kvp + (size_t)13 * 8 * 4096;
    kvT = (unsigned short*)alloc((size_t)8 * 4096 * 2);
    ksum = (float*)alloc((size_t)8 * 64 * 4);
    y1c = uni;
  }

  // FFT/conv overlay inside qb_ (dead after the final layer's o-proj)
  float* dre  = (float*)qb_;
  float* dimg = dre + (size_t)NB * SS;
  float* tre  = dimg + (size_t)NB * SS;
  float* tim  = tre + (size_t)NB * 128 * 65;
  float* img  = tim + (size_t)NB * 128 * 65;
  float* c1buf = img + (size_t)NB * 128 * 128;
  float* bnp  = c1buf + (size_t)NB * 8 * 128 * 128;
  float* stats = bnp + 512;

  P4 sq4 = { Wq, Wk, Wv, Wo };
  transpose_qkvo_kernel<<<dim3(16, 16, 16), 256, 0, stream>>>(sq4, wsTall);
  transpose_bf16_kernel<<<dim3(64, 16, 4), 256, 0, stream>>>(W1, w1Tall, DD, FF_);
  transpose_bf16_kernel<<<dim3(16, 64, 4), 256, 0, stream>>>(W2, w2Tall, FF_, DD);

  embed_kernel<<<MTOT, 256, 0, stream>>>(fbp, coords, emb_w, emb_b, hb);

  const int npass = (mode >= 1) ? 1 : 4;
  const int NBH = (mode >= 1) ? 32 : 8;
  const int Mrows = (mode >= 1) ? MTOT : SS;

  for (int i = 0; i < LL; ++i) {
    const unsigned short* wsT = wsTall + (size_t)i * 4 * DD * DD;
    const unsigned short* w1T = w1Tall + (size_t)i * DD * FF_;
    const unsigned short* w2T = w2Tall + (size_t)i * DD * FF_;

    for (int p = 0; p < npass; ++p) {
      unsigned short* hbp = hb + (size_t)p * SS * DD;
      gemm_qkv_kernel<<<dim3(12, Mrows / 128), 256, 0, stream>>>(
          hbp, wsT, bq + (size_t)i * DD, bk + (size_t)i * DD, bv + (size_t)i * DD,
          qb_, kb_, vb_);
      kv_part_kernel<<<dim3(13, NBH), 256, 0, stream>>>(kb_, vb_, kvp, ksp);
      kv_reduce_kernel<<<(NBH * 4096 + NBH * 64 + 255) / 256, 256, 0, stream>>>(kvp, ksp, kvT, ksum, NBH);
      attn_kernel<<<dim3(65, NBH), 256, 0, stream>>>(qb_, kvT, ksum);
      gemm_res_kernel<<<dim3(4, Mrows / 128), 256, 0, stream>>>(
          qb_, wsT + (size_t)3 * DD * DD, bo + (size_t)i * DD, hbp, DD, DD, DD, DD);
      ln_wave_kernel<<<Mrows / 4, 256, 0, stream>>>(hbp, ln1g + (size_t)i * DD, ln1b + (size_t)i * DD);

      if (mode == 2) {
        gemm_kernel<2><<<dim3(16, MTOT / 128), 256, 0, stream>>>(
            hb, w1T, b1 + (size_t)i * FF_, y1ded, FF_, DD, DD, DD);
        gemm_res_kernel<<<dim3(4, MTOT / 128), 256, 0, stream>>>(
            y1ded, w2T, b2 + (size_t)i * DD, hb, DD, FF_, FF_, FF_);
      } else if (mode == 1) {
        unsigned short* y1half = qb_;   // overlays qb_+kb_ (both dead here)
        for (int g2 = 0; g2 < 2; ++g2) {
          unsigned short* hbg = hb + (size_t)g2 * 2 * SS * DD;
          gemm_kernel<2><<<dim3(16, 2 * SS / 128), 256, 0, stream>>>(
              hbg, w1T, b1 + (size_t)i * FF_, y1half, FF_, DD, DD, DD);
          gemm_res_kernel<<<dim3(4, 2 * SS / 128), 256, 0, stream>>>(
              y1half, w2T, b2 + (size_t)i * DD, hbg, DD, FF_, FF_, FF_);
        }
      } else {
        gemm_kernel<2><<<dim3(16, SS / 128), 256, 0, stream>>>(
            hbp, w1T, b1 + (size_t)i * FF_, y1c, FF_, DD, DD, DD);
        gemm_res_kernel<<<dim3(4, SS / 128), 256, 0, stream>>>(
            y1c, w2T, b2 + (size_t)i * DD, hbp, DD, FF_, FF_, FF_);
      }
      ln_wave_kernel<<<Mrows / 4, 256, 0, stream>>>(hbp, ln2g + (size_t)i * DD, ln2b + (size_t)i * DD);
    }
  }

  (void)hipMemsetAsync(dre, 0, (size_t)NB * SS * 4 * 2, stream);
  head_wave_kernel<<<MTOT / 4, 256, 0, stream>>>(hb, lnfg, lnfb, aw, ab, pw, pb,
                                                 mag_min, mag_max, atten, dstc,
                                                 (float*)d_out, dre, dimg);
  fftA_kernel<<<130, 256, 0, stream>>>(dre, dimg, tre, tim);
  fftB_kernel<<<256, 256, 0, stream>>>(tre, tim, img);
  conv1_kernel<<<2048, 256, 0, stream>>>(img, c1w, c1b, c1buf);
  bn_part_kernel<<<256, 256, 0, stream>>>(c1buf, bnp);
  bn_final_kernel<<<1, 256, 0, stream>>>(bnp, stats);
  conv2_kernel<<<256, 256, 0, stream>>>(c1buf, stats, bng, bnb, c2w, c2b, img,
                                        (float*)d_out + (size_t)MTOT * 2);
}

// Round 15
// 1827.272 us; speedup vs baseline: 1.1766x; 1.0056x over previous
//
#include <hip/hip_runtime.h>
#include <math.h>

#define NB 4
#define SS 8320
#define DD 512
#define NH_ 8
#define LL 4
#define FF_ 2048
#define MTOT (NB*SS)   // 33280

typedef __attribute__((ext_vector_type(8))) short short8;
typedef __attribute__((ext_vector_type(4))) float f32x4;

__device__ __forceinline__ unsigned short f2bf(float f){
  union { float f; unsigned int u; } x; x.f = f;
  unsigned int r = x.u + 0x7FFFu + ((x.u >> 16) & 1u);
  return (unsigned short)(r >> 16);
}
__device__ __forceinline__ float bf2f(unsigned short u){
  return __uint_as_float(((unsigned int)u) << 16);
}
__device__ __forceinline__ void gload_lds16(const void* g, void* l){
  __builtin_amdgcn_global_load_lds(
      (__attribute__((address_space(1))) void*)g,
      (__attribute__((address_space(3))) void*)l, 16, 0, 0);
}
__device__ __forceinline__ float wred(float v){
  #pragma unroll
  for (int o = 32; o; o >>= 1) v += __shfl_xor(v, o);
  return v;
}
__device__ __forceinline__ float block_sum256(float v){
  __shared__ float sb[4];
  #pragma unroll
  for (int o = 32; o; o >>= 1) v += __shfl_down(v, o);
  int w = threadIdx.x >> 6;
  __syncthreads();
  if ((threadIdx.x & 63) == 0) sb[w] = v;
  __syncthreads();
  return sb[0] + sb[1] + sb[2] + sb[3];
}

// bijective XCD-chunked block remap
__device__ __forceinline__ void xcd_remap(int& bn, int& bm)
{
  const int gx = gridDim.x;
  const int nblk = gx * gridDim.y;
  const int id = blockIdx.x + gx * blockIdx.y;
  const int qd = nblk >> 3, rd = nblk & 7;
  const int xcd = id & 7, pos = id >> 3;
  const int nid = (xcd < rd) ? (xcd * (qd + 1) + pos)
                             : (rd * (qd + 1) + (xcd - rd) * qd + pos);
  bn = nid % gx; bm = nid / gx;
}

// ---------------- batched weight transposes (K x N fp32 -> N x K bf16) -------
struct P4 { const float* p0; const float* p1; const float* p2; const float* p3; };

__global__ __launch_bounds__(256) void transpose_qkvo_kernel(P4 srcs, unsigned short* __restrict__ dst)
{
  __shared__ float tile[32][33];
  const int z = blockIdx.z;
  const int layer = z >> 2, m = z & 3;
  const float* base = (m == 0) ? srcs.p0 : (m == 1) ? srcs.p1 : (m == 2) ? srcs.p2 : srcs.p3;
  const float* src = base + (size_t)layer * DD * DD;
  unsigned short* d = dst + (size_t)z * DD * DD;
  const int n0 = blockIdx.x * 32, k0 = blockIdx.y * 32;
  const int tx = threadIdx.x & 31, ty = threadIdx.x >> 5;
  #pragma unroll
  for (int j = 0; j < 32; j += 8) tile[ty + j][tx] = src[(size_t)(k0 + ty + j) * DD + n0 + tx];
  __syncthreads();
  #pragma unroll
  for (int j = 0; j < 32; j += 8) d[(size_t)(n0 + ty + j) * DD + k0 + tx] = f2bf(tile[tx][ty + j]);
}

__global__ __launch_bounds__(256) void transpose_bf16_kernel(
    const float* __restrict__ src0, unsigned short* __restrict__ dst0, int K, int N)
{
  __shared__ float tile[32][33];
  const float* src = src0 + (size_t)blockIdx.z * K * N;
  unsigned short* dst = dst0 + (size_t)blockIdx.z * K * N;
  const int n0 = blockIdx.x * 32, k0 = blockIdx.y * 32;
  const int tx = threadIdx.x & 31, ty = threadIdx.x >> 5;
  #pragma unroll
  for (int j = 0; j < 32; j += 8) tile[ty + j][tx] = src[(size_t)(k0 + ty + j) * N + n0 + tx];
  __syncthreads();
  #pragma unroll
  for (int j = 0; j < 32; j += 8) dst[(size_t)(n0 + ty + j) * K + k0 + tx] = f2bf(tile[tx][ty + j]);
}

// ---------------- embedding + 2D sinusoidal PE ----------------
__global__ __launch_bounds__(256) void embed_kernel(
    const float* __restrict__ fbp, const int* __restrict__ coords,
    const float* __restrict__ emb_w, const float* __restrict__ emb_b,
    unsigned short* __restrict__ hb)
{
  const int row = blockIdx.x;
  const int c = threadIdx.x;
  const int s = row % SS;
  const float f0 = fbp[(size_t)row * 2], f1 = fbp[(size_t)row * 2 + 1];
  const float v0 = f0 * emb_w[c] + f1 * emb_w[256 + c] + emb_b[c];
  const int p = (c < 128) ? coords[s * 2 + 1] : coords[s * 2];
  const int c2 = c & 127;
  const int jj = c2 >> 1;
  const float dv = expf(-(float)(2 * jj) * (9.210340371976184f / 128.f));
  const float a = (float)p * dv;
  const float v1 = (c2 & 1) ? cosf(a) : sinf(a);
  const size_t base = (size_t)row * DD;
  hb[base + c] = f2bf(v0);
  hb[base + 256 + c] = f2bf(v1);
}

// ---------------- fused QKV GEMM, 128^2 tile, XCD-remapped (unswapped) -------
__global__ __launch_bounds__(256, 4) void gemm_qkv_kernel(
    const unsigned short* __restrict__ A,     // [M][512]
    const unsigned short* __restrict__ Bt,    // [1536][512]
    const float* __restrict__ bq_, const float* __restrict__ bk_, const float* __restrict__ bv_,
    unsigned short* __restrict__ qo, unsigned short* __restrict__ ko, unsigned short* __restrict__ vo)
{
  __shared__ __attribute__((aligned(16))) unsigned short As[128 * 64];
  __shared__ __attribute__((aligned(16))) unsigned short Bs[128 * 64];
  const int tid = threadIdx.x;
  const int lane = tid & 63, w = tid >> 6;
  const int lr = lane & 15, lg = lane >> 4;
  const int wm = w >> 1, wn = w & 1;
  int bn, bm; xcd_remap(bn, bm);                 // bn 0..11
  const int which = bn >> 2;
  const unsigned short* Ag = A + (size_t)bm * 128 * DD;
  const unsigned short* Bg = Bt + (size_t)bn * 128 * DD;
  unsigned short* out = (which == 0) ? qo : (which == 1) ? ko : vo;
  const float* bias = (which == 0) ? bq_ : (which == 1) ? bk_ : bv_;
  f32x4 acc[4][4] = {};
  for (int kt = 0; kt < 8; ++kt) {
    if (kt) __syncthreads();
    const int kbase = kt << 6;
    #pragma unroll
    for (int i = 0; i < 4; ++i) {
      int cid = i * 256 + tid;
      int row = cid >> 3, c = cid & 7;
      gload_lds16(Ag + (size_t)row * DD + kbase + ((c ^ (row & 7)) << 3), (void*)(As + cid * 8));
    }
    #pragma unroll
    for (int i = 0; i < 4; ++i) {
      int cid = i * 256 + tid;
      int row = cid >> 3, c = cid & 7;
      gload_lds16(Bg + (size_t)row * DD + kbase + ((c ^ (row & 7)) << 3), (void*)(Bs + cid * 8));
    }
    __syncthreads();
    #pragma unroll
    for (int kk = 0; kk < 2; ++kk) {
      short8 af[4], bfv[4];
      #pragma unroll
      for (int f = 0; f < 4; ++f) {
        int row = wm * 64 + f * 16 + lr;
        af[f] = *(const short8*)(As + row * 64 + (((kk * 4 + lg) ^ (row & 7)) << 3));
      }
      #pragma unroll
      for (int f = 0; f < 4; ++f) {
        int row = wn * 64 + f * 16 + lr;
        bfv[f] = *(const short8*)(Bs + row * 64 + (((kk * 4 + lg) ^ (row & 7)) << 3));
      }
      #pragma unroll
      for (int fm = 0; fm < 4; ++fm)
        #pragma unroll
        for (int fn = 0; fn < 4; ++fn)
          acc[fm][fn] = __builtin_amdgcn_mfma_f32_16x16x32_bf16(af[fm], bfv[fn], acc[fm][fn], 0, 0, 0);
    }
  }
  const int elu = (which < 2);
  #pragma unroll
  for (int fm = 0; fm < 4; ++fm) {
    const int row0 = bm * 128 + wm * 64 + fm * 16 + lg * 4;
    #pragma unroll
    for (int fn = 0; fn < 4; ++fn) {
      const int col = (bn & 3) * 128 + wn * 64 + fn * 16 + lr;
      const float bv = bias[col];
      #pragma unroll
      for (int r = 0; r < 4; ++r) {
        float v = acc[fm][fn][r] + bv;
        if (elu) v = (v > 0.f) ? (v + 1.f) : __expf(v);
        out[(size_t)(row0 + r) * DD + col] = f2bf(v);
      }
    }
  }
}

// ---------------- generic GEMM (no residual), swapped-MFMA epilogue ---------
// ACT: 0=none 2=relu
template<int ACT>
__global__ __launch_bounds__(256, 4) void gemm_kernel(
    const unsigned short* __restrict__ A,
    const unsigned short* __restrict__ Bt,
    const float* __restrict__ bias,
    unsigned short* __restrict__ C,
    int N, int K, int lda, int ldb)
{
  __shared__ __attribute__((aligned(16))) unsigned short As[128 * 64];
  __shared__ __attribute__((aligned(16))) unsigned short Bs[128 * 64];
  const int tid = threadIdx.x;
  const int lane = tid & 63, w = tid >> 6;
  const int lr = lane & 15, lg = lane >> 4;
  const int wm = w >> 1, wn = w & 1;
  int bn, bm; xcd_remap(bn, bm);
  const unsigned short* Ag = A + (size_t)bm * 128 * lda;
  const unsigned short* Bg = Bt + (size_t)bn * 128 * ldb;
  f32x4 acc[4][4] = {};
  const int nkt = K >> 6;
  for (int kt = 0; kt < nkt; ++kt) {
    if (kt) __syncthreads();
    const int kbase = kt << 6;
    #pragma unroll
    for (int i = 0; i < 4; ++i) {
      int cid = i * 256 + tid;
      int row = cid >> 3, c = cid & 7;
      gload_lds16(Ag + (size_t)row * lda + kbase + ((c ^ (row & 7)) << 3), (void*)(As + cid * 8));
    }
    #pragma unroll
    for (int i = 0; i < 4; ++i) {
      int cid = i * 256 + tid;
      int row = cid >> 3, c = cid & 7;
      gload_lds16(Bg + (size_t)row * ldb + kbase + ((c ^ (row & 7)) << 3), (void*)(Bs + cid * 8));
    }
    __syncthreads();
    #pragma unroll
    for (int kk = 0; kk < 2; ++kk) {
      short8 af[4], bfv[4];
      #pragma unroll
      for (int f = 0; f < 4; ++f) {
        int row = wm * 64 + f * 16 + lr;
        af[f] = *(const short8*)(As + row * 64 + (((kk * 4 + lg) ^ (row & 7)) << 3));
      }
      #pragma unroll
      for (int f = 0; f < 4; ++f) {
        int row = wn * 64 + f * 16 + lr;
        bfv[f] = *(const short8*)(Bs + row * 64 + (((kk * 4 + lg) ^ (row & 7)) << 3));
      }
      #pragma unroll
      for (int fm = 0; fm < 4; ++fm)
        #pragma unroll
        for (int fn = 0; fn < 4; ++fn)
          acc[fm][fn] = __builtin_amdgcn_mfma_f32_16x16x32_bf16(bfv[fn], af[fm], acc[fm][fn], 0, 0, 0);
    }
  }
  #pragma unroll
  for (int fm = 0; fm < 4; ++fm) {
    const int row = bm * 128 + wm * 64 + fm * 16 + lr;
    #pragma unroll
    for (int fn = 0; fn < 4; ++fn) {
      const int colq = bn * 128 + wn * 64 + fn * 16 + lg * 4;
      const float4 bv4 = *(const float4*)(bias + colq);
      float v0 = acc[fm][fn][0] + bv4.x;
      float v1 = acc[fm][fn][1] + bv4.y;
      float v2 = acc[fm][fn][2] + bv4.z;
      float v3 = acc[fm][fn][3] + bv4.w;
      if (ACT == 2) {
        v0 = v0 > 0.f ? v0 : 0.f;
        v1 = v1 > 0.f ? v1 : 0.f;
        v2 = v2 > 0.f ? v2 : 0.f;
        v3 = v3 > 0.f ? v3 : 0.f;
      }
      ushort4 o4 = { f2bf(v0), f2bf(v1), f2bf(v2), f2bf(v3) };
      *(ushort4*)(C + (size_t)row * N + colq) = o4;
    }
  }
}

// ---------------- residual GEMM (C += A@Bt^T + bias), vector epilogue -------
__global__ __launch_bounds__(256) void gemm_res_kernel(
    const unsigned short* __restrict__ A,
    const unsigned short* __restrict__ Bt,
    const float* __restrict__ bias,
    unsigned short* __restrict__ C,
    int N, int K, int lda, int ldb)
{
  __shared__ __attribute__((aligned(16))) unsigned short As[128 * 64];
  __shared__ __attribute__((aligned(16))) unsigned short Bs[128 * 64];
  const int tid = threadIdx.x;
  const int lane = tid & 63, w = tid >> 6;
  const int lr = lane & 15, lg = lane >> 4;
  const int wm = w >> 1, wn = w & 1;
  int bn, bm; xcd_remap(bn, bm);
  const unsigned short* Ag = A + (size_t)bm * 128 * lda;
  const unsigned short* Bg = Bt + (size_t)bn * 128 * ldb;
  f32x4 acc[4][4] = {};
  const int nkt = K >> 6;
  for (int kt = 0; kt < nkt; ++kt) {
    if (kt) __syncthreads();
    const int kbase = kt << 6;
    #pragma unroll
    for (int i = 0; i < 4; ++i) {
      int cid = i * 256 + tid;
      int row = cid >> 3, c = cid & 7;
      gload_lds16(Ag + (size_t)row * lda + kbase + ((c ^ (row & 7)) << 3), (void*)(As + cid * 8));
    }
    #pragma unroll
    for (int i = 0; i < 4; ++i) {
      int cid = i * 256 + tid;
      int row = cid >> 3, c = cid & 7;
      gload_lds16(Bg + (size_t)row * ldb + kbase + ((c ^ (row & 7)) << 3), (void*)(Bs + cid * 8));
    }
    __syncthreads();
    #pragma unroll
    for (int kk = 0; kk < 2; ++kk) {
      short8 af[4], bfv[4];
      #pragma unroll
      for (int f = 0; f < 4; ++f) {
        int row = wm * 64 + f * 16 + lr;
        af[f] = *(const short8*)(As + row * 64 + (((kk * 4 + lg) ^ (row & 7)) << 3));
      }
      #pragma unroll
      for (int f = 0; f < 4; ++f) {
        int row = wn * 64 + f * 16 + lr;
        bfv[f] = *(const short8*)(Bs + row * 64 + (((kk * 4 + lg) ^ (row & 7)) << 3));
      }
      #pragma unroll
      for (int fm = 0; fm < 4; ++fm)
        #pragma unroll
        for (int fn = 0; fn < 4; ++fn)
          acc[fm][fn] = __builtin_amdgcn_mfma_f32_16x16x32_bf16(bfv[fn], af[fm], acc[fm][fn], 0, 0, 0);
    }
  }
  #pragma unroll
  for (int fm = 0; fm < 4; ++fm) {
    const int row = bm * 128 + wm * 64 + fm * 16 + lr;
    #pragma unroll
    for (int fn = 0; fn < 4; ++fn) {
      const int colq = bn * 128 + wn * 64 + fn * 16 + lg * 4;
      const float4 bv4 = *(const float4*)(bias + colq);
      unsigned short* cp = C + (size_t)row * N + colq;
      const ushort4 r4 = *(const ushort4*)cp;
      ushort4 o4;
      o4.x = f2bf(acc[fm][fn][0] + bv4.x + bf2f(r4.x));
      o4.y = f2bf(acc[fm][fn][1] + bv4.y + bf2f(r4.y));
      o4.z = f2bf(acc[fm][fn][2] + bv4.z + bf2f(r4.z));
      o4.w = f2bf(acc[fm][fn][3] + bv4.w + bf2f(r4.w));
      *(ushort4*)cp = o4;
    }
  }
}

// ---- kv partials: bf16 LDS staging + 4d x 4m register blocking -------------
__global__ __launch_bounds__(256) void kv_part_kernel(
    const unsigned short* __restrict__ kb, const unsigned short* __restrict__ vb,
    float* __restrict__ kvp, float* __restrict__ ksp)
{
  __shared__ __attribute__((aligned(16))) unsigned short Kc[128 * 64];
  __shared__ __attribute__((aligned(16))) unsigned short Vc[128 * 64];
  const int ch = blockIdx.x;
  const int bh = blockIdx.y;
  const int NBH = gridDim.y;
  const int b = bh >> 3, h = bh & 7;
  const int tid = threadIdx.x;
  const int d0 = (tid >> 4) * 4, m0 = (tid & 15) * 4;
  f32x4 acc[4] = {};           // acc[i][j] = kv[d0+i][m0+j]
  float sk = 0.f;
  for (int t = 0; t < 5; ++t) {
    if (t) __syncthreads();
    const size_t roff = ((size_t)b * SS + ch * 640 + t * 128) * DD + h * 64;
    #pragma unroll
    for (int i = 0; i < 4; ++i) {
      int cid = i * 256 + tid;
      int r = cid >> 3, c = cid & 7;
      gload_lds16(kb + roff + (size_t)r * DD + c * 8, (void*)(Kc + cid * 8));
      gload_lds16(vb + roff + (size_t)r * DD + c * 8, (void*)(Vc + cid * 8));
    }
    __syncthreads();
    for (int s2 = 0; s2 < 128; ++s2) {
      const ushort4 ku = *(const ushort4*)(Kc + s2 * 64 + d0);
      const ushort4 vu = *(const ushort4*)(Vc + s2 * 64 + m0);
      const f32x4 vv = { bf2f(vu.x), bf2f(vu.y), bf2f(vu.z), bf2f(vu.w) };
      acc[0] += bf2f(ku.x) * vv;
      acc[1] += bf2f(ku.y) * vv;
      acc[2] += bf2f(ku.z) * vv;
      acc[3] += bf2f(ku.w) * vv;
    }
    if (tid < 64) {
      for (int s2 = 0; s2 < 128; ++s2) sk += bf2f(Kc[s2 * 64 + tid]);
    }
  }
  float* ko = kvp + (((size_t)ch * NBH + bh) * 64 + d0) * 64 + m0;
  #pragma unroll
  for (int i = 0; i < 4; ++i) *(f32x4*)(ko + i * 64) = acc[i];
  if (tid < 64) ksp[((size_t)ch * NBH + bh) * 64 + tid] = sk;
}

__global__ __launch_bounds__(256) void kv_reduce_kernel(
    const float* __restrict__ kvp, const float* __restrict__ ksp,
    unsigned short* __restrict__ kvT, float* __restrict__ ksum, int NBH)
{
  const int idx = blockIdx.x * 256 + threadIdx.x;
  const int nkv = NBH * 4096;
  if (idx < nkv) {
    const int bh = idx >> 12, dm = idx & 4095;
    const int d = dm >> 6, m = dm & 63;
    float s = 0.f;
    #pragma unroll
    for (int c = 0; c < 13; ++c) s += kvp[(((size_t)c * NBH + bh) << 12) + dm];
    kvT[(size_t)bh * 4096 + m * 64 + d] = f2bf(s);
  } else if (idx < nkv + NBH * 64) {
    const int i2 = idx - nkv;
    const int bh = i2 >> 6, d = i2 & 63;
    float s = 0.f;
    #pragma unroll
    for (int c = 0; c < 13; ++c) s += ksp[((size_t)c * NBH + bh) * 64 + d];
    ksum[i2] = s;
  }
}

// ---------------- attn: z fused + (qf @ kv) * z, swapped-MFMA, in-place -----
__global__ __launch_bounds__(256, 4) void attn_kernel(
    unsigned short* __restrict__ qb, const unsigned short* __restrict__ kvT,
    const float* __restrict__ ksum)
{
  __shared__ __attribute__((aligned(16))) unsigned short Qs[128 * 64];
  __shared__ __attribute__((aligned(16))) unsigned short Ks[64 * 64];
  __shared__ float zloc[128];
  const int st = blockIdx.x;
  const int bh = blockIdx.y;
  const int b = bh >> 3, h = bh & 7;
  const int tid = threadIdx.x, lane = tid & 63, w = tid >> 6;
  const int lr = lane & 15, lg = lane >> 4;
  const size_t row0 = (size_t)b * SS + st * 128;
  const unsigned short* Qg = qb + row0 * DD + h * 64;
  #pragma unroll
  for (int i = 0; i < 4; ++i) {
    int cid = i * 256 + tid;
    int r = cid >> 3, c = cid & 7;
    gload_lds16(Qg + (size_t)r * DD + ((c ^ (r & 7)) << 3), (void*)(Qs + cid * 8));
  }
  #pragma unroll
  for (int i = 0; i < 2; ++i) {
    int cid = i * 256 + tid;
    int r = cid >> 3, c = cid & 7;
    gload_lds16(kvT + (size_t)bh * 4096 + r * 64 + ((c ^ (r & 7)) << 3), (void*)(Ks + cid * 8));
  }
  __syncthreads();
  {
    const int row = tid >> 1, half = tid & 1;
    const float* ks = ksum + (size_t)bh * 64;
    float dot = 0.f;
    #pragma unroll
    for (int c0 = 0; c0 < 4; ++c0) {
      const int c = half * 4 + c0;
      short8 qv = *(const short8*)(Qs + row * 64 + ((c ^ (row & 7)) << 3));
      #pragma unroll
      for (int j = 0; j < 8; ++j) dot += bf2f((unsigned short)qv[j]) * ks[c * 8 + j];
    }
    dot += __shfl_xor(dot, 1);
    if (half == 0) zloc[row] = 1.f / (dot + 1e-6f);
  }
  __syncthreads();
  f32x4 acc[2][4] = {};   // [fm][fn]: row = w*32+fm*16+lr, cols = fn*16+lg*4+r
  #pragma unroll
  for (int kk = 0; kk < 2; ++kk) {
    short8 af[2], bfv[4];
    #pragma unroll
    for (int f = 0; f < 2; ++f) {
      int r = w * 32 + f * 16 + lr;
      af[f] = *(const short8*)(Qs + r * 64 + (((kk * 4 + lg) ^ (r & 7)) << 3));
    }
    #pragma unroll
    for (int f = 0; f < 4; ++f) {
      int r = f * 16 + lr;
      bfv[f] = *(const short8*)(Ks + r * 64 + (((kk * 4 + lg) ^ (r & 7)) << 3));
    }
    #pragma unroll
    for (int fm = 0; fm < 2; ++fm)
      #pragma unroll
      for (int fn = 0; fn < 4; ++fn)
        acc[fm][fn] = __builtin_amdgcn_mfma_f32_16x16x32_bf16(bfv[fn], af[fm], acc[fm][fn], 0, 0, 0);
  }
  #pragma unroll
  for (int fm = 0; fm < 2; ++fm) {
    const int lrow = w * 32 + fm * 16 + lr;
    const float zv = zloc[lrow];
    unsigned short* outp = qb + (row0 + lrow) * DD + h * 64;
    #pragma unroll
    for (int fn = 0; fn < 4; ++fn) {
      ushort4 o4;
      o4.x = f2bf(acc[fm][fn][0] * zv);
      o4.y = f2bf(acc[fm][fn][1] * zv);
      o4.z = f2bf(acc[fm][fn][2] * zv);
      o4.w = f2bf(acc[fm][fn][3] * zv);
      *(ushort4*)(outp + fn * 16 + lg * 4) = o4;
    }
  }
}

// ---------------- wave-per-row LayerNorm, in-place bf16 ----------------
__global__ __launch_bounds__(256) void ln_wave_kernel(
    unsigned short* __restrict__ hb, const float* __restrict__ g, const float* __restrict__ bt)
{
  const int tid = threadIdx.x, wv = tid >> 6, ln = tid & 63;
  const size_t row = (size_t)blockIdx.x * 4 + wv;
  unsigned short* p = hb + row * DD + ln * 8;
  ushort4 u0 = *(const ushort4*)p;
  ushort4 u1 = *(const ushort4*)(p + 4);
  float x[8] = { bf2f(u0.x), bf2f(u0.y), bf2f(u0.z), bf2f(u0.w),
                 bf2f(u1.x), bf2f(u1.y), bf2f(u1.z), bf2f(u1.w) };
  float s = 0.f;
  #pragma unroll
  for (int i = 0; i < 8; ++i) s += x[i];
  const float mean = wred(s) * (1.f / DD);
  float sq = 0.f;
  #pragma unroll
  for (int i = 0; i < 8; ++i) { const float d = x[i] - mean; sq += d * d; }
  const float rstd = rsqrtf(wred(sq) * (1.f / DD) + 1e-5f);
  const float4 g0 = *(const float4*)(g + ln * 8), g1 = *(const float4*)(g + ln * 8 + 4);
  const float4 b0 = *(const float4*)(bt + ln * 8), b1 = *(const float4*)(bt + ln * 8 + 4);
  const float gg[8] = { g0.x, g0.y, g0.z, g0.w, g1.x, g1.y, g1.z, g1.w };
  const float bb[8] = { b0.x, b0.y, b0.z, b0.w, b1.x, b1.y, b1.z, b1.w };
  ushort4 o0, o1;
  o0.x = f2bf((x[0] - mean) * rstd * gg[0] + bb[0]);
  o0.y = f2bf((x[1] - mean) * rstd * gg[1] + bb[1]);
  o0.z = f2bf((x[2] - mean) * rstd * gg[2] + bb[2]);
  o0.w = f2bf((x[3] - mean) * rstd * gg[3] + bb[3]);
  o1.x = f2bf((x[4] - mean) * rstd * gg[4] + bb[4]);
  o1.y = f2bf((x[5] - mean) * rstd * gg[5] + bb[5]);
  o1.z = f2bf((x[6] - mean) * rstd * gg[6] + bb[6]);
  o1.w = f2bf((x[7] - mean) * rstd * gg[7] + bb[7]);
  *(ushort4*)p = o0;
  *(ushort4*)(p + 4) = o1;
}

// ---------------- wave-per-row final LN + heads + DFT scatter ----------------
__global__ __launch_bounds__(256) void head_wave_kernel(
    const unsigned short* __restrict__ hb,
    const float* __restrict__ lg_, const float* __restrict__ lb_,
    const float* __restrict__ aw, const float* __restrict__ ab,
    const float* __restrict__ pw, const float* __restrict__ pb,
    const float* __restrict__ mag_min, const float* __restrict__ mag_max,
    const float* __restrict__ atten, const int* __restrict__ dst,
    float* __restrict__ yhat, float* __restrict__ dre, float* __restrict__ dimg)
{
  const int tid = threadIdx.x, wv = tid >> 6, ln = tid & 63;
  const size_t row = (size_t)blockIdx.x * 4 + wv;
  const unsigned short* p = hb + row * DD + ln * 8;
  ushort4 u0 = *(const ushort4*)p;
  ushort4 u1 = *(const ushort4*)(p + 4);
  float x[8] = { bf2f(u0.x), bf2f(u0.y), bf2f(u0.z), bf2f(u0.w),
                 bf2f(u1.x), bf2f(u1.y), bf2f(u1.z), bf2f(u1.w) };
  float s = 0.f;
  #pragma unroll
  for (int i = 0; i < 8; ++i) s += x[i];
  const float mean = wred(s) * (1.f / DD);
  float sq = 0.f;
  #pragma unroll
  for (int i = 0; i < 8; ++i) { const float d = x[i] - mean; sq += d * d; }
  const float rstd = rsqrtf(wred(sq) * (1.f / DD) + 1e-5f);
  float ad = 0.f, pd = 0.f;
  #pragma unroll
  for (int i = 0; i < 8; ++i) {
    const float y = (x[i] - mean) * rstd * lg_[ln * 8 + i] + lb_[ln * 8 + i];
    ad += y * aw[ln * 8 + i];
    pd += y * pw[ln * 8 + i];
  }
  ad = wred(ad); pd = wred(pd);
  if (ln == 0) {
    const float ya = ad + ab[0];
    const float yp = tanhf(pd + pb[0]);
    yhat[row * 2] = ya;
    yhat[row * 2 + 1] = yp;
    const int b = (int)(row / SS), s2 = (int)(row % SS);
    const float amp = expf((ya + 1.f) * 0.5f * (mag_max[0] - mag_min[0]) + mag_min[0]);
    const float phi = yp * 3.14159265358979323846f;
    const int j = dst[s2];
    const float at = atten[j];
    dre[(size_t)b * SS + j] = amp * cosf(phi) * at;
    dimg[(size_t)b * SS + j] = amp * sinf(phi) * at;
  }
}

// ---------------- iDFT stage A ----------------
__global__ __launch_bounds__(256) void fftA_kernel(
    const float* __restrict__ dre, const float* __restrict__ dimg,
    float* __restrict__ tre, float* __restrict__ tim)
{
  __shared__ float ct[128], st[128];
  const int tid = threadIdx.x;
  if (tid < 128) {
    float a = (float)tid * (3.14159265358979323846f / 64.f);
    ct[tid] = cosf(a); st[tid] = sinf(a);
  }
  __syncthreads();
  const int idx = blockIdx.x * 256 + tid;
  const int v = idx % 65;
  const int y = (idx / 65) & 127;
  const int b = idx / (65 * 128);
  const float* pr = dre + (size_t)b * SS + v;
  const float* pi = dimg + (size_t)b * SS + v;
  float ar = 0.f, ai = 0.f;
  for (int u = 0; u < 128; ++u) {
    int t2 = (u * y) & 127;
    float cr = ct[t2], si = st[t2];
    float xr = pr[(size_t)u * 65], xi = pi[(size_t)u * 65];
    ar += xr * cr - xi * si;
    ai += xr * si + xi * cr;
  }
  tre[idx] = ar * (1.f / 128.f);
  tim[idx] = ai * (1.f / 128.f);
}

// ---------------- iDFT stage B ----------------
__global__ __launch_bounds__(256) void fftB_kernel(
    const float* __restrict__ tre, const float* __restrict__ tim,
    float* __restrict__ img)
{
  __shared__ float ct[128], st[128];
  const int tid = threadIdx.x;
  if (tid < 128) {
    float a = (float)tid * (3.14159265358979323846f / 64.f);
    ct[tid] = cosf(a); st[tid] = sinf(a);
  }
  __syncthreads();
  const int idx = blockIdx.x * 256 + tid;
  const int x = idx & 127;
  const int y = (idx >> 7) & 127;
  const int b = idx >> 14;
  const float* pr = tre + ((size_t)b * 128 + y) * 65;
  const float* pi = tim + ((size_t)b * 128 + y) * 65;
  float a2 = pr[0] + ((x & 1) ? -pr[64] : pr[64]);
  for (int v = 1; v < 64; ++v) {
    int t2 = (v * x) & 127;
    a2 += 2.f * (pr[v] * ct[t2] - pi[v] * st[t2]);
  }
  a2 *= (1.f / 128.f);
  const int yy = (y + 64) & 127, xx = (x + 64) & 127;
  img[((size_t)b << 14) + (yy << 7) + xx] = a2;
}

// ---------------- conv 3x3 (1->8) + relu ----------------
__global__ __launch_bounds__(256) void conv1_kernel(
    const float* __restrict__ img, const float* __restrict__ w,
    const float* __restrict__ bi, float* __restrict__ c1)
{
  const int idx = blockIdx.x * 256 + threadIdx.x;
  const int x = idx & 127, y = (idx >> 7) & 127, ch = (idx >> 14) & 7, b = idx >> 17;
  const float* ip = img + ((size_t)b << 14);
  const float* wp = w + ch * 9;
  float acc = bi[ch];
  #pragma unroll
  for (int dy = -1; dy <= 1; ++dy) {
    const int yy = y + dy;
    if (yy < 0 || yy > 127) continue;
    #pragma unroll
    for (int dx = -1; dx <= 1; ++dx) {
      const int xx = x + dx;
      if (xx < 0 || xx > 127) continue;
      acc += ip[(yy << 7) + xx] * wp[(dy + 1) * 3 + (dx + 1)];
    }
  }
  c1[idx] = acc > 0.f ? acc : 0.f;
}

// ---------------- BN stats: two-stage ----------------
__global__ __launch_bounds__(256) void bn_part_kernel(
    const float* __restrict__ c1, float* __restrict__ bnp)
{
  const int ch = blockIdx.x >> 5, sl = blockIdx.x & 31;
  const int tid = threadIdx.x;
  const int n = sl * 2048 + tid * 8;
  const int b = n >> 14, i = n & 16383;
  const float* p = c1 + (((size_t)b * 8 + ch) << 14) + i;
  float4 a0 = *(const float4*)p, a1 = *(const float4*)(p + 4);
  float s = a0.x + a0.y + a0.z + a0.w + a1.x + a1.y + a1.z + a1.w;
  float sq = a0.x*a0.x + a0.y*a0.y + a0.z*a0.z + a0.w*a0.w
           + a1.x*a1.x + a1.y*a1.y + a1.z*a1.z + a1.w*a1.w;
  s = block_sum256(s);
  sq = block_sum256(sq);
  if (tid == 0) { bnp[blockIdx.x] = s; bnp[256 + blockIdx.x] = sq; }
}

__global__ __launch_bounds__(256) void bn_final_kernel(
    const float* __restrict__ bnp, float* __restrict__ stats)
{
  const int t = threadIdx.x;
  float s = bnp[t], sq = bnp[256 + t];
  #pragma unroll
  for (int o = 16; o; o >>= 1) { s += __shfl_down(s, o, 32); sq += __shfl_down(sq, o, 32); }
  if ((t & 31) == 0) {
    const int ch = t >> 5;
    const float m = s * (1.f / 65536.f);
    const float var = sq * (1.f / 65536.f) - m * m;
    stats[ch] = m;
    stats[8 + ch] = rsqrtf(var + 1e-5f);
  }
}

__global__ __launch_bounds__(256) void conv2_kernel(
    const float* __restrict__ c1, const float* __restrict__ stats,
    const float* __restrict__ bng, const float* __restrict__ bnb,
    const float* __restrict__ w2, const float* __restrict__ b2,
    const float* __restrict__ img, float* __restrict__ out)
{
  const int idx = blockIdx.x * 256 + threadIdx.x;
  const int b = idx >> 14, sp = idx & 16383;
  float acc = b2[0];
  #pragma unroll
  for (int ch = 0; ch < 8; ++ch) {
    float v = c1[(((size_t)b * 8 + ch) << 14) + sp];
    v = (v - stats[ch]) * stats[8 + ch] * bng[ch] + bnb[ch];
    acc += v * w2[ch];
  }
  out[idx] = acc + img[idx];
}

extern "C" void kernel_launch(void* const* d_in, const int* in_sizes, int n_in,
                              void* d_out, int out_size, void* d_ws, size_t ws_size,
                              hipStream_t stream)
{
  (void)in_sizes; (void)n_in; (void)out_size;
  const float* fbp = (const float*)d_in[1];
  const float* mag_min = (const float*)d_in[2];
  const float* mag_max = (const float*)d_in[3];
  const float* atten = (const float*)d_in[4];
  const int* coords = (const int*)d_in[5];
  const int* dstc = (const int*)d_in[6];
  const float* emb_w = (const float*)d_in[8];
  const float* emb_b = (const float*)d_in[9];
  const float* Wq = (const float*)d_in[10]; const float* bq = (const float*)d_in[11];
  const float* Wk = (const float*)d_in[12]; const float* bk = (const float*)d_in[13];
  const float* Wv = (const float*)d_in[14]; const float* bv = (const float*)d_in[15];
  const float* Wo = (const float*)d_in[16]; const float* bo = (const float*)d_in[17];
  const float* ln1g = (const float*)d_in[18]; const float* ln1b = (const float*)d_in[19];
  const float* W1 = (const float*)d_in[20]; const float* b1 = (const float*)d_in[21];
  const float* W2 = (const float*)d_in[22]; const float* b2 = (const float*)d_in[23];
  const float* ln2g = (const float*)d_in[24]; const float* ln2b = (const float*)d_in[25];
  const float* lnfg = (const float*)d_in[26]; const float* lnfb = (const float*)d_in[27];
  const float* aw = (const float*)d_in[28]; const float* ab = (const float*)d_in[29];
  const float* pw = (const float*)d_in[30]; const float* pb = (const float*)d_in[31];
  const float* c1w = (const float*)d_in[32]; const float* c1b = (const float*)d_in[33];
  const float* bng = (const float*)d_in[34]; const float* bnb = (const float*)d_in[35];
  const float* c2w = (const float*)d_in[36]; const float* c2b = (const float*)d_in[37];

  auto rnd = [](size_t b_) { return (b_ + 255) & ~(size_t)255; };
  const size_t SZ_M    = rnd((size_t)MTOT * DD * 2);            // 34.08 MB
  const size_t SZ_Y1   = rnd((size_t)MTOT * FF_ * 2);           // 136.3 MB
  const size_t SZ_WQKVO= rnd((size_t)LL * 4 * DD * DD * 2);
  const size_t SZ_W12  = rnd((size_t)LL * DD * FF_ * 2);
  const size_t SZ_WALL = SZ_WQKVO + 2 * SZ_W12;
  const size_t NEED_FULL = SZ_WALL + 4 * SZ_M + rnd((size_t)13*32*4096*4) + rnd((size_t)13*32*64*4) +
                           rnd((size_t)32*4096*2) + rnd((size_t)32*64*4) + 4096;
  const size_t NEED_FULLY = NEED_FULL + SZ_Y1;
  const size_t NEED_FB = SZ_WALL + SZ_M + rnd((size_t)SS*DD*2) + rnd((size_t)SS*FF_*2) +
                         rnd((size_t)8*4096*2) + rnd((size_t)8*64*4) + 4096;
  const int mode = (ws_size >= NEED_FULLY) ? 2 : (ws_size >= NEED_FULL) ? 1 : 0;
  if (mode == 0 && ws_size < NEED_FB) return;

  char* wsp = (char*)d_ws;
  size_t off = 0;
  auto alloc = [&](size_t bytes) -> char* { char* p = wsp + off; off += rnd(bytes); return p; };

  unsigned short* wsTall = (unsigned short*)alloc((size_t)LL * 4 * DD * DD * 2);
  unsigned short* w1Tall = (unsigned short*)alloc((size_t)LL * DD * FF_ * 2);
  unsigned short* w2Tall = (unsigned short*)alloc((size_t)LL * DD * FF_ * 2);

  unsigned short *hb, *qb_, *kb_, *vb_, *y1c, *y1ded = nullptr, *kvT;
  float *kvp, *ksp, *ksum;
  if (mode >= 1) {
    hb  = (unsigned short*)alloc((size_t)MTOT * DD * 2);
    qb_ = (unsigned short*)alloc((size_t)MTOT * DD * 2);
    kb_ = (unsigned short*)alloc((size_t)MTOT * DD * 2);
    vb_ = (unsigned short*)alloc((size_t)MTOT * DD * 2);
    if (mode == 2) y1ded = (unsigned short*)alloc((size_t)MTOT * FF_ * 2);
    kvp = (float*)alloc((size_t)13 * 32 * 4096 * 4);
    ksp = (float*)alloc((size_t)13 * 32 * 64 * 4);
    kvT = (unsigned short*)alloc((size_t)32 * 4096 * 2);
    ksum = (float*)alloc((size_t)32 * 64 * 4);
    y1c = nullptr;
  } else {
    hb  = (unsigned short*)alloc((size_t)MTOT * DD * 2);
    qb_ = (unsigned short*)alloc((size_t)SS * DD * 2);
    unsigned short* uni = (unsigned short*)alloc((size_t)SS * FF_ * 2);
    kb_ = uni;
    vb_ = uni + (size_t)SS * DD;
    kvp = (float*)(uni + 2 * (size_t)SS * DD);
    ksp = kvp + (size_t)13 * 8 * 4096;
    kvT = (unsigned short*)alloc((size_t)8 * 4096 * 2);
    ksum = (float*)alloc((size_t)8 * 64 * 4);
    y1c = uni;
  }

  // FFT/conv overlay inside qb_ (dead after the final layer's o-proj)
  float* dre  = (float*)qb_;
  float* dimg = dre + (size_t)NB * SS;
  float* tre  = dimg + (size_t)NB * SS;
  float* tim  = tre + (size_t)NB * 128 * 65;
  float* img  = tim + (size_t)NB * 128 * 65;
  float* c1buf = img + (size_t)NB * 128 * 128;
  float* bnp  = c1buf + (size_t)NB * 8 * 128 * 128;
  float* stats = bnp + 512;

  P4 sq4 = { Wq, Wk, Wv, Wo };
  transpose_qkvo_kernel<<<dim3(16, 16, 16), 256, 0, stream>>>(sq4, wsTall);
  transpose_bf16_kernel<<<dim3(64, 16, 4), 256, 0, stream>>>(W1, w1Tall, DD, FF_);
  transpose_bf16_kernel<<<dim3(16, 64, 4), 256, 0, stream>>>(W2, w2Tall, FF_, DD);

  embed_kernel<<<MTOT, 256, 0, stream>>>(fbp, coords, emb_w, emb_b, hb);

  const int npass = (mode >= 1) ? 1 : 4;
  const int NBH = (mode >= 1) ? 32 : 8;
  const int Mrows = (mode >= 1) ? MTOT : SS;

  for (int i = 0; i < LL; ++i) {
    const unsigned short* wsT = wsTall + (size_t)i * 4 * DD * DD;
    const unsigned short* w1T = w1Tall + (size_t)i * DD * FF_;
    const unsigned short* w2T = w2Tall + (size_t)i * DD * FF_;

    for (int p = 0; p < npass; ++p) {
      unsigned short* hbp = hb + (size_t)p * SS * DD;
      gemm_qkv_kernel<<<dim3(12, Mrows / 128), 256, 0, stream>>>(
          hbp, wsT, bq + (size_t)i * DD, bk + (size_t)i * DD, bv + (size_t)i * DD,
          qb_, kb_, vb_);
      kv_part_kernel<<<dim3(13, NBH), 256, 0, stream>>>(kb_, vb_, kvp, ksp);
      kv_reduce_kernel<<<(NBH * 4096 + NBH * 64 + 255) / 256, 256, 0, stream>>>(kvp, ksp, kvT, ksum, NBH);
      attn_kernel<<<dim3(65, NBH), 256, 0, stream>>>(qb_, kvT, ksum);
      gemm_res_kernel<<<dim3(4, Mrows / 128), 256, 0, stream>>>(
          qb_, wsT + (size_t)3 * DD * DD, bo + (size_t)i * DD, hbp, DD, DD, DD, DD);
      ln_wave_kernel<<<Mrows / 4, 256, 0, stream>>>(hbp, ln1g + (size_t)i * DD, ln1b + (size_t)i * DD);

      if (mode == 2) {
        gemm_kernel<2><<<dim3(16, MTOT / 128), 256, 0, stream>>>(
            hb, w1T, b1 + (size_t)i * FF_, y1ded, FF_, DD, DD, DD);
        gemm_res_kernel<<<dim3(4, MTOT / 128), 256, 0, stream>>>(
            y1ded, w2T, b2 + (size_t)i * DD, hb, DD, FF_, FF_, FF_);
      } else if (mode == 1) {
        unsigned short* y1half = qb_;   // overlays qb_+kb_ (both dead here)
        for (int g2 = 0; g2 < 2; ++g2) {
          unsigned short* hbg = hb + (size_t)g2 * 2 * SS * DD;
          gemm_kernel<2><<<dim3(16, 2 * SS / 128), 256, 0, stream>>>(
              hbg, w1T, b1 + (size_t)i * FF_, y1half, FF_, DD, DD, DD);
          gemm_res_kernel<<<dim3(4, 2 * SS / 128), 256, 0, stream>>>(
              y1half, w2T, b2 + (size_t)i * DD, hbg, DD, FF_, FF_, FF_);
        }
      } else {
        gemm_kernel<2><<<dim3(16, SS / 128), 256, 0, stream>>>(
            hbp, w1T, b1 + (size_t)i * FF_, y1c, FF_, DD, DD, DD);
        gemm_res_kernel<<<dim3(4, SS / 128), 256, 0, stream>>>(
            y1c, w2T, b2 + (size_t)i * DD, hbp, DD, FF_, FF_, FF_);
      }
      ln_wave_kernel<<<Mrows / 4, 256, 0, stream>>>(hbp, ln2g + (size_t)i * DD, ln2b + (size_t)i * DD);
    }
  }

  (void)hipMemsetAsync(dre, 0, (size_t)NB * SS * 4 * 2, stream);
  head_wave_kernel<<<MTOT / 4, 256, 0, stream>>>(hb, lnfg, lnfb, aw, ab, pw, pb,
                                                 mag_min, mag_max, atten, dstc,
                                                 (float*)d_out, dre, dimg);
  fftA_kernel<<<130, 256, 0, stream>>>(dre, dimg, tre, tim);
  fftB_kernel<<<256, 256, 0, stream>>>(tre, tim, img);
  conv1_kernel<<<2048, 256, 0, stream>>>(img, c1w, c1b, c1buf);
  bn_part_kernel<<<256, 256, 0, stream>>>(c1buf, bnp);
  bn_final_kernel<<<1, 256, 0, stream>>>(bnp, stats);
  conv2_kernel<<<256, 256, 0, stream>>>(c1buf, stats, bng, bnb, c2w, c2b, img,
                                        (float*)d_out + (size_t)MTOT * 2);
}

// Round 16
// 1798.536 us; speedup vs baseline: 1.1954x; 1.0160x over previous
//
#include <hip/hip_runtime.h>
#include <math.h>

#define NB 4
#define SS 8320
#define DD 512
#define NH_ 8
#define LL 4
#define FF_ 2048
#define MTOT (NB*SS)   // 33280

typedef __attribute__((ext_vector_type(8))) short short8;
typedef __attribute__((ext_vector_type(4))) float f32x4;

__device__ __forceinline__ unsigned short f2bf(float f){
  union { float f; unsigned int u; } x; x.f = f;
  unsigned int r = x.u + 0x7FFFu + ((x.u >> 16) & 1u);
  return (unsigned short)(r >> 16);
}
__device__ __forceinline__ float bf2f(unsigned short u){
  return __uint_as_float(((unsigned int)u) << 16);
}
__device__ __forceinline__ void gload_lds16(const void* g, void* l){
  __builtin_amdgcn_global_load_lds(
      (__attribute__((address_space(1))) void*)g,
      (__attribute__((address_space(3))) void*)l, 16, 0, 0);
}
__device__ __forceinline__ float wred(float v){
  #pragma unroll
  for (int o = 32; o; o >>= 1) v += __shfl_xor(v, o);
  return v;
}
__device__ __forceinline__ float block_sum256(float v){
  __shared__ float sb[4];
  #pragma unroll
  for (int o = 32; o; o >>= 1) v += __shfl_down(v, o);
  int w = threadIdx.x >> 6;
  __syncthreads();
  if ((threadIdx.x & 63) == 0) sb[w] = v;
  __syncthreads();
  return sb[0] + sb[1] + sb[2] + sb[3];
}

// bijective XCD-chunked block remap
__device__ __forceinline__ void xcd_remap(int& bn, int& bm)
{
  const int gx = gridDim.x;
  const int nblk = gx * gridDim.y;
  const int id = blockIdx.x + gx * blockIdx.y;
  const int qd = nblk >> 3, rd = nblk & 7;
  const int xcd = id & 7, pos = id >> 3;
  const int nid = (xcd < rd) ? (xcd * (qd + 1) + pos)
                             : (rd * (qd + 1) + (xcd - rd) * qd + pos);
  bn = nid % gx; bm = nid / gx;
}

// ---------------- batched weight transposes (K x N fp32 -> N x K bf16) -------
struct P4 { const float* p0; const float* p1; const float* p2; const float* p3; };

__global__ __launch_bounds__(256) void transpose_qkvo_kernel(P4 srcs, unsigned short* __restrict__ dst)
{
  __shared__ float tile[32][33];
  const int z = blockIdx.z;
  const int layer = z >> 2, m = z & 3;
  const float* base = (m == 0) ? srcs.p0 : (m == 1) ? srcs.p1 : (m == 2) ? srcs.p2 : srcs.p3;
  const float* src = base + (size_t)layer * DD * DD;
  unsigned short* d = dst + (size_t)z * DD * DD;
  const int n0 = blockIdx.x * 32, k0 = blockIdx.y * 32;
  const int tx = threadIdx.x & 31, ty = threadIdx.x >> 5;
  #pragma unroll
  for (int j = 0; j < 32; j += 8) tile[ty + j][tx] = src[(size_t)(k0 + ty + j) * DD + n0 + tx];
  __syncthreads();
  #pragma unroll
  for (int j = 0; j < 32; j += 8) d[(size_t)(n0 + ty + j) * DD + k0 + tx] = f2bf(tile[tx][ty + j]);
}

__global__ __launch_bounds__(256) void transpose_bf16_kernel(
    const float* __restrict__ src0, unsigned short* __restrict__ dst0, int K, int N)
{
  __shared__ float tile[32][33];
  const float* src = src0 + (size_t)blockIdx.z * K * N;
  unsigned short* dst = dst0 + (size_t)blockIdx.z * K * N;
  const int n0 = blockIdx.x * 32, k0 = blockIdx.y * 32;
  const int tx = threadIdx.x & 31, ty = threadIdx.x >> 5;
  #pragma unroll
  for (int j = 0; j < 32; j += 8) tile[ty + j][tx] = src[(size_t)(k0 + ty + j) * N + n0 + tx];
  __syncthreads();
  #pragma unroll
  for (int j = 0; j < 32; j += 8) dst[(size_t)(n0 + ty + j) * K + k0 + tx] = f2bf(tile[tx][ty + j]);
}

// ---------------- embedding + 2D sinusoidal PE ----------------
__global__ __launch_bounds__(256) void embed_kernel(
    const float* __restrict__ fbp, const int* __restrict__ coords,
    const float* __restrict__ emb_w, const float* __restrict__ emb_b,
    unsigned short* __restrict__ hb)
{
  const int row = blockIdx.x;
  const int c = threadIdx.x;
  const int s = row % SS;
  const float f0 = fbp[(size_t)row * 2], f1 = fbp[(size_t)row * 2 + 1];
  const float v0 = f0 * emb_w[c] + f1 * emb_w[256 + c] + emb_b[c];
  const int p = (c < 128) ? coords[s * 2 + 1] : coords[s * 2];
  const int c2 = c & 127;
  const int jj = c2 >> 1;
  const float dv = expf(-(float)(2 * jj) * (9.210340371976184f / 128.f));
  const float a = (float)p * dv;
  const float v1 = (c2 & 1) ? cosf(a) : sinf(a);
  const size_t base = (size_t)row * DD;
  hb[base + c] = f2bf(v0);
  hb[base + 256 + c] = f2bf(v1);
}

// ---------------- fused QKV GEMM, 128^2 tile, XCD-remapped (unswapped) -------
__global__ __launch_bounds__(256, 4) void gemm_qkv_kernel(
    const unsigned short* __restrict__ A,     // [M][512]
    const unsigned short* __restrict__ Bt,    // [1536][512]
    const float* __restrict__ bq_, const float* __restrict__ bk_, const float* __restrict__ bv_,
    unsigned short* __restrict__ qo, unsigned short* __restrict__ ko, unsigned short* __restrict__ vo)
{
  __shared__ __attribute__((aligned(16))) unsigned short As[128 * 64];
  __shared__ __attribute__((aligned(16))) unsigned short Bs[128 * 64];
  const int tid = threadIdx.x;
  const int lane = tid & 63, w = tid >> 6;
  const int lr = lane & 15, lg = lane >> 4;
  const int wm = w >> 1, wn = w & 1;
  int bn, bm; xcd_remap(bn, bm);                 // bn 0..11
  const int which = bn >> 2;
  const unsigned short* Ag = A + (size_t)bm * 128 * DD;
  const unsigned short* Bg = Bt + (size_t)bn * 128 * DD;
  unsigned short* out = (which == 0) ? qo : (which == 1) ? ko : vo;
  const float* bias = (which == 0) ? bq_ : (which == 1) ? bk_ : bv_;
  f32x4 acc[4][4] = {};
  for (int kt = 0; kt < 8; ++kt) {
    if (kt) __syncthreads();
    const int kbase = kt << 6;
    #pragma unroll
    for (int i = 0; i < 4; ++i) {
      int cid = i * 256 + tid;
      int row = cid >> 3, c = cid & 7;
      gload_lds16(Ag + (size_t)row * DD + kbase + ((c ^ (row & 7)) << 3), (void*)(As + cid * 8));
    }
    #pragma unroll
    for (int i = 0; i < 4; ++i) {
      int cid = i * 256 + tid;
      int row = cid >> 3, c = cid & 7;
      gload_lds16(Bg + (size_t)row * DD + kbase + ((c ^ (row & 7)) << 3), (void*)(Bs + cid * 8));
    }
    __syncthreads();
    #pragma unroll
    for (int kk = 0; kk < 2; ++kk) {
      short8 af[4], bfv[4];
      #pragma unroll
      for (int f = 0; f < 4; ++f) {
        int row = wm * 64 + f * 16 + lr;
        af[f] = *(const short8*)(As + row * 64 + (((kk * 4 + lg) ^ (row & 7)) << 3));
      }
      #pragma unroll
      for (int f = 0; f < 4; ++f) {
        int row = wn * 64 + f * 16 + lr;
        bfv[f] = *(const short8*)(Bs + row * 64 + (((kk * 4 + lg) ^ (row & 7)) << 3));
      }
      #pragma unroll
      for (int fm = 0; fm < 4; ++fm)
        #pragma unroll
        for (int fn = 0; fn < 4; ++fn)
          acc[fm][fn] = __builtin_amdgcn_mfma_f32_16x16x32_bf16(af[fm], bfv[fn], acc[fm][fn], 0, 0, 0);
    }
  }
  const int elu = (which < 2);
  #pragma unroll
  for (int fm = 0; fm < 4; ++fm) {
    const int row0 = bm * 128 + wm * 64 + fm * 16 + lg * 4;
    #pragma unroll
    for (int fn = 0; fn < 4; ++fn) {
      const int col = (bn & 3) * 128 + wn * 64 + fn * 16 + lr;
      const float bv = bias[col];
      #pragma unroll
      for (int r = 0; r < 4; ++r) {
        float v = acc[fm][fn][r] + bv;
        if (elu) v = (v > 0.f) ? (v + 1.f) : __expf(v);
        out[(size_t)(row0 + r) * DD + col] = f2bf(v);
      }
    }
  }
}

// ---------------- generic GEMM (no residual), swapped-MFMA epilogue ---------
// ACT: 0=none 2=relu
template<int ACT>
__global__ __launch_bounds__(256, 4) void gemm_kernel(
    const unsigned short* __restrict__ A,
    const unsigned short* __restrict__ Bt,
    const float* __restrict__ bias,
    unsigned short* __restrict__ C,
    int N, int K, int lda, int ldb)
{
  __shared__ __attribute__((aligned(16))) unsigned short As[128 * 64];
  __shared__ __attribute__((aligned(16))) unsigned short Bs[128 * 64];
  const int tid = threadIdx.x;
  const int lane = tid & 63, w = tid >> 6;
  const int lr = lane & 15, lg = lane >> 4;
  const int wm = w >> 1, wn = w & 1;
  int bn, bm; xcd_remap(bn, bm);
  const unsigned short* Ag = A + (size_t)bm * 128 * lda;
  const unsigned short* Bg = Bt + (size_t)bn * 128 * ldb;
  f32x4 acc[4][4] = {};
  const int nkt = K >> 6;
  for (int kt = 0; kt < nkt; ++kt) {
    if (kt) __syncthreads();
    const int kbase = kt << 6;
    #pragma unroll
    for (int i = 0; i < 4; ++i) {
      int cid = i * 256 + tid;
      int row = cid >> 3, c = cid & 7;
      gload_lds16(Ag + (size_t)row * lda + kbase + ((c ^ (row & 7)) << 3), (void*)(As + cid * 8));
    }
    #pragma unroll
    for (int i = 0; i < 4; ++i) {
      int cid = i * 256 + tid;
      int row = cid >> 3, c = cid & 7;
      gload_lds16(Bg + (size_t)row * ldb + kbase + ((c ^ (row & 7)) << 3), (void*)(Bs + cid * 8));
    }
    __syncthreads();
    #pragma unroll
    for (int kk = 0; kk < 2; ++kk) {
      short8 af[4], bfv[4];
      #pragma unroll
      for (int f = 0; f < 4; ++f) {
        int row = wm * 64 + f * 16 + lr;
        af[f] = *(const short8*)(As + row * 64 + (((kk * 4 + lg) ^ (row & 7)) << 3));
      }
      #pragma unroll
      for (int f = 0; f < 4; ++f) {
        int row = wn * 64 + f * 16 + lr;
        bfv[f] = *(const short8*)(Bs + row * 64 + (((kk * 4 + lg) ^ (row & 7)) << 3));
      }
      #pragma unroll
      for (int fm = 0; fm < 4; ++fm)
        #pragma unroll
        for (int fn = 0; fn < 4; ++fn)
          acc[fm][fn] = __builtin_amdgcn_mfma_f32_16x16x32_bf16(bfv[fn], af[fm], acc[fm][fn], 0, 0, 0);
    }
  }
  #pragma unroll
  for (int fm = 0; fm < 4; ++fm) {
    const int row = bm * 128 + wm * 64 + fm * 16 + lr;
    #pragma unroll
    for (int fn = 0; fn < 4; ++fn) {
      const int colq = bn * 128 + wn * 64 + fn * 16 + lg * 4;
      const float4 bv4 = *(const float4*)(bias + colq);
      float v0 = acc[fm][fn][0] + bv4.x;
      float v1 = acc[fm][fn][1] + bv4.y;
      float v2 = acc[fm][fn][2] + bv4.z;
      float v3 = acc[fm][fn][3] + bv4.w;
      if (ACT == 2) {
        v0 = v0 > 0.f ? v0 : 0.f;
        v1 = v1 > 0.f ? v1 : 0.f;
        v2 = v2 > 0.f ? v2 : 0.f;
        v3 = v3 > 0.f ? v3 : 0.f;
      }
      ushort4 o4 = { f2bf(v0), f2bf(v1), f2bf(v2), f2bf(v3) };
      *(ushort4*)(C + (size_t)row * N + colq) = o4;
    }
  }
}

// ---------------- residual GEMM (C += A@Bt^T + bias), vector epilogue -------
__global__ __launch_bounds__(256) void gemm_res_kernel(
    const unsigned short* __restrict__ A,
    const unsigned short* __restrict__ Bt,
    const float* __restrict__ bias,
    unsigned short* __restrict__ C,
    int N, int K, int lda, int ldb)
{
  __shared__ __attribute__((aligned(16))) unsigned short As[128 * 64];
  __shared__ __attribute__((aligned(16))) unsigned short Bs[128 * 64];
  const int tid = threadIdx.x;
  const int lane = tid & 63, w = tid >> 6;
  const int lr = lane & 15, lg = lane >> 4;
  const int wm = w >> 1, wn = w & 1;
  int bn, bm; xcd_remap(bn, bm);
  const unsigned short* Ag = A + (size_t)bm * 128 * lda;
  const unsigned short* Bg = Bt + (size_t)bn * 128 * ldb;
  f32x4 acc[4][4] = {};
  const int nkt = K >> 6;
  for (int kt = 0; kt < nkt; ++kt) {
    if (kt) __syncthreads();
    const int kbase = kt << 6;
    #pragma unroll
    for (int i = 0; i < 4; ++i) {
      int cid = i * 256 + tid;
      int row = cid >> 3, c = cid & 7;
      gload_lds16(Ag + (size_t)row * lda + kbase + ((c ^ (row & 7)) << 3), (void*)(As + cid * 8));
    }
    #pragma unroll
    for (int i = 0; i < 4; ++i) {
      int cid = i * 256 + tid;
      int row = cid >> 3, c = cid & 7;
      gload_lds16(Bg + (size_t)row * ldb + kbase + ((c ^ (row & 7)) << 3), (void*)(Bs + cid * 8));
    }
    __syncthreads();
    #pragma unroll
    for (int kk = 0; kk < 2; ++kk) {
      short8 af[4], bfv[4];
      #pragma unroll
      for (int f = 0; f < 4; ++f) {
        int row = wm * 64 + f * 16 + lr;
        af[f] = *(const short8*)(As + row * 64 + (((kk * 4 + lg) ^ (row & 7)) << 3));
      }
      #pragma unroll
      for (int f = 0; f < 4; ++f) {
        int row = wn * 64 + f * 16 + lr;
        bfv[f] = *(const short8*)(Bs + row * 64 + (((kk * 4 + lg) ^ (row & 7)) << 3));
      }
      #pragma unroll
      for (int fm = 0; fm < 4; ++fm)
        #pragma unroll
        for (int fn = 0; fn < 4; ++fn)
          acc[fm][fn] = __builtin_amdgcn_mfma_f32_16x16x32_bf16(bfv[fn], af[fm], acc[fm][fn], 0, 0, 0);
    }
  }
  #pragma unroll
  for (int fm = 0; fm < 4; ++fm) {
    const int row = bm * 128 + wm * 64 + fm * 16 + lr;
    #pragma unroll
    for (int fn = 0; fn < 4; ++fn) {
      const int colq = bn * 128 + wn * 64 + fn * 16 + lg * 4;
      const float4 bv4 = *(const float4*)(bias + colq);
      unsigned short* cp = C + (size_t)row * N + colq;
      const ushort4 r4 = *(const ushort4*)cp;
      ushort4 o4;
      o4.x = f2bf(acc[fm][fn][0] + bv4.x + bf2f(r4.x));
      o4.y = f2bf(acc[fm][fn][1] + bv4.y + bf2f(r4.y));
      o4.z = f2bf(acc[fm][fn][2] + bv4.z + bf2f(r4.z));
      o4.w = f2bf(acc[fm][fn][3] + bv4.w + bf2f(r4.w));
      *(ushort4*)cp = o4;
    }
  }
}

// ---- kv partials: 320-row chunks, 64-row subtiles, bf16 LDS, 4x4 blocking --
__global__ __launch_bounds__(256) void kv_part_kernel(
    const unsigned short* __restrict__ kb, const unsigned short* __restrict__ vb,
    float* __restrict__ kvp, float* __restrict__ ksp)
{
  __shared__ __attribute__((aligned(16))) unsigned short Kc[64 * 64];
  __shared__ __attribute__((aligned(16))) unsigned short Vc[64 * 64];
  const int ch = blockIdx.x;           // 0..25 (320 rows each)
  const int bh = blockIdx.y;
  const int NBH = gridDim.y;
  const int b = bh >> 3, h = bh & 7;
  const int tid = threadIdx.x;
  const int d0 = (tid >> 4) * 4, m0 = (tid & 15) * 4;
  f32x4 acc[4] = {};           // acc[i][j] = kv[d0+i][m0+j]
  float sk = 0.f;
  for (int t = 0; t < 5; ++t) {
    if (t) __syncthreads();
    const size_t roff = ((size_t)b * SS + ch * 320 + t * 64) * DD + h * 64;
    #pragma unroll
    for (int i = 0; i < 2; ++i) {
      int cid = i * 256 + tid;
      int r = cid >> 3, c = cid & 7;
      gload_lds16(kb + roff + (size_t)r * DD + c * 8, (void*)(Kc + cid * 8));
      gload_lds16(vb + roff + (size_t)r * DD + c * 8, (void*)(Vc + cid * 8));
    }
    __syncthreads();
    for (int s2 = 0; s2 < 64; ++s2) {
      const ushort4 ku = *(const ushort4*)(Kc + s2 * 64 + d0);
      const ushort4 vu = *(const ushort4*)(Vc + s2 * 64 + m0);
      const f32x4 vv = { bf2f(vu.x), bf2f(vu.y), bf2f(vu.z), bf2f(vu.w) };
      acc[0] += bf2f(ku.x) * vv;
      acc[1] += bf2f(ku.y) * vv;
      acc[2] += bf2f(ku.z) * vv;
      acc[3] += bf2f(ku.w) * vv;
    }
    if (tid < 64) {
      for (int s2 = 0; s2 < 64; ++s2) sk += bf2f(Kc[s2 * 64 + tid]);
    }
  }
  float* ko = kvp + (((size_t)ch * NBH + bh) * 64 + d0) * 64 + m0;
  #pragma unroll
  for (int i = 0; i < 4; ++i) *(f32x4*)(ko + i * 64) = acc[i];
  if (tid < 64) ksp[((size_t)ch * NBH + bh) * 64 + tid] = sk;
}

__global__ __launch_bounds__(256) void kv_reduce_kernel(
    const float* __restrict__ kvp, const float* __restrict__ ksp,
    unsigned short* __restrict__ kvT, float* __restrict__ ksum, int NBH)
{
  const int idx = blockIdx.x * 256 + threadIdx.x;
  const int nkv = NBH * 4096;
  if (idx < nkv) {
    const int bh = idx >> 12, dm = idx & 4095;
    const int d = dm >> 6, m = dm & 63;
    float s = 0.f;
    #pragma unroll
    for (int c = 0; c < 26; ++c) s += kvp[(((size_t)c * NBH + bh) << 12) + dm];
    kvT[(size_t)bh * 4096 + m * 64 + d] = f2bf(s);
  } else if (idx < nkv + NBH * 64) {
    const int i2 = idx - nkv;
    const int bh = i2 >> 6, d = i2 & 63;
    float s = 0.f;
    #pragma unroll
    for (int c = 0; c < 26; ++c) s += ksp[((size_t)c * NBH + bh) * 64 + d];
    ksum[i2] = s;
  }
}

// ---------------- attn: z fused + (qf @ kv) * z, swapped-MFMA, in-place -----
__global__ __launch_bounds__(256, 4) void attn_kernel(
    unsigned short* __restrict__ qb, const unsigned short* __restrict__ kvT,
    const float* __restrict__ ksum)
{
  __shared__ __attribute__((aligned(16))) unsigned short Qs[128 * 64];
  __shared__ __attribute__((aligned(16))) unsigned short Ks[64 * 64];
  __shared__ float zloc[128];
  const int st = blockIdx.x;
  const int bh = blockIdx.y;
  const int b = bh >> 3, h = bh & 7;
  const int tid = threadIdx.x, lane = tid & 63, w = tid >> 6;
  const int lr = lane & 15, lg = lane >> 4;
  const size_t row0 = (size_t)b * SS + st * 128;
  const unsigned short* Qg = qb + row0 * DD + h * 64;
  #pragma unroll
  for (int i = 0; i < 4; ++i) {
    int cid = i * 256 + tid;
    int r = cid >> 3, c = cid & 7;
    gload_lds16(Qg + (size_t)r * DD + ((c ^ (r & 7)) << 3), (void*)(Qs + cid * 8));
  }
  #pragma unroll
  for (int i = 0; i < 2; ++i) {
    int cid = i * 256 + tid;
    int r = cid >> 3, c = cid & 7;
    gload_lds16(kvT + (size_t)bh * 4096 + r * 64 + ((c ^ (r & 7)) << 3), (void*)(Ks + cid * 8));
  }
  __syncthreads();
  {
    const int row = tid >> 1, half = tid & 1;
    const float* ks = ksum + (size_t)bh * 64;
    float dot = 0.f;
    #pragma unroll
    for (int c0 = 0; c0 < 4; ++c0) {
      const int c = half * 4 + c0;
      short8 qv = *(const short8*)(Qs + row * 64 + ((c ^ (row & 7)) << 3));
      #pragma unroll
      for (int j = 0; j < 8; ++j) dot += bf2f((unsigned short)qv[j]) * ks[c * 8 + j];
    }
    dot += __shfl_xor(dot, 1);
    if (half == 0) zloc[row] = 1.f / (dot + 1e-6f);
  }
  __syncthreads();
  f32x4 acc[2][4] = {};   // [fm][fn]: row = w*32+fm*16+lr, cols = fn*16+lg*4+r
  #pragma unroll
  for (int kk = 0; kk < 2; ++kk) {
    short8 af[2], bfv[4];
    #pragma unroll
    for (int f = 0; f < 2; ++f) {
      int r = w * 32 + f * 16 + lr;
      af[f] = *(const short8*)(Qs + r * 64 + (((kk * 4 + lg) ^ (r & 7)) << 3));
    }
    #pragma unroll
    for (int f = 0; f < 4; ++f) {
      int r = f * 16 + lr;
      bfv[f] = *(const short8*)(Ks + r * 64 + (((kk * 4 + lg) ^ (r & 7)) << 3));
    }
    #pragma unroll
    for (int fm = 0; fm < 2; ++fm)
      #pragma unroll
      for (int fn = 0; fn < 4; ++fn)
        acc[fm][fn] = __builtin_amdgcn_mfma_f32_16x16x32_bf16(bfv[fn], af[fm], acc[fm][fn], 0, 0, 0);
  }
  #pragma unroll
  for (int fm = 0; fm < 2; ++fm) {
    const int lrow = w * 32 + fm * 16 + lr;
    const float zv = zloc[lrow];
    unsigned short* outp = qb + (row0 + lrow) * DD + h * 64;
    #pragma unroll
    for (int fn = 0; fn < 4; ++fn) {
      ushort4 o4;
      o4.x = f2bf(acc[fm][fn][0] * zv);
      o4.y = f2bf(acc[fm][fn][1] * zv);
      o4.z = f2bf(acc[fm][fn][2] * zv);
      o4.w = f2bf(acc[fm][fn][3] * zv);
      *(ushort4*)(outp + fn * 16 + lg * 4) = o4;
    }
  }
}

// ---------------- wave-per-row LayerNorm, in-place bf16 ----------------
__global__ __launch_bounds__(256) void ln_wave_kernel(
    unsigned short* __restrict__ hb, const float* __restrict__ g, const float* __restrict__ bt)
{
  const int tid = threadIdx.x, wv = tid >> 6, ln = tid & 63;
  const size_t row = (size_t)blockIdx.x * 4 + wv;
  unsigned short* p = hb + row * DD + ln * 8;
  ushort4 u0 = *(const ushort4*)p;
  ushort4 u1 = *(const ushort4*)(p + 4);
  float x[8] = { bf2f(u0.x), bf2f(u0.y), bf2f(u0.z), bf2f(u0.w),
                 bf2f(u1.x), bf2f(u1.y), bf2f(u1.z), bf2f(u1.w) };
  float s = 0.f;
  #pragma unroll
  for (int i = 0; i < 8; ++i) s += x[i];
  const float mean = wred(s) * (1.f / DD);
  float sq = 0.f;
  #pragma unroll
  for (int i = 0; i < 8; ++i) { const float d = x[i] - mean; sq += d * d; }
  const float rstd = rsqrtf(wred(sq) * (1.f / DD) + 1e-5f);
  const float4 g0 = *(const float4*)(g + ln * 8), g1 = *(const float4*)(g + ln * 8 + 4);
  const float4 b0 = *(const float4*)(bt + ln * 8), b1 = *(const float4*)(bt + ln * 8 + 4);
  const float gg[8] = { g0.x, g0.y, g0.z, g0.w, g1.x, g1.y, g1.z, g1.w };
  const float bb[8] = { b0.x, b0.y, b0.z, b0.w, b1.x, b1.y, b1.z, b1.w };
  ushort4 o0, o1;
  o0.x = f2bf((x[0] - mean) * rstd * gg[0] + bb[0]);
  o0.y = f2bf((x[1] - mean) * rstd * gg[1] + bb[1]);
  o0.z = f2bf((x[2] - mean) * rstd * gg[2] + bb[2]);
  o0.w = f2bf((x[3] - mean) * rstd * gg[3] + bb[3]);
  o1.x = f2bf((x[4] - mean) * rstd * gg[4] + bb[4]);
  o1.y = f2bf((x[5] - mean) * rstd * gg[5] + bb[5]);
  o1.z = f2bf((x[6] - mean) * rstd * gg[6] + bb[6]);
  o1.w = f2bf((x[7] - mean) * rstd * gg[7] + bb[7]);
  *(ushort4*)p = o0;
  *(ushort4*)(p + 4) = o1;
}

// ---------------- wave-per-row final LN + heads + DFT scatter ----------------
__global__ __launch_bounds__(256) void head_wave_kernel(
    const unsigned short* __restrict__ hb,
    const float* __restrict__ lg_, const float* __restrict__ lb_,
    const float* __restrict__ aw, const float* __restrict__ ab,
    const float* __restrict__ pw, const float* __restrict__ pb,
    const float* __restrict__ mag_min, const float* __restrict__ mag_max,
    const float* __restrict__ atten, const int* __restrict__ dst,
    float* __restrict__ yhat, float* __restrict__ dre, float* __restrict__ dimg)
{
  const int tid = threadIdx.x, wv = tid >> 6, ln = tid & 63;
  const size_t row = (size_t)blockIdx.x * 4 + wv;
  const unsigned short* p = hb + row * DD + ln * 8;
  ushort4 u0 = *(const ushort4*)p;
  ushort4 u1 = *(const ushort4*)(p + 4);
  float x[8] = { bf2f(u0.x), bf2f(u0.y), bf2f(u0.z), bf2f(u0.w),
                 bf2f(u1.x), bf2f(u1.y), bf2f(u1.z), bf2f(u1.w) };
  float s = 0.f;
  #pragma unroll
  for (int i = 0; i < 8; ++i) s += x[i];
  const float mean = wred(s) * (1.f / DD);
  float sq = 0.f;
  #pragma unroll
  for (int i = 0; i < 8; ++i) { const float d = x[i] - mean; sq += d * d; }
  const float rstd = rsqrtf(wred(sq) * (1.f / DD) + 1e-5f);
  float ad = 0.f, pd = 0.f;
  #pragma unroll
  for (int i = 0; i < 8; ++i) {
    const float y = (x[i] - mean) * rstd * lg_[ln * 8 + i] + lb_[ln * 8 + i];
    ad += y * aw[ln * 8 + i];
    pd += y * pw[ln * 8 + i];
  }
  ad = wred(ad); pd = wred(pd);
  if (ln == 0) {
    const float ya = ad + ab[0];
    const float yp = tanhf(pd + pb[0]);
    yhat[row * 2] = ya;
    yhat[row * 2 + 1] = yp;
    const int b = (int)(row / SS), s2 = (int)(row % SS);
    const float amp = expf((ya + 1.f) * 0.5f * (mag_max[0] - mag_min[0]) + mag_min[0]);
    const float phi = yp * 3.14159265358979323846f;
    const int j = dst[s2];
    const float at = atten[j];
    dre[(size_t)b * SS + j] = amp * cosf(phi) * at;
    dimg[(size_t)b * SS + j] = amp * sinf(phi) * at;
  }
}

// ---------------- iDFT stage A ----------------
__global__ __launch_bounds__(256) void fftA_kernel(
    const float* __restrict__ dre, const float* __restrict__ dimg,
    float* __restrict__ tre, float* __restrict__ tim)
{
  __shared__ float ct[128], st[128];
  const int tid = threadIdx.x;
  if (tid < 128) {
    float a = (float)tid * (3.14159265358979323846f / 64.f);
    ct[tid] = cosf(a); st[tid] = sinf(a);
  }
  __syncthreads();
  const int idx = blockIdx.x * 256 + tid;
  const int v = idx % 65;
  const int y = (idx / 65) & 127;
  const int b = idx / (65 * 128);
  const float* pr = dre + (size_t)b * SS + v;
  const float* pi = dimg + (size_t)b * SS + v;
  float ar = 0.f, ai = 0.f;
  for (int u = 0; u < 128; ++u) {
    int t2 = (u * y) & 127;
    float cr = ct[t2], si = st[t2];
    float xr = pr[(size_t)u * 65], xi = pi[(size_t)u * 65];
    ar += xr * cr - xi * si;
    ai += xr * si + xi * cr;
  }
  tre[idx] = ar * (1.f / 128.f);
  tim[idx] = ai * (1.f / 128.f);
}

// ---------------- iDFT stage B ----------------
__global__ __launch_bounds__(256) void fftB_kernel(
    const float* __restrict__ tre, const float* __restrict__ tim,
    float* __restrict__ img)
{
  __shared__ float ct[128], st[128];
  const int tid = threadIdx.x;
  if (tid < 128) {
    float a = (float)tid * (3.14159265358979323846f / 64.f);
    ct[tid] = cosf(a); st[tid] = sinf(a);
  }
  __syncthreads();
  const int idx = blockIdx.x * 256 + tid;
  const int x = idx & 127;
  const int y = (idx >> 7) & 127;
  const int b = idx >> 14;
  const float* pr = tre + ((size_t)b * 128 + y) * 65;
  const float* pi = tim + ((size_t)b * 128 + y) * 65;
  float a2 = pr[0] + ((x & 1) ? -pr[64] : pr[64]);
  for (int v = 1; v < 64; ++v) {
    int t2 = (v * x) & 127;
    a2 += 2.f * (pr[v] * ct[t2] - pi[v] * st[t2]);
  }
  a2 *= (1.f / 128.f);
  const int yy = (y + 64) & 127, xx = (x + 64) & 127;
  img[((size_t)b << 14) + (yy << 7) + xx] = a2;
}

// ---------------- conv 3x3 (1->8) + relu ----------------
__global__ __launch_bounds__(256) void conv1_kernel(
    const float* __restrict__ img, const float* __restrict__ w,
    const float* __restrict__ bi, float* __restrict__ c1)
{
  const int idx = blockIdx.x * 256 + threadIdx.x;
  const int x = idx & 127, y = (idx >> 7) & 127, ch = (idx >> 14) & 7, b = idx >> 17;
  const float* ip = img + ((size_t)b << 14);
  const float* wp = w + ch * 9;
  float acc = bi[ch];
  #pragma unroll
  for (int dy = -1; dy <= 1; ++dy) {
    const int yy = y + dy;
    if (yy < 0 || yy > 127) continue;
    #pragma unroll
    for (int dx = -1; dx <= 1; ++dx) {
      const int xx = x + dx;
      if (xx < 0 || xx > 127) continue;
      acc += ip[(yy << 7) + xx] * wp[(dy + 1) * 3 + (dx + 1)];
    }
  }
  c1[idx] = acc > 0.f ? acc : 0.f;
}

// ---------------- BN stats: two-stage ----------------
__global__ __launch_bounds__(256) void bn_part_kernel(
    const float* __restrict__ c1, float* __restrict__ bnp)
{
  const int ch = blockIdx.x >> 5, sl = blockIdx.x & 31;
  const int tid = threadIdx.x;
  const int n = sl * 2048 + tid * 8;
  const int b = n >> 14, i = n & 16383;
  const float* p = c1 + (((size_t)b * 8 + ch) << 14) + i;
  float4 a0 = *(const float4*)p, a1 = *(const float4*)(p + 4);
  float s = a0.x + a0.y + a0.z + a0.w + a1.x + a1.y + a1.z + a1.w;
  float sq = a0.x*a0.x + a0.y*a0.y + a0.z*a0.z + a0.w*a0.w
           + a1.x*a1.x + a1.y*a1.y + a1.z*a1.z + a1.w*a1.w;
  s = block_sum256(s);
  sq = block_sum256(sq);
  if (tid == 0) { bnp[blockIdx.x] = s; bnp[256 + blockIdx.x] = sq; }
}

__global__ __launch_bounds__(256) void bn_final_kernel(
    const float* __restrict__ bnp, float* __restrict__ stats)
{
  const int t = threadIdx.x;
  float s = bnp[t], sq = bnp[256 + t];
  #pragma unroll
  for (int o = 16; o; o >>= 1) { s += __shfl_down(s, o, 32); sq += __shfl_down(sq, o, 32); }
  if ((t & 31) == 0) {
    const int ch = t >> 5;
    const float m = s * (1.f / 65536.f);
    const float var = sq * (1.f / 65536.f) - m * m;
    stats[ch] = m;
    stats[8 + ch] = rsqrtf(var + 1e-5f);
  }
}

__global__ __launch_bounds__(256) void conv2_kernel(
    const float* __restrict__ c1, const float* __restrict__ stats,
    const float* __restrict__ bng, const float* __restrict__ bnb,
    const float* __restrict__ w2, const float* __restrict__ b2,
    const float* __restrict__ img, float* __restrict__ out)
{
  const int idx = blockIdx.x * 256 + threadIdx.x;
  const int b = idx >> 14, sp = idx & 16383;
  float acc = b2[0];
  #pragma unroll
  for (int ch = 0; ch < 8; ++ch) {
    float v = c1[(((size_t)b * 8 + ch) << 14) + sp];
    v = (v - stats[ch]) * stats[8 + ch] * bng[ch] + bnb[ch];
    acc += v * w2[ch];
  }
  out[idx] = acc + img[idx];
}

extern "C" void kernel_launch(void* const* d_in, const int* in_sizes, int n_in,
                              void* d_out, int out_size, void* d_ws, size_t ws_size,
                              hipStream_t stream)
{
  (void)in_sizes; (void)n_in; (void)out_size;
  const float* fbp = (const float*)d_in[1];
  const float* mag_min = (const float*)d_in[2];
  const float* mag_max = (const float*)d_in[3];
  const float* atten = (const float*)d_in[4];
  const int* coords = (const int*)d_in[5];
  const int* dstc = (const int*)d_in[6];
  const float* emb_w = (const float*)d_in[8];
  const float* emb_b = (const float*)d_in[9];
  const float* Wq = (const float*)d_in[10]; const float* bq = (const float*)d_in[11];
  const float* Wk = (const float*)d_in[12]; const float* bk = (const float*)d_in[13];
  const float* Wv = (const float*)d_in[14]; const float* bv = (const float*)d_in[15];
  const float* Wo = (const float*)d_in[16]; const float* bo = (const float*)d_in[17];
  const float* ln1g = (const float*)d_in[18]; const float* ln1b = (const float*)d_in[19];
  const float* W1 = (const float*)d_in[20]; const float* b1 = (const float*)d_in[21];
  const float* W2 = (const float*)d_in[22]; const float* b2 = (const float*)d_in[23];
  const float* ln2g = (const float*)d_in[24]; const float* ln2b = (const float*)d_in[25];
  const float* lnfg = (const float*)d_in[26]; const float* lnfb = (const float*)d_in[27];
  const float* aw = (const float*)d_in[28]; const float* ab = (const float*)d_in[29];
  const float* pw = (const float*)d_in[30]; const float* pb = (const float*)d_in[31];
  const float* c1w = (const float*)d_in[32]; const float* c1b = (const float*)d_in[33];
  const float* bng = (const float*)d_in[34]; const float* bnb = (const float*)d_in[35];
  const float* c2w = (const float*)d_in[36]; const float* c2b = (const float*)d_in[37];

  auto rnd = [](size_t b_) { return (b_ + 255) & ~(size_t)255; };
  const size_t SZ_M    = rnd((size_t)MTOT * DD * 2);            // 34.08 MB
  const size_t SZ_Y1   = rnd((size_t)MTOT * FF_ * 2);           // 136.3 MB
  const size_t SZ_WQKVO= rnd((size_t)LL * 4 * DD * DD * 2);
  const size_t SZ_W12  = rnd((size_t)LL * DD * FF_ * 2);
  const size_t SZ_WALL = SZ_WQKVO + 2 * SZ_W12;
  const size_t NEED_FULL = SZ_WALL + 4 * SZ_M + rnd((size_t)26*32*4096*4) + rnd((size_t)26*32*64*4) +
                           rnd((size_t)32*4096*2) + rnd((size_t)32*64*4) + 4096;
  const size_t NEED_FULLY = NEED_FULL + SZ_Y1;
  const size_t NEED_FB = SZ_WALL + SZ_M + rnd((size_t)SS*DD*2) + rnd((size_t)SS*FF_*2) +
                         rnd((size_t)8*4096*2) + rnd((size_t)8*64*4) + 4096;
  const int mode = (ws_size >= NEED_FULLY) ? 2 : (ws_size >= NEED_FULL) ? 1 : 0;
  if (mode == 0 && ws_size < NEED_FB) return;

  char* wsp = (char*)d_ws;
  size_t off = 0;
  auto alloc = [&](size_t bytes) -> char* { char* p = wsp + off; off += rnd(bytes); return p; };

  unsigned short* wsTall = (unsigned short*)alloc((size_t)LL * 4 * DD * DD * 2);
  unsigned short* w1Tall = (unsigned short*)alloc((size_t)LL * DD * FF_ * 2);
  unsigned short* w2Tall = (unsigned short*)alloc((size_t)LL * DD * FF_ * 2);

  unsigned short *hb, *qb_, *kb_, *vb_, *y1c, *y1ded = nullptr, *kvT;
  float *kvp, *ksp, *ksum;
  if (mode >= 1) {
    hb  = (unsigned short*)alloc((size_t)MTOT * DD * 2);
    qb_ = (unsigned short*)alloc((size_t)MTOT * DD * 2);
    kb_ = (unsigned short*)alloc((size_t)MTOT * DD * 2);
    vb_ = (unsigned short*)alloc((size_t)MTOT * DD * 2);
    if (mode == 2) y1ded = (unsigned short*)alloc((size_t)MTOT * FF_ * 2);
    kvp = (float*)alloc((size_t)26 * 32 * 4096 * 4);
    ksp = (float*)alloc((size_t)26 * 32 * 64 * 4);
    kvT = (unsigned short*)alloc((size_t)32 * 4096 * 2);
    ksum = (float*)alloc((size_t)32 * 64 * 4);
    y1c = nullptr;
  } else {
    hb  = (unsigned short*)alloc((size_t)MTOT * DD * 2);
    qb_ = (unsigned short*)alloc((size_t)SS * DD * 2);
    unsigned short* uni = (unsigned short*)alloc((size_t)SS * FF_ * 2);
    kb_ = uni;
    vb_ = uni + (size_t)SS * DD;
    kvp = (float*)(uni + 2 * (size_t)SS * DD);
    ksp = kvp + (size_t)26 * 8 * 4096;
    kvT = (unsigned short*)alloc((size_t)8 * 4096 * 2);
    ksum = (float*)alloc((size_t)8 * 64 * 4);
    y1c = uni;
  }

  // FFT/conv overlay inside qb_ (dead after the final layer's o-proj)
  float* dre  = (float*)qb_;
  float* dimg = dre + (size_t)NB * SS;
  float* tre  = dimg + (size_t)NB * SS;
  float* tim  = tre + (size_t)NB * 128 * 65;
  float* img  = tim + (size_t)NB * 128 * 65;
  float* c1buf = img + (size_t)NB * 128 * 128;
  float* bnp  = c1buf + (size_t)NB * 8 * 128 * 128;
  float* stats = bnp + 512;

  P4 sq4 = { Wq, Wk, Wv, Wo };
  transpose_qkvo_kernel<<<dim3(16, 16, 16), 256, 0, stream>>>(sq4, wsTall);
  transpose_bf16_kernel<<<dim3(64, 16, 4), 256, 0, stream>>>(W1, w1Tall, DD, FF_);
  transpose_bf16_kernel<<<dim3(16, 64, 4), 256, 0, stream>>>(W2, w2Tall, FF_, DD);

  embed_kernel<<<MTOT, 256, 0, stream>>>(fbp, coords, emb_w, emb_b, hb);

  const int npass = (mode >= 1) ? 1 : 4;
  const int NBH = (mode >= 1) ? 32 : 8;
  const int Mrows = (mode >= 1) ? MTOT : SS;

  for (int i = 0; i < LL; ++i) {
    const unsigned short* wsT = wsTall + (size_t)i * 4 * DD * DD;
    const unsigned short* w1T = w1Tall + (size_t)i * DD * FF_;
    const unsigned short* w2T = w2Tall + (size_t)i * DD * FF_;

    for (int p = 0; p < npass; ++p) {
      unsigned short* hbp = hb + (size_t)p * SS * DD;
      gemm_qkv_kernel<<<dim3(12, Mrows / 128), 256, 0, stream>>>(
          hbp, wsT, bq + (size_t)i * DD, bk + (size_t)i * DD, bv + (size_t)i * DD,
          qb_, kb_, vb_);
      kv_part_kernel<<<dim3(26, NBH), 256, 0, stream>>>(kb_, vb_, kvp, ksp);
      kv_reduce_kernel<<<(NBH * 4096 + NBH * 64 + 255) / 256, 256, 0, stream>>>(kvp, ksp, kvT, ksum, NBH);
      attn_kernel<<<dim3(65, NBH), 256, 0, stream>>>(qb_, kvT, ksum);
      gemm_res_kernel<<<dim3(4, Mrows / 128), 256, 0, stream>>>(
          qb_, wsT + (size_t)3 * DD * DD, bo + (size_t)i * DD, hbp, DD, DD, DD, DD);
      ln_wave_kernel<<<Mrows / 4, 256, 0, stream>>>(hbp, ln1g + (size_t)i * DD, ln1b + (size_t)i * DD);

      if (mode == 2) {
        gemm_kernel<2><<<dim3(16, MTOT / 128), 256, 0, stream>>>(
            hb, w1T, b1 + (size_t)i * FF_, y1ded, FF_, DD, DD, DD);
        gemm_res_kernel<<<dim3(4, MTOT / 128), 256, 0, stream>>>(
            y1ded, w2T, b2 + (size_t)i * DD, hb, DD, FF_, FF_, FF_);
      } else if (mode == 1) {
        unsigned short* y1half = qb_;   // overlays qb_+kb_ (both dead here)
        for (int g2 = 0; g2 < 2; ++g2) {
          unsigned short* hbg = hb + (size_t)g2 * 2 * SS * DD;
          gemm_kernel<2><<<dim3(16, 2 * SS / 128), 256, 0, stream>>>(
              hbg, w1T, b1 + (size_t)i * FF_, y1half, FF_, DD, DD, DD);
          gemm_res_kernel<<<dim3(4, 2 * SS / 128), 256, 0, stream>>>(
              y1half, w2T, b2 + (size_t)i * DD, hbg, DD, FF_, FF_, FF_);
        }
      } else {
        gemm_kernel<2><<<dim3(16, SS / 128), 256, 0, stream>>>(
            hbp, w1T, b1 + (size_t)i * FF_, y1c, FF_, DD, DD, DD);
        gemm_res_kernel<<<dim3(4, SS / 128), 256, 0, stream>>>(
            y1c, w2T, b2 + (size_t)i * DD, hbp, DD, FF_, FF_, FF_);
      }
      ln_wave_kernel<<<Mrows / 4, 256, 0, stream>>>(hbp, ln2g + (size_t)i * DD, ln2b + (size_t)i * DD);
    }
  }

  (void)hipMemsetAsync(dre, 0, (size_t)NB * SS * 4 * 2, stream);
  head_wave_kernel<<<MTOT / 4, 256, 0, stream>>>(hb, lnfg, lnfb, aw, ab, pw, pb,
                                                 mag_min, mag_max, atten, dstc,
                                                 (float*)d_out, dre, dimg);
  fftA_kernel<<<130, 256, 0, stream>>>(dre, dimg, tre, tim);
  fftB_kernel<<<256, 256, 0, stream>>>(tre, tim, img);
  conv1_kernel<<<2048, 256, 0, stream>>>(img, c1w, c1b, c1buf);
  bn_part_kernel<<<256, 256, 0, stream>>>(c1buf, bnp);
  bn_final_kernel<<<1, 256, 0, stream>>>(bnp, stats);
  conv2_kernel<<<256, 256, 0, stream>>>(c1buf, stats, bng, bnb, c2w, c2b, img,
                                        (float*)d_out + (size_t)MTOT * 2);
}